// Round 9
// baseline (422.448 us; speedup 1.0000x reference)
//
#include <hip/hip_runtime.h>
#include <hip/hip_bf16.h>

// DynamicJKGCN on MI355X — round 21: CH 64->32 (halve CSR partials traffic).
// Round-20 (411us = best): agg_fc3 fixed via MFMA fc; scatter_gemm0 61us tops.
// Insight: count/scatter edge-scan work is SL*E*2 regardless of CH (each slice
// block scans its whole chunk), so halving CH halves partials (25.6->12.8MB):
// count writes, reduce_bsum reads, prefix r+w (51->25.6MB), scatter seeds —
// at zero extra scan work. Per-CU scatter work unchanged (2 blk/CU x 25K edges).
// Single-knob round; everything else identical to round 20.

#define H_FEATS 128
#define TPAD 136

typedef __attribute__((ext_vector_type(8))) short short8;
typedef __attribute__((ext_vector_type(4))) float float4v;
typedef unsigned short u16;

__device__ __forceinline__ float dload(const void* p, size_t i, int isbf) {
    return isbf ? __bfloat162float(((const __hip_bfloat16*)p)[i])
                : ((const float*)p)[i];
}

__device__ __forceinline__ float4 load4bf(const u16* p) {
    uint2 u = *(const uint2*)p;
    float4 f;
    f.x = __uint_as_float((u.x & 0xFFFFu) << 16);
    f.y = __uint_as_float(u.x & 0xFFFF0000u);
    f.z = __uint_as_float((u.y & 0xFFFFu) << 16);
    f.w = __uint_as_float(u.y & 0xFFFF0000u);
    return f;
}

__device__ __forceinline__ float bf2f(u16 h) {
    return __uint_as_float((unsigned)h << 16);
}

__device__ __forceinline__ u16 f2bf(float v) {
    return __bfloat16_as_ushort(__float2bfloat16(v));
}

__device__ __forceinline__ void add8(float* a, uint4 u) {
    a[0] += __uint_as_float((u.x & 0xFFFFu) << 16);
    a[1] += __uint_as_float(u.x & 0xFFFF0000u);
    a[2] += __uint_as_float((u.y & 0xFFFFu) << 16);
    a[3] += __uint_as_float(u.y & 0xFFFF0000u);
    a[4] += __uint_as_float((u.z & 0xFFFFu) << 16);
    a[5] += __uint_as_float(u.z & 0xFFFF0000u);
    a[6] += __uint_as_float((u.w & 0xFFFFu) << 16);
    a[7] += __uint_as_float(u.w & 0xFFFF0000u);
}

__device__ __forceinline__ void set8(float* a, uint4 u) {
    a[0] = __uint_as_float((u.x & 0xFFFFu) << 16);
    a[1] = __uint_as_float(u.x & 0xFFFF0000u);
    a[2] = __uint_as_float((u.y & 0xFFFFu) << 16);
    a[3] = __uint_as_float(u.y & 0xFFFF0000u);
    a[4] = __uint_as_float((u.z & 0xFFFFu) << 16);
    a[5] = __uint_as_float(u.z & 0xFFFF0000u);
    a[6] = __uint_as_float((u.w & 0xFFFFu) << 16);
    a[7] = __uint_as_float(u.w & 0xFFFF0000u);
}

__device__ __forceinline__ uint4 pack8(const float* f) {
    uint4 r;
    r.x = (unsigned)f2bf(f[0]) | ((unsigned)f2bf(f[1]) << 16);
    r.y = (unsigned)f2bf(f[2]) | ((unsigned)f2bf(f[3]) << 16);
    r.z = (unsigned)f2bf(f[4]) | ((unsigned)f2bf(f[5]) << 16);
    r.w = (unsigned)f2bf(f[6]) | ((unsigned)f2bf(f[7]) << 16);
    return r;
}

// ---------------- dtype sniff + jk softmax ----------------
__device__ __forceinline__ void sniff_body(const unsigned int* __restrict__ x,
                                           const void* __restrict__ jkwb,
                                           float* __restrict__ meta) {
    __shared__ int cnt[256];
    int t = threadIdx.x;
    int c = 0;
    for (int i = 0; i < 16; i++) {
        unsigned int w = x[t * 16 + i];
        unsigned int e = (w >> 7) & 0xFFu;
        c += (e >= 0x60u && e <= 0x8Fu) ? 1 : 0;
    }
    cnt[t] = c;
    __syncthreads();
    for (int s = 128; s > 0; s >>= 1) {
        if (t < s) cnt[t] += cnt[t + s];
        __syncthreads();
    }
    if (t == 0) {
        int isbf = (cnt[0] > 3000) ? 1 : 0;
        ((int*)meta)[0] = isbf;
        float w0 = dload(jkwb, 0, isbf);
        float w1 = dload(jkwb, 1, isbf);
        float w2 = dload(jkwb, 2, isbf);
        float m = fmaxf(w0, fmaxf(w1, w2));
        float e0 = expf(w0 - m), e1 = expf(w1 - m), e2 = expf(w2 - m);
        float s = e0 + e1 + e2;
        meta[8] = e0 / s; meta[9] = e1 / s; meta[10] = e2 / s;
    }
}

__global__ __launch_bounds__(256) void sniff_jkw(const unsigned int* __restrict__ x,
                                                 const void* __restrict__ jkwb,
                                                 float* __restrict__ meta) {
    sniff_body(x, jkwb, meta);
}

// ---------------- atomic-free CSR build (tier 0) ----------------
#define CSR_CH 32
#define CSR_SL 8
#define CSR_NSC (CSR_CH * CSR_SL * 2)

__global__ __launch_bounds__(256) void count_partial(const int* __restrict__ row,
                                                     const int* __restrict__ col,
                                                     unsigned* __restrict__ partC,
                                                     unsigned* __restrict__ partR,
                                                     int E, int N,
                                                     const unsigned int* __restrict__ x,
                                                     const void* __restrict__ jkwb,
                                                     float* __restrict__ meta) {
    if (blockIdx.x == gridDim.x - 1) {  // piggyback the dtype sniff
        sniff_body(x, jkwb, meta);
        return;
    }
    int b = blockIdx.x;
    int dir = b / (CSR_CH * CSR_SL);
    int r = b % (CSR_CH * CSR_SL);
    int sl = r / CSR_CH;
    int k  = r % CSR_CH;
    const int* arr = dir ? row : col;
    unsigned* part = (dir ? partR : partC) + (size_t)k * N;
    int lo = (int)(((long long)N * sl) / CSR_SL);
    int hi = (int)(((long long)N * (sl + 1)) / CSR_SL);
    int wid = hi - lo;

    __shared__ unsigned cnt[8192];
    for (int i = threadIdx.x; i < wid; i += 256) cnt[i] = 0;
    __syncthreads();

    int e0 = (int)(((long long)E * k) / CSR_CH);
    int e1 = (int)(((long long)E * (k + 1)) / CSR_CH);
    for (int e = e0 + threadIdx.x; e < e1; e += 256) {
        int d = arr[e] - lo;
        if ((unsigned)d < (unsigned)wid) atomicAdd(&cnt[d], 1u);
    }
    __syncthreads();
    for (int i = threadIdx.x; i < wid; i += 256) part[lo + i] = cnt[i];
}

// Fused: cnt[i] = sum_k part[k][i]  AND  per-1024-block sums for the scan.
__global__ __launch_bounds__(256) void reduce_bsum(const unsigned* __restrict__ partC,
                                                   const unsigned* __restrict__ partR,
                                                   int* __restrict__ cntc,
                                                   int* __restrict__ cntr,
                                                   int* __restrict__ b0,
                                                   int* __restrict__ b1, int N) {
    const unsigned* p = blockIdx.y ? partR : partC;
    int* cnt = blockIdx.y ? cntr : cntc;
    int* bs = blockIdx.y ? b1 : b0;
    int base = blockIdx.x * 1024 + threadIdx.x * 4;
    unsigned v0 = 0, v1 = 0, v2 = 0, v3 = 0;
    if (base + 3 < N) {
        for (int k = 0; k < CSR_CH; k++) {
            uint4 u = *(const uint4*)(p + (size_t)k * N + base);
            v0 += u.x; v1 += u.y; v2 += u.z; v3 += u.w;
        }
        int4 w = {(int)v0, (int)v1, (int)v2, (int)v3};
        *(int4*)&cnt[base] = w;
    } else {
        unsigned vv[4] = {0, 0, 0, 0};
        for (int k = 0; k < CSR_CH; k++)
            for (int i = 0; i < 4; i++)
                if (base + i < N) vv[i] += p[(size_t)k * N + base + i];
        for (int i = 0; i < 4; i++) if (base + i < N) cnt[base + i] = (int)vv[i];
        v0 = vv[0]; v1 = vv[1]; v2 = vv[2]; v3 = vv[3];
    }
    int s = (int)(v0 + v1 + v2 + v3);
    __shared__ int red[256];
    red[threadIdx.x] = s;
    __syncthreads();
    for (int d = 128; d > 0; d >>= 1) {
        if (threadIdx.x < d) red[threadIdx.x] += red[threadIdx.x + d];
        __syncthreads();
    }
    if (threadIdx.x == 0) bs[blockIdx.x] = red[0];
}

// part[k][i] <- off[i] + sum_{k'<k} part[k'][i]
__global__ __launch_bounds__(256) void prefix_partials(unsigned* __restrict__ partC,
                                                       unsigned* __restrict__ partR,
                                                       const int* __restrict__ coff,
                                                       const int* __restrict__ roff, int N) {
    int i = blockIdx.x * 256 + threadIdx.x;
    if (i >= N) return;
    unsigned* p = blockIdx.y ? partR : partC;
    const int* off = blockIdx.y ? roff : coff;
    unsigned acc = (unsigned)off[i];
    for (int k = 0; k < CSR_CH; k++) {
        unsigned t = p[(size_t)k * N + i];
        p[(size_t)k * N + i] = acc;
        acc += t;
    }
}

// single-pass scatter body: LDS cursors seeded from bases; 0 global atomics.
__device__ __forceinline__ void scatter_body(int b,
                                             const int* __restrict__ row,
                                             const int* __restrict__ col,
                                             const unsigned* __restrict__ partC,
                                             const unsigned* __restrict__ partR,
                                             u16* __restrict__ ecol,
                                             u16* __restrict__ erow,
                                             int E, int N,
                                             unsigned* __restrict__ cur) {
    int dir = b / (CSR_CH * CSR_SL);
    int r = b % (CSR_CH * CSR_SL);
    int sl = r / CSR_CH;
    int k  = r % CSR_CH;
    const int* darr = dir ? row : col;
    const int* sarr = dir ? col : row;
    u16* out = dir ? erow : ecol;
    const unsigned* base = (dir ? partR : partC) + (size_t)k * N;
    int lo = (int)(((long long)N * sl) / CSR_SL);
    int hi = (int)(((long long)N * (sl + 1)) / CSR_SL);
    int wid = hi - lo;

    for (int i = threadIdx.x; i < wid; i += 256) cur[i] = base[lo + i];
    __syncthreads();

    int e0 = (int)(((long long)E * k) / CSR_CH);
    int e1 = (int)(((long long)E * (k + 1)) / CSR_CH);
    for (int e = e0 + threadIdx.x; e < e1; e += 256) {
        int d = darr[e] - lo;
        if ((unsigned)d < (unsigned)wid) {
            unsigned p = atomicAdd(&cur[d], 1u);
            out[p] = (u16)sarr[e];
        }
    }
}

// ---------------- legacy CSR build (tier B fallback) ----------------
__global__ __launch_bounds__(256) void histo_sniff(const int* __restrict__ row, const int* __restrict__ col,
                                                   int* __restrict__ cntc, int* __restrict__ cntr, int E,
                                                   const unsigned int* __restrict__ x,
                                                   const void* __restrict__ jkwb,
                                                   float* __restrict__ meta) {
    if (blockIdx.x == gridDim.x - 1) {
        sniff_body(x, jkwb, meta);
        return;
    }
    int e = blockIdx.x * 256 + threadIdx.x;
    if (e < E) {
        atomicAdd(&cntc[col[e]], 1);
        atomicAdd(&cntr[row[e]], 1);
    }
}

__global__ __launch_bounds__(256) void scan_bsum(const int* __restrict__ c0, const int* __restrict__ c1,
                                                 int* __restrict__ b0, int* __restrict__ b1, int N) {
    const int* cnt = blockIdx.y ? c1 : c0;
    int* bs = blockIdx.y ? b1 : b0;
    int base = blockIdx.x * 1024 + threadIdx.x * 4;
    int s = 0;
    if (base + 3 < N) {
        int4 v = *(const int4*)&cnt[base];
        s = v.x + v.y + v.z + v.w;
    } else {
        for (int i = 0; i < 4; i++) if (base + i < N) s += cnt[base + i];
    }
    __shared__ int red[256];
    red[threadIdx.x] = s;
    __syncthreads();
    for (int d = 128; d > 0; d >>= 1) {
        if (threadIdx.x < d) red[threadIdx.x] += red[threadIdx.x + d];
        __syncthreads();
    }
    if (threadIdx.x == 0) bs[blockIdx.x] = red[0];
}

__global__ __launch_bounds__(256) void scan_bsum_scan(int* __restrict__ b0, int* __restrict__ b1,
                                                      int* __restrict__ offN0, int* __restrict__ offN1,
                                                      int nb) {
    int* bs = blockIdx.x ? b1 : b0;
    int* offN = blockIdx.x ? offN1 : offN0;
    __shared__ int sh[256];
    int t = threadIdx.x;
    int v = (t < nb) ? bs[t] : 0;
    sh[t] = v;
    __syncthreads();
    for (int d = 1; d < 256; d <<= 1) {
        int u = (t >= d) ? sh[t - d] : 0;
        __syncthreads();
        sh[t] += u;
        __syncthreads();
    }
    if (t < nb) bs[t] = (t == 0) ? 0 : sh[t - 1];
    if (t == 255) *offN = sh[255];
}

// scan_final also produces dinv = rsqrt(1+cntc) (y==0 branch).
__global__ __launch_bounds__(256) void scan_final(const int* __restrict__ c0, const int* __restrict__ c1,
                                                  const int* __restrict__ b0, const int* __restrict__ b1,
                                                  int* __restrict__ o0, int* __restrict__ u0,
                                                  int* __restrict__ o1, int* __restrict__ u1,
                                                  float* __restrict__ dinvp, int N) {
    const int* cnt = blockIdx.y ? c1 : c0;
    const int* bs  = blockIdx.y ? b1 : b0;
    int* off = blockIdx.y ? o1 : o0;
    int* cur = blockIdx.y ? u1 : u0;
    int t = threadIdx.x;
    int base = blockIdx.x * 1024 + t * 4;
    int4 v = {0, 0, 0, 0};
    if (base + 3 < N) {
        v = *(const int4*)&cnt[base];
    } else {
        int tmp[4] = {0, 0, 0, 0};
        for (int i = 0; i < 4; i++) if (base + i < N) tmp[i] = cnt[base + i];
        v.x = tmp[0]; v.y = tmp[1]; v.z = tmp[2]; v.w = tmp[3];
    }
    if (blockIdx.y == 0) {
        if (base + 3 < N) {
            float4 dv;
            dv.x = rsqrtf(1.0f + (float)v.x);
            dv.y = rsqrtf(1.0f + (float)v.y);
            dv.z = rsqrtf(1.0f + (float)v.z);
            dv.w = rsqrtf(1.0f + (float)v.w);
            *(float4*)&dinvp[base] = dv;
        } else {
            int vv[4] = {v.x, v.y, v.z, v.w};
            for (int i = 0; i < 4; i++)
                if (base + i < N) dinvp[base + i] = rsqrtf(1.0f + (float)vv[i]);
        }
    }
    int s = v.x + v.y + v.z + v.w;
    __shared__ int sh[256];
    sh[t] = s;
    __syncthreads();
    for (int d = 1; d < 256; d <<= 1) {
        int u = (t >= d) ? sh[t - d] : 0;
        __syncthreads();
        sh[t] += u;
        __syncthreads();
    }
    int ex = bs[blockIdx.x] + ((t == 0) ? 0 : sh[t - 1]);
    int4 o;
    o.x = ex; o.y = ex + v.x; o.z = o.y + v.y; o.w = o.z + v.z;
    if (base + 3 < N) {
        *(int4*)&off[base] = o;
        *(int4*)&cur[base] = o;
    } else {
        int arr[4] = {o.x, o.y, o.z, o.w};
        for (int i = 0; i < 4; i++) if (base + i < N) { off[base + i] = arr[i]; cur[base + i] = arr[i]; }
    }
}

__global__ __launch_bounds__(256) void scatter_tile(const int* __restrict__ row, const int* __restrict__ col,
                                                    int* __restrict__ curc, int* __restrict__ curr,
                                                    u16* __restrict__ ecol, u16* __restrict__ erow,
                                                    int E, int lo, int hi, int doRow) {
    int e = blockIdx.x * 256 + threadIdx.x;
    if (e >= E) return;
    int s = row[e], d = col[e];
    if (d >= lo && d < hi) {
        int p = atomicAdd(&curc[d], 1);
        ecol[p] = (u16)s;
    }
    if (doRow && s >= lo && s < hi) {
        int q = atomicAdd(&curr[s], 1);
        erow[q] = (u16)d;
    }
}

// ---------------- W prepack (W1/W2/W3/Wfc in one launch: 16+8+8+4 blocks) ----------------
__global__ __launch_bounds__(256) void pack_all(const void* __restrict__ W1,
                                                const void* __restrict__ W2,
                                                const void* __restrict__ W3,
                                                const void* __restrict__ Wf,
                                                u16* __restrict__ Wp1,
                                                u16* __restrict__ Wp2,
                                                u16* __restrict__ Wp3,
                                                u16* __restrict__ Wfp,
                                                const int* __restrict__ flagp) {
    int bid = blockIdx.x;
    const void* W; u16* Wp; int K, C, gid;
    if (bid < 16)      { W = W1; Wp = Wp1; K = 256; C = 128; gid = bid * 256 + threadIdx.x; }
    else if (bid < 24) { W = W2; Wp = Wp2; K = 128; C = 128; gid = (bid - 16) * 256 + threadIdx.x; }
    else if (bid < 32) { W = W3; Wp = Wp3; K = 128; C = 128; gid = (bid - 24) * 256 + threadIdx.x; }
    else               { W = Wf; Wp = Wfp; K = 128; C = 64;  gid = (bid - 32) * 256 + threadIdx.x; }
    int tiles = C >> 4;
    int steps = K >> 5;
    if (gid >= steps * tiles * 64) return;
    int isbf = *flagp;
    int lane = gid & 63;
    int tt = (gid >> 6) % tiles;
    int s = (gid >> 6) / tiles;
    int krow = s * 32 + ((lane >> 4) << 3);
    int ncol = tt * 16 + (lane & 15);
#pragma unroll
    for (int j = 0; j < 8; j++) {
        float v = dload(W, (size_t)(krow + j) * C + ncol, isbf);
        Wp[(size_t)gid * 8 + j] = f2bf(v);
    }
}

// ---------------- MFMA GEMM body (global A) ----------------
template <int K, bool RTBF, bool BFIN, bool SCALE>
__device__ __forceinline__ void gemm_mfma_body(int bid, const void* __restrict__ Xv,
                                               const u16* __restrict__ Wp,
                                               u16* __restrict__ Cb,
                                               const float* __restrict__ dinv,
                                               const int* __restrict__ flagp, int M) {
    const int isbf = RTBF ? *flagp : (BFIN ? 1 : 0);
    const int tid = threadIdx.x;
    const int wave = tid >> 6, lane = tid & 63;
    const int m16 = lane & 15, quad = lane >> 4;
    const int row = bid * 64 + wave * 16 + m16;
    constexpr int STEPS = K / 32;

    float4v acc[8];
#pragma unroll
    for (int t = 0; t < 8; t++) acc[t] = (float4v){0.f, 0.f, 0.f, 0.f};

    const bool rowOK = row < M;
#pragma unroll
    for (int s = 0; s < STEPS; s++) {
        int k0 = s * 32 + quad * 8;
        short8 a = (short8)(short)0;
        if (rowOK) {
            if (isbf) {
                a = *(const short8*)((const u16*)Xv + (size_t)row * K + k0);
            } else {
                const float* p = (const float*)Xv + (size_t)row * K + k0;
                float4 f0 = *(const float4*)p;
                float4 f1 = *(const float4*)(p + 4);
                a[0] = (short)f2bf(f0.x); a[1] = (short)f2bf(f0.y);
                a[2] = (short)f2bf(f0.z); a[3] = (short)f2bf(f0.w);
                a[4] = (short)f2bf(f1.x); a[5] = (short)f2bf(f1.y);
                a[6] = (short)f2bf(f1.z); a[7] = (short)f2bf(f1.w);
            }
        }
#pragma unroll
        for (int t = 0; t < 8; t++) {
            short8 b = *(const short8*)(Wp + ((size_t)(s * 8 + t) * 64 + lane) * 8);
            acc[t] = __builtin_amdgcn_mfma_f32_16x16x32_bf16(a, b, acc[t], 0, 0, 0);
        }
    }
#pragma unroll
    for (int r = 0; r < 4; r++) {
        int gr = bid * 64 + wave * 16 + quad * 4 + r;
        if (gr < M) {
            float sc = SCALE ? dinv[gr] : 1.0f;
#pragma unroll
            for (int t = 0; t < 8; t++) {
                size_t o = (size_t)gr * H_FEATS + t * 16 + m16;
                Cb[o] = f2bf(sc * acc[t][r]);
            }
        }
    }
}

template <int K, bool RTBF, bool BFIN, bool SCALE>
__global__ __launch_bounds__(256) void gemm_mfma(const void* __restrict__ Xv,
                                                 const u16* __restrict__ Wp,
                                                 u16* __restrict__ Cb,
                                                 const float* __restrict__ dinv,
                                                 const int* __restrict__ flagp, int M) {
    gemm_mfma_body<K, RTBF, BFIN, SCALE>(blockIdx.x, Xv, Wp, Cb, dinv, flagp, M);
}

// ---------------- fused: scatter (blocks [0,NSC)) + gemm L0 (rest) ----------------
__global__ __launch_bounds__(256) void scatter_gemm0(const int* __restrict__ row,
                                                     const int* __restrict__ col,
                                                     const unsigned* __restrict__ partC,
                                                     const unsigned* __restrict__ partR,
                                                     u16* __restrict__ ecol,
                                                     u16* __restrict__ erow,
                                                     int E, int N,
                                                     const void* __restrict__ Xv,
                                                     const u16* __restrict__ Wp,
                                                     u16* __restrict__ Pb,
                                                     const float* __restrict__ dinv,
                                                     const int* __restrict__ flagp) {
    __shared__ unsigned cur[8192];
    if (blockIdx.x < CSR_NSC) {
        scatter_body(blockIdx.x, row, col, partC, partR, ecol, erow, E, N, cur);
    } else {
        gemm_mfma_body<256, true, false, true>(blockIdx.x - CSR_NSC, Xv, Wp, Pb, dinv, flagp, N);
    }
}

// ---------------- standalone tier-0 gather (L0): 32-lane/8B, depth-4 (proven) ----------------
__global__ __launch_bounds__(256) void agg_sum(const int* __restrict__ off,
                                               const u16* __restrict__ idx,
                                               const float* __restrict__ dinv,
                                               const u16* __restrict__ Pb,
                                               const void* __restrict__ bv,
                                               u16* __restrict__ hout,
                                               const int* __restrict__ flagp, int N) {
    int node = blockIdx.x * 8 + (threadIdx.x >> 5);
    if (node >= N) return;
    int l = threadIdx.x & 31;
    int isbf = *flagp;
    int beg = off[node], end = off[node + 1];
    size_t ro = (size_t)l * 4;

    float4 acc = load4bf(&Pb[(size_t)node * H_FEATS + ro]);

    const float4 z = {0.f, 0.f, 0.f, 0.f};
    int i = beg;
    int s0 = (i     < end) ? (int)idx[i]     : 0;
    int s1 = (i + 1 < end) ? (int)idx[i + 1] : 0;
    int s2 = (i + 2 < end) ? (int)idx[i + 2] : 0;
    int s3 = (i + 3 < end) ? (int)idx[i + 3] : 0;
    float4 h0 = (i     < end) ? load4bf(&Pb[(size_t)s0 * H_FEATS + ro]) : z;
    float4 h1 = (i + 1 < end) ? load4bf(&Pb[(size_t)s1 * H_FEATS + ro]) : z;
    float4 h2 = (i + 2 < end) ? load4bf(&Pb[(size_t)s2 * H_FEATS + ro]) : z;
    float4 h3 = (i + 3 < end) ? load4bf(&Pb[(size_t)s3 * H_FEATS + ro]) : z;
    for (; i + 4 < end; i += 4) {
        int t0 = (int)idx[i + 4];
        int t1 = (i + 5 < end) ? (int)idx[i + 5] : 0;
        int t2 = (i + 6 < end) ? (int)idx[i + 6] : 0;
        int t3 = (i + 7 < end) ? (int)idx[i + 7] : 0;
        float4 n0 = load4bf(&Pb[(size_t)t0 * H_FEATS + ro]);
        float4 n1 = (i + 5 < end) ? load4bf(&Pb[(size_t)t1 * H_FEATS + ro]) : z;
        float4 n2 = (i + 6 < end) ? load4bf(&Pb[(size_t)t2 * H_FEATS + ro]) : z;
        float4 n3 = (i + 7 < end) ? load4bf(&Pb[(size_t)t3 * H_FEATS + ro]) : z;
        acc.x += (h0.x + h1.x) + (h2.x + h3.x);
        acc.y += (h0.y + h1.y) + (h2.y + h3.y);
        acc.z += (h0.z + h1.z) + (h2.z + h3.z);
        acc.w += (h0.w + h1.w) + (h2.w + h3.w);
        h0 = n0; h1 = n1; h2 = n2; h3 = n3;
    }
    acc.x += (h0.x + h1.x) + (h2.x + h3.x);
    acc.y += (h0.y + h1.y) + (h2.y + h3.y);
    acc.z += (h0.z + h1.z) + (h2.z + h3.z);
    acc.w += (h0.w + h1.w) + (h2.w + h3.w);

    float dd = dinv[node];
    acc.x = fmaxf(fmaf(dd, acc.x, dload(bv, l * 4 + 0, isbf)), 0.0f);
    acc.y = fmaxf(fmaf(dd, acc.y, dload(bv, l * 4 + 1, isbf)), 0.0f);
    acc.z = fmaxf(fmaf(dd, acc.z, dload(bv, l * 4 + 2, isbf)), 0.0f);
    acc.w = fmaxf(fmaf(dd, acc.w, dload(bv, l * 4 + 3, isbf)), 0.0f);
    uint2 pk;
    pk.x = (unsigned)f2bf(acc.x) | ((unsigned)f2bf(acc.y) << 16);
    pk.y = (unsigned)f2bf(acc.z) | ((unsigned)f2bf(acc.w) << 16);
    *(uint2*)&hout[(size_t)node * H_FEATS + ro] = pk;
}

// ---------------- fused gather-tile helper: 16 lanes/row, uint4, depth-4 ----------------
// MODE 0 = AGG (self + sum, dinv scale, bias, relu); MODE 1 = MEAN (out-nbr mean, self fallback)
template <int MODE, bool WRITEG>
__device__ __forceinline__ void gather_tile(int bid,
                                            const int* __restrict__ off,
                                            const u16* __restrict__ idx,
                                            const float* __restrict__ dinv,
                                            const u16* __restrict__ Src,
                                            const void* __restrict__ bv, int isbf,
                                            u16* __restrict__ Hg,
                                            u16* __restrict__ tile, int N) {
    int lane16 = threadIdx.x & 15;
    int rloc = threadIdx.x >> 4;
    int co = lane16 * 8;
    const uint4 zz = {0u, 0u, 0u, 0u};
#pragma unroll
    for (int pass = 0; pass < 4; ++pass) {
        int r = pass * 16 + rloc;
        int gr = bid * 64 + r;
        uint4* ldst = (uint4*)(tile + (size_t)r * TPAD + co);
        if (gr >= N) { *ldst = zz; continue; }
        int beg = off[gr], end = off[gr + 1];
        float acc[8];
        if (MODE == 0) {
            uint4 u = *(const uint4*)(Src + (size_t)gr * H_FEATS + co);
            set8(acc, u);
        } else {
#pragma unroll
            for (int j = 0; j < 8; j++) acc[j] = 0.0f;
        }
        int i = beg;
        int s0 = (i     < end) ? (int)idx[i]     : 0;
        int s1 = (i + 1 < end) ? (int)idx[i + 1] : 0;
        int s2 = (i + 2 < end) ? (int)idx[i + 2] : 0;
        int s3 = (i + 3 < end) ? (int)idx[i + 3] : 0;
        uint4 h0 = (i     < end) ? *(const uint4*)(Src + (size_t)s0 * H_FEATS + co) : zz;
        uint4 h1 = (i + 1 < end) ? *(const uint4*)(Src + (size_t)s1 * H_FEATS + co) : zz;
        uint4 h2 = (i + 2 < end) ? *(const uint4*)(Src + (size_t)s2 * H_FEATS + co) : zz;
        uint4 h3 = (i + 3 < end) ? *(const uint4*)(Src + (size_t)s3 * H_FEATS + co) : zz;
        for (; i + 4 < end; i += 4) {
            int t0 = (int)idx[i + 4];
            int t1 = (i + 5 < end) ? (int)idx[i + 5] : 0;
            int t2 = (i + 6 < end) ? (int)idx[i + 6] : 0;
            int t3 = (i + 7 < end) ? (int)idx[i + 7] : 0;
            uint4 n0 = *(const uint4*)(Src + (size_t)t0 * H_FEATS + co);
            uint4 n1 = (i + 5 < end) ? *(const uint4*)(Src + (size_t)t1 * H_FEATS + co) : zz;
            uint4 n2 = (i + 6 < end) ? *(const uint4*)(Src + (size_t)t2 * H_FEATS + co) : zz;
            uint4 n3 = (i + 7 < end) ? *(const uint4*)(Src + (size_t)t3 * H_FEATS + co) : zz;
            add8(acc, h0); add8(acc, h1); add8(acc, h2); add8(acc, h3);
            h0 = n0; h1 = n1; h2 = n2; h3 = n3;
        }
        add8(acc, h0); add8(acc, h1); add8(acc, h2); add8(acc, h3);

        if (MODE == 0) {
            float dd = dinv[gr];
#pragma unroll
            for (int j = 0; j < 8; j++)
                acc[j] = fmaxf(fmaf(dd, acc[j], dload(bv, co + j, isbf)), 0.0f);
        } else {
            int cnt = end - beg;
            if (cnt > 0) {
                float inv = 1.0f / (float)cnt;
#pragma unroll
                for (int j = 0; j < 8; j++) acc[j] *= inv;
            } else {
                uint4 u = *(const uint4*)(Src + (size_t)gr * H_FEATS + co);
                set8(acc, u);
            }
        }
        uint4 pk = pack8(acc);
        *ldst = pk;
        if (WRITEG) *(uint4*)(Hg + (size_t)gr * H_FEATS + co) = pk;
    }
}

// ---------------- MFMA GEMM phase with A from LDS tile (K=128) ----------------
__device__ __forceinline__ void gemm_lds_body(int bid, const u16* __restrict__ tile,
                                              const u16* __restrict__ Wp,
                                              u16* __restrict__ Cb,
                                              const float* __restrict__ dinv, int M) {
    const int tid = threadIdx.x;
    const int wave = tid >> 6, lane = tid & 63;
    const int m16 = lane & 15, quad = lane >> 4;
    const int lrow = wave * 16 + m16;

    float4v acc[8];
#pragma unroll
    for (int t = 0; t < 8; t++) acc[t] = (float4v){0.f, 0.f, 0.f, 0.f};

#pragma unroll
    for (int s = 0; s < 4; s++) {
        int k0 = s * 32 + quad * 8;
        short8 a = *(const short8*)(tile + (size_t)lrow * TPAD + k0);
#pragma unroll
        for (int t = 0; t < 8; t++) {
            short8 b = *(const short8*)(Wp + ((size_t)(s * 8 + t) * 64 + lane) * 8);
            acc[t] = __builtin_amdgcn_mfma_f32_16x16x32_bf16(a, b, acc[t], 0, 0, 0);
        }
    }
#pragma unroll
    for (int r = 0; r < 4; r++) {
        int gr = bid * 64 + wave * 16 + quad * 4 + r;
        if (gr < M) {
            float sc = dinv[gr];
#pragma unroll
            for (int t = 0; t < 8; t++) {
                size_t o = (size_t)gr * H_FEATS + t * 16 + m16;
                Cb[o] = f2bf(sc * acc[t][r]);
            }
        }
    }
}

// ---------------- fused gather + gemm (tier 0, layers 1/2) ----------------
template <int MODE>
__global__ __launch_bounds__(256) void agg_gemm(const int* __restrict__ off,
                                                const u16* __restrict__ idx,
                                                const float* __restrict__ dinv,
                                                const u16* __restrict__ Src,
                                                const void* __restrict__ bv,
                                                const u16* __restrict__ Wp,
                                                u16* __restrict__ Hg,
                                                u16* __restrict__ Pnext,
                                                const int* __restrict__ flagp, int N) {
    __shared__ u16 tile[64 * TPAD];
    gather_tile<MODE, true>(blockIdx.x, off, idx, dinv, Src, bv, *flagp, Hg, tile, N);
    __syncthreads();
    gemm_lds_body(blockIdx.x, tile, Wp, Pnext, dinv, N);
}

// ---------------- fused gather + jk + MFMA fc (tier 0, last layer) ----------------
__global__ __launch_bounds__(256) void agg_fc3(const int* __restrict__ off,
                                               const u16* __restrict__ idx,
                                               const float* __restrict__ dinv,
                                               const u16* __restrict__ Src,
                                               const void* __restrict__ bv3,
                                               const u16* __restrict__ H0,
                                               const u16* __restrict__ H1,
                                               const u16* __restrict__ Wfp,
                                               const void* __restrict__ bv,
                                               void* __restrict__ Outv,
                                               const float* __restrict__ meta, int N) {
    __shared__ u16 tile[64 * TPAD];
    const int isbf = ((const int*)meta)[0];
    gather_tile<0, false>(blockIdx.x, off, idx, dinv, Src, bv3, isbf, (u16*)0, tile, N);
    __syncthreads();

    const float w0 = meta[8], w1 = meta[9], w2 = meta[10];
    const int tid = threadIdx.x;
    const int wave = tid >> 6, lane = tid & 63;
    const int m16 = lane & 15, quad = lane >> 4;
    const int lrow = wave * 16 + m16;
    const int gr0 = blockIdx.x * 64 + lrow;

    float4v acc[4];
#pragma unroll
    for (int t = 0; t < 4; t++) acc[t] = (float4v){0.f, 0.f, 0.f, 0.f};

#pragma unroll
    for (int s = 0; s < 4; s++) {
        int k0 = s * 32 + quad * 8;
        short8 a = (short8)(short)0;
        if (gr0 < N) {
            float f0[8], f1[8], f2[8];
            uint4 u0 = *(const uint4*)(H0 + (size_t)gr0 * H_FEATS + k0);
            uint4 u1 = *(const uint4*)(H1 + (size_t)gr0 * H_FEATS + k0);
            uint4 tv = *(const uint4*)(tile + (size_t)lrow * TPAD + k0);
            set8(f0, u0); set8(f1, u1); set8(f2, tv);
#pragma unroll
            for (int j = 0; j < 8; j++)
                a[j] = (short)f2bf(w0 * f0[j] + w1 * f1[j] + w2 * f2[j]);
        }
#pragma unroll
        for (int t = 0; t < 4; t++) {
            short8 b = *(const short8*)(Wfp + ((size_t)(s * 4 + t) * 64 + lane) * 8);
            acc[t] = __builtin_amdgcn_mfma_f32_16x16x32_bf16(a, b, acc[t], 0, 0, 0);
        }
    }

    __hip_bfloat16* ob = (__hip_bfloat16*)Outv;
    float* of = (float*)Outv;
#pragma unroll
    for (int r = 0; r < 4; r++) {
        int gr = blockIdx.x * 64 + wave * 16 + quad * 4 + r;
        if (gr < N) {
#pragma unroll
            for (int t = 0; t < 4; t++) {
                int c = t * 16 + m16;
                size_t o = (size_t)gr * 64 + c;
                float v = acc[t][r] + dload(bv, c, isbf);
                if (isbf) ob[o] = __float2bfloat16(v); else of[o] = v;
            }
        }
    }
}

// ---------------- weighted gather (tier B only) ----------------
template <bool BF16OUT>
__global__ __launch_bounds__(256) void agg_gather3b(const int* __restrict__ off,
                                                    const u16* __restrict__ idx,
                                                    const float* __restrict__ dinv,
                                                    const u16* __restrict__ Hb,
                                                    const void* __restrict__ bv,
                                                    void* __restrict__ houtv,
                                                    const int* __restrict__ flagp, int N) {
    int node = blockIdx.x * 8 + (threadIdx.x >> 5);
    if (node >= N) return;
    int l = threadIdx.x & 31;
    int isbf = *flagp;
    int beg = off[node], end = off[node + 1];
    float dd = dinv[node];
    size_t ro = (size_t)l * 4;

    float4 self = load4bf(&Hb[(size_t)node * H_FEATS + ro]);
    float w0s = dd * dd;
    float4 acc = {w0s * self.x, w0s * self.y, w0s * self.z, w0s * self.w};

    int i = beg;
    int s0 = (i < end) ? (int)idx[i] : 0;
    float4 h0 = (i < end) ? load4bf(&Hb[(size_t)s0 * H_FEATS + ro])
                          : (float4){0.f, 0.f, 0.f, 0.f};
    for (; i < end; i++) {
        int s1 = (i + 1 < end) ? (int)idx[i + 1] : 0;
        float4 h1 = (i + 1 < end) ? load4bf(&Hb[(size_t)s1 * H_FEATS + ro]) : h0;
        float w = dinv[s0] * dd;
        acc.x = fmaf(w, h0.x, acc.x);
        acc.y = fmaf(w, h0.y, acc.y);
        acc.z = fmaf(w, h0.z, acc.z);
        acc.w = fmaf(w, h0.w, acc.w);
        s0 = s1; h0 = h1;
    }
    acc.x = fmaxf(acc.x + dload(bv, l * 4 + 0, isbf), 0.0f);
    acc.y = fmaxf(acc.y + dload(bv, l * 4 + 1, isbf), 0.0f);
    acc.z = fmaxf(acc.z + dload(bv, l * 4 + 2, isbf), 0.0f);
    acc.w = fmaxf(acc.w + dload(bv, l * 4 + 3, isbf), 0.0f);
    if (BF16OUT) {
        u16* hb = (u16*)houtv;
        uint2 pk;
        pk.x = (unsigned)f2bf(acc.x) | ((unsigned)f2bf(acc.y) << 16);
        pk.y = (unsigned)f2bf(acc.z) | ((unsigned)f2bf(acc.w) << 16);
        *(uint2*)&hb[(size_t)node * H_FEATS + ro] = pk;
    } else {
        *(float4*)&((float*)houtv)[(size_t)node * H_FEATS + ro] = acc;
    }
}

// ---------------- fp32 GEMM (tier C) ----------------
template <int K, bool XIN, bool GATEBF, bool BF16OUT>
__global__ __launch_bounds__(256) void gemm128(const void* __restrict__ Xv,
                                               const void* __restrict__ Wv,
                                               void* __restrict__ Cv,
                                               const int* __restrict__ flagp, int N) {
    constexpr int BM = 64, BK = 16, BN = 128, TN = 8, TX = BN / TN;
    __shared__ float Xs[BK][BM + 4];
    __shared__ float Ws[BK][BN];
    const int isbf = *flagp;
    if (GATEBF && isbf != 1) return;
    const float* Xf = (const float*)Xv;

    const int tid = threadIdx.x;
    const int tx = tid % TX;
    const int ty = tid / TX;
    const int rowBase = blockIdx.x * BM;

    float acc[4][TN] = {};
    const int lk = tid % BK;
    const int lr0 = tid / BK;

    for (int kb = 0; kb < K; kb += BK) {
#pragma unroll
        for (int i = 0; i < 4; i++) {
            int r = lr0 + i * 16;
            int gr = rowBase + r;
            float v = 0.0f;
            if (gr < N) {
                size_t idx = (size_t)gr * K + kb + lk;
                v = XIN ? dload(Xv, idx, isbf) : Xf[idx];
            }
            Xs[lk][r] = v;
        }
#pragma unroll
        for (int i = 0; i < 8; i++) {
            int idx = i * 256 + tid;
            int k = idx >> 7, c = idx & 127;
            Ws[k][c] = dload(Wv, (size_t)(kb + k) * BN + c, isbf);
        }
        __syncthreads();
#pragma unroll
        for (int k = 0; k < BK; k++) {
            float4 a = *(const float4*)&Xs[k][ty * 4];
            float av[4] = {a.x, a.y, a.z, a.w};
            float4 b0 = *(const float4*)&Ws[k][tx * TN];
            float4 b1 = *(const float4*)&Ws[k][tx * TN + 4];
            float bv[8] = {b0.x, b0.y, b0.z, b0.w, b1.x, b1.y, b1.z, b1.w};
#pragma unroll
            for (int i = 0; i < 4; i++)
#pragma unroll
                for (int j = 0; j < TN; j++) acc[i][j] = fmaf(av[i], bv[j], acc[i][j]);
        }
        __syncthreads();
    }
#pragma unroll
    for (int i = 0; i < 4; i++) {
        int gr = rowBase + ty * 4 + i;
        if (gr < N) {
#pragma unroll
            for (int j = 0; j < TN; j++) {
                size_t o = (size_t)gr * BN + tx * TN + j;
                if (BF16OUT) ((u16*)Cv)[o] = f2bf(acc[i][j]);
                else         ((float*)Cv)[o] = acc[i][j];
            }
        }
    }
}

template <bool FIRST, bool LAST, bool BFIN>
__global__ __launch_bounds__(256) void fc_accum(const void* __restrict__ Hmv,
                                                const void* __restrict__ Wv,
                                                const void* __restrict__ bv,
                                                void* __restrict__ Outv,
                                                const float* __restrict__ meta,
                                                int widx, int N) {
    constexpr int BM = 64, BK = 16, BN = 64, TN = 4, TX = BN / TN, K = 128;
    __shared__ float Xs[BK][BM + 4];
    __shared__ float Ws[BK][BN];
    const int isbf = ((const int*)meta)[0];
    const float scale = meta[8 + widx];

    const int tid = threadIdx.x;
    const int tx = tid % TX;
    const int ty = tid / TX;
    const int rowBase = blockIdx.x * BM;

    float acc[4][TN] = {};
    const int lk = tid % BK;
    const int lr0 = tid / BK;

    for (int kb = 0; kb < K; kb += BK) {
#pragma unroll
        for (int i = 0; i < 4; i++) {
            int r = lr0 + i * 16;
            int gr = rowBase + r;
            float v = 0.0f;
            if (gr < N) {
                size_t idx = (size_t)gr * K + kb + lk;
                if (BFIN) v = bf2f(((const u16*)Hmv)[idx]);
                else      v = ((const float*)Hmv)[idx];
            }
            Xs[lk][r] = v;
        }
#pragma unroll
        for (int i = 0; i < 4; i++) {
            int idx = i * 256 + tid;
            int k = idx >> 6, c = idx & 63;
            Ws[k][c] = dload(Wv, (size_t)(kb + k) * BN + c, isbf);
        }
        __syncthreads();
#pragma unroll
        for (int k = 0; k < BK; k++) {
            float4 a = *(const float4*)&Xs[k][ty * 4];
            float av[4] = {a.x, a.y, a.z, a.w};
            float4 bb = *(const float4*)&Ws[k][tx * TN];
            float bvv[4] = {bb.x, bb.y, bb.z, bb.w};
#pragma unroll
            for (int i = 0; i < 4; i++)
#pragma unroll
                for (int j = 0; j < TN; j++) acc[i][j] = fmaf(av[i], bvv[j], acc[i][j]);
        }
        __syncthreads();
    }
    __hip_bfloat16* ob = (__hip_bfloat16*)Outv;
    float* of = (float*)Outv;
#pragma unroll
    for (int i = 0; i < 4; i++) {
        int gr = rowBase + ty * 4 + i;
        if (gr < N) {
#pragma unroll
            for (int j = 0; j < TN; j++) {
                int c = tx * TN + j;
                size_t o = (size_t)gr * BN + c;
                float v = scale * acc[i][j];
                if (!FIRST) v += isbf ? __bfloat162float(ob[o]) : of[o];
                if (LAST) v += dload(bv, c, isbf);
                if (isbf) ob[o] = __float2bfloat16(v); else of[o] = v;
            }
        }
    }
}

// ---------------- atomic fallbacks (tier B / C) ----------------
__global__ __launch_bounds__(256) void init_deg(float* deg, float* odeg, int N) {
    int i = blockIdx.x * 256 + threadIdx.x;
    if (i < N) { deg[i] = 1.0f; odeg[i] = 0.0f; }
}
__global__ __launch_bounds__(256) void count_deg(const int* __restrict__ row, const int* __restrict__ col,
                                                 float* deg, float* odeg, int E) {
    int e = blockIdx.x * 256 + threadIdx.x;
    if (e < E) {
        atomicAdd(&deg[col[e]], 1.0f);
        atomicAdd(&odeg[row[e]], 1.0f);
    }
}
__global__ __launch_bounds__(256) void deg_to_dinv(float* deg, int N) {
    int i = blockIdx.x * 256 + threadIdx.x;
    if (i < N) deg[i] = rsqrtf(deg[i]);
}
__global__ __launch_bounds__(256) void agg_edges(const int* __restrict__ row, const int* __restrict__ col,
                                                 const float* __restrict__ dinv,
                                                 const float* __restrict__ H,
                                                 float* __restrict__ agg, int E) {
    int e = blockIdx.x * 2 + (threadIdx.x >> 7);
    if (e >= E) return;
    int j = threadIdx.x & 127;
    int s = row[e], d = col[e];
    float w = dinv[s] * dinv[d];
    atomicAdd(&agg[(size_t)d * H_FEATS + j], w * H[(size_t)s * H_FEATS + j]);
}
__global__ __launch_bounds__(256) void mean_edges(const int* __restrict__ row, const int* __restrict__ col,
                                                  const float* __restrict__ h0pre,
                                                  float* __restrict__ nsum, int E) {
    int e = blockIdx.x * 2 + (threadIdx.x >> 7);
    if (e >= E) return;
    int j = threadIdx.x & 127;
    int r = row[e], c = col[e];
    atomicAdd(&nsum[(size_t)r * H_FEATS + j], h0pre[(size_t)c * H_FEATS + j]);
}
__global__ __launch_bounds__(256) void finalize_layer(const float* __restrict__ agg,
                                                      const float* __restrict__ H,
                                                      const float* __restrict__ dinv,
                                                      const void* __restrict__ bv,
                                                      float* __restrict__ hout,
                                                      const int* __restrict__ flagp, int NH) {
    int idx = blockIdx.x * 256 + threadIdx.x;
    if (idx >= NH) return;
    int isbf = *flagp;
    int v = idx >> 7, j = idx & 127;
    float di = dinv[v];
    float h = fmaf(di * di, H[idx], agg[idx]) + dload(bv, j, isbf);
    hout[idx] = fmaxf(h, 0.0f);
}
__global__ __launch_bounds__(256) void finalize_mean(const float* __restrict__ nsum,
                                                     const float* __restrict__ h0pre,
                                                     const float* __restrict__ odeg,
                                                     float* __restrict__ h0, int NH) {
    int idx = blockIdx.x * 256 + threadIdx.x;
    if (idx >= NH) return;
    int v = idx >> 7;
    float od = odeg[v];
    h0[idx] = (od > 0.0f) ? (nsum[idx] / od) : h0pre[idx];
}
__global__ __launch_bounds__(256) void finalize_mean_cnt(const float* __restrict__ nsum,
                                                         const float* __restrict__ h0pre,
                                                         const int* __restrict__ cntr,
                                                         float* __restrict__ h0, int NH) {
    int idx = blockIdx.x * 256 + threadIdx.x;
    if (idx >= NH) return;
    int v = idx >> 7;
    int od = cntr[v];
    h0[idx] = (od > 0) ? (nsum[idx] / (float)od) : h0pre[idx];
}

extern "C" void kernel_launch(void* const* d_in, const int* in_sizes, int n_in,
                              void* d_out, int out_size, void* d_ws, size_t ws_size,
                              hipStream_t stream) {
    const void* x   = d_in[0];
    const int*  ei  = (const int*)d_in[1];
    const void* W1  = d_in[2];
    const void* b1  = d_in[3];
    const void* W2  = d_in[4];
    const void* b2  = d_in[5];
    const void* W3  = d_in[6];
    const void* b3  = d_in[7];
    const void* jkb = d_in[8];
    const void* Wfc = d_in[9];
    const void* bfc = d_in[10];

    const int IN = 256;
    const int N = in_sizes[0] / IN;          // 50000
    const int E = in_sizes[1] / 2;           // 800000
    const int NH = N * H_FEATS;

    const int* row = ei;
    const int* col = ei + E;

    // ---- workspace layout (fp32 words); arrays 16B-aligned ----
    auto a4 = [](size_t v) { return (v + 3) & ~(size_t)3; };
    float* ws = (float*)d_ws;
    size_t o = 0;
    float* meta  = ws + o;           o += 256;
    float* dinv  = ws + o;           o += N;          o = a4(o);
    int*   cntc  = (int*)(ws + o);   o += N;          o = a4(o);
    int*   cntr  = (int*)(ws + o);   o += N;          o = a4(o);
    int*   bsumc = (int*)(ws + o);   o += 256;
    int*   bsumr = (int*)(ws + o);   o += 256;
    int*   coff  = (int*)(ws + o);   o += N + 1;      o = a4(o);
    int*   curc  = (int*)(ws + o);   o += N;          o = a4(o);
    u16*   ecol  = (u16*)(ws + o);   o += E;          o = a4(o);
    size_t oB_small = o;
    int*   roff  = (int*)(ws + o);   o += N + 1;      o = a4(o);
    int*   curr  = (int*)(ws + o);   o += N;          o = a4(o);
    u16*   erow  = (u16*)(ws + o);   o += E;          o = a4(o);
    size_t oA_full = o;

    auto alignup = [](size_t v) { return (v + 63) & ~(size_t)63; };
    const size_t WPW = 16384 + 8192 + 8192 + 4096;   // Wp1 + Wp2 + Wp3 + Wfcp (fp32 words)
    size_t needA = alignup(oA_full) + 2 * (size_t)NH + 64 + WPW;
    size_t needB = alignup(oB_small) + 2 * (size_t)NH + 64 + WPW;

    int tier;
    size_t hoff;
    if (N >= 65536)                { tier = 2; hoff = alignup(256 + 2 * (size_t)N); }
    else if (ws_size >= needA * 4) { tier = 0; hoff = alignup(oA_full); }
    else if (ws_size >= needB * 4) { tier = 1; hoff = alignup(oB_small); }
    else                           { tier = 2; hoff = alignup(256 + 2 * (size_t)N); }
    float* A = ws + hoff;
    float* B = A + NH;
    u16* HbA = (u16*)A;
    u16* HbB = (u16*)B;
    // tier-0 carves four bf16 NH buffers out of the same 2*NH-float region:
    u16* Pb  = (u16*)A;              // P rows (rotating)
    u16* Qb  = Pb + (size_t)NH;      // h0pre, later P2
    u16* H0b = Pb + 2 * (size_t)NH;
    u16* H1b = Pb + 3 * (size_t)NH;
    // CSR-build partials overlay the H0/H1 half (dead until meangemm1):
    // CSR_CH*N*2dirs*4B = 256N B <= H0b..end = 512N B.
    unsigned* partC = (unsigned*)H0b;
    unsigned* partR = partC + (size_t)CSR_CH * N;
    size_t wpoff = alignup(hoff + 2 * (size_t)NH);
    u16* Wp1 = (u16*)(ws + wpoff);
    u16* Wp2 = Wp1 + 32768;
    u16* Wp3 = Wp2 + 16384;
    u16* Wfcp = Wp3 + 16384;
    float* odegf = ws + 256 + N;
    const int* flag = (const int*)meta;

    dim3 blk(256);
    int gN = (N + 255) / 256;
    int gE = (E + 255) / 256;
    int gE2 = (E + 1) / 2;
    int gNH = (NH + 255) / 256;
    int gGemm = (N + 63) / 64;
    int gNode8 = (N + 7) / 8;
    int nb = (N + 1023) / 1024;

    if (tier == 0) {
        // ---- atomic-free CSR build (XCD-local block order) ----
        count_partial<<<CSR_NSC + 1, blk, 0, stream>>>(row, col, partC, partR, E, N,
                                                       (const unsigned int*)x, jkb, meta);
        pack_all<<<36, blk, 0, stream>>>(W1, W2, W3, Wfc, Wp1, Wp2, Wp3, Wfcp, flag);
        reduce_bsum<<<dim3(nb, 2), blk, 0, stream>>>(partC, partR, cntc, cntr, bsumc, bsumr, N);
        scan_bsum_scan<<<2, blk, 0, stream>>>(bsumc, bsumr, &coff[N], &roff[N], nb);
        scan_final<<<dim3(nb, 2), blk, 0, stream>>>(cntc, cntr, bsumc, bsumr,
                                                    coff, curc, roff, curr, dinv, N);
        prefix_partials<<<dim3(gN, 2), blk, 0, stream>>>(partC, partR, coff, roff, N);

        // ---- fused: scatter + layer-0 GEMM (P0 = dinv .* (x@W1)) ----
        scatter_gemm0<<<CSR_NSC + gGemm, blk, 0, stream>>>(row, col, partC, partR, ecol, erow,
                                                           E, N, x, Wp1, Pb, dinv, flag);

        // ---- h0pre = relu(dd*(P0[d]+sum P0[s]) + b1) ----
        agg_sum<<<gNode8, blk, 0, stream>>>(coff, ecol, dinv, Pb, b1, Qb, flag, N);

        // ---- fused mean + gemm1: h0 -> H0b, P1 = dinv.(h0@W2) -> Pb ----
        agg_gemm<1><<<gGemm, blk, 0, stream>>>(roff, erow, dinv, Qb, b1, Wp2, H0b, Pb, flag, N);

        // ---- fused agg + gemm2: h1 -> H1b, P2 = dinv.(h1@W3) -> Qb ----
        agg_gemm<0><<<gGemm, blk, 0, stream>>>(coff, ecol, dinv, Pb, b2, Wp3, H1b, Qb, flag, N);

        // ---- fused agg + jk + MFMA fc: h2 (LDS only) + out ----
        agg_fc3<<<gGemm, blk, 0, stream>>>(coff, ecol, dinv, Qb, b3, H0b, H1b,
                                           Wfcp, bfc, d_out, meta, N);
    } else if (tier == 1) {
        // ---- tier B: legacy atomic CSR build (col only) + fp32 mean path ----
        hipMemsetAsync(cntc, 0, 2 * (size_t)N * 4, stream);
        histo_sniff<<<gE + 1, blk, 0, stream>>>(row, col, cntc, cntr, E,
                                                (const unsigned int*)x, jkb, meta);
        const int T = 4;
        int step = (N + T - 1) / T;
        scan_bsum<<<dim3(nb, 1), blk, 0, stream>>>(cntc, cntc, bsumc, bsumc, N);
        scan_bsum_scan<<<1, blk, 0, stream>>>(bsumc, bsumc, &coff[N], &coff[N], nb);
        scan_final<<<dim3(nb, 1), blk, 0, stream>>>(cntc, cntc, bsumc, bsumc,
                                                    coff, curc, coff, curc, dinv, N);
        for (int t = 0; t < T; t++) {
            int lo = t * step, hi = lo + step; if (hi > N) hi = N;
            scatter_tile<<<gE, blk, 0, stream>>>(row, col, curc, curc, ecol, ecol, E, lo, hi, 0);
        }

        pack_all<<<36, blk, 0, stream>>>(W1, W2, W3, Wfc, Wp1, Wp2, Wp3, Wfcp, flag);

        gemm_mfma<256, true, false, false><<<gGemm, blk, 0, stream>>>(x, Wp1, HbA, dinv, flag, N);
        agg_gather3b<false><<<gNode8, blk, 0, stream>>>(coff, ecol, dinv, HbA, b1, B, flag, N);
        hipMemsetAsync(A, 0, (size_t)NH * 4, stream);
        mean_edges<<<gE2, blk, 0, stream>>>(row, col, B, A, E);
        finalize_mean_cnt<<<gNH, blk, 0, stream>>>(A, B, cntr, A, NH);
        fc_accum<true, false, false><<<gGemm, blk, 0, stream>>>(A, Wfc, bfc, d_out, meta, 0, N);

        gemm_mfma<128, false, false, false><<<gGemm, blk, 0, stream>>>(A, Wp2, HbB, dinv, flag, N);
        agg_gather3b<true><<<gNode8, blk, 0, stream>>>(coff, ecol, dinv, HbB, b2, HbA, flag, N);
        fc_accum<false, false, true><<<gGemm, blk, 0, stream>>>(HbA, Wfc, bfc, d_out, meta, 1, N);

        gemm_mfma<128, false, true, false><<<gGemm, blk, 0, stream>>>(HbA, Wp3, HbB, dinv, flag, N);
        agg_gather3b<true><<<gNode8, blk, 0, stream>>>(coff, ecol, dinv, HbB, b3, HbA, flag, N);
        fc_accum<false, true, true><<<gGemm, blk, 0, stream>>>(HbA, Wfc, bfc, d_out, meta, 2, N);
    } else {
        // ---- tier C: fp32 atomic path ----
        sniff_jkw<<<1, blk, 0, stream>>>((const unsigned int*)x, jkb, meta);
        init_deg<<<gN, blk, 0, stream>>>(dinv, odegf, N);
        count_deg<<<gE, blk, 0, stream>>>(row, col, dinv, odegf, E);
        deg_to_dinv<<<gN, blk, 0, stream>>>(dinv, N);

        gemm128<256, true, false, false><<<gGemm, blk, 0, stream>>>(x, W1, A, flag, N);
        hipMemsetAsync(B, 0, (size_t)NH * 4, stream);
        agg_edges<<<gE2, blk, 0, stream>>>(row, col, dinv, A, B, E);
        finalize_layer<<<gNH, blk, 0, stream>>>(B, A, dinv, b1, B, flag, NH);
        hipMemsetAsync(A, 0, (size_t)NH * 4, stream);
        mean_edges<<<gE2, blk, 0, stream>>>(row, col, B, A, E);
        finalize_mean<<<gNH, blk, 0, stream>>>(A, B, odegf, A, NH);
        fc_accum<true, false, false><<<gGemm, blk, 0, stream>>>(A, Wfc, bfc, d_out, meta, 0, N);

        gemm128<128, false, false, false><<<gGemm, blk, 0, stream>>>(A, W2, B, flag, N);
        hipMemsetAsync(A, 0, (size_t)NH * 4, stream);
        agg_edges<<<gE2, blk, 0, stream>>>(row, col, dinv, B, A, E);
        finalize_layer<<<gNH, blk, 0, stream>>>(A, B, dinv, b2, A, flag, NH);
        fc_accum<false, false, false><<<gGemm, blk, 0, stream>>>(A, Wfc, bfc, d_out, meta, 1, N);

        gemm128<128, false, false, false><<<gGemm, blk, 0, stream>>>(A, W3, B, flag, N);
        hipMemsetAsync(A, 0, (size_t)NH * 4, stream);
        agg_edges<<<gE2, blk, 0, stream>>>(row, col, dinv, B, A, E);
        finalize_layer<<<gNH, blk, 0, stream>>>(A, B, dinv, b3, A, flag, NH);
        fc_accum<false, true, false><<<gGemm, blk, 0, stream>>>(A, Wfc, bfc, d_out, meta, 2, N);
    }
}

// Round 10
// 405.782 us; speedup vs baseline: 1.0411x; 1.0411x over previous
//
#include <hip/hip_runtime.h>
#include <hip/hip_bf16.h>

// DynamicJKGCN on MI355X — round 22: revert CH to 64 + fuse prefix into scan_final.
// Round-21 (422us, regression): CH=32 halved aux traffic (FETCH 41->35MB) but the
// scatter phase lost parallelism (512 blocks, 2/CU, 25K-edge serial scans) -> the
// scatter tail beyond the gemm co-residents doubled; pre-committed revert fired.
// This round: CH=64 (measured best, 411us) + prefix_partials folded into
// scan_final (the exclusive offset 'ex' is already in-register there; walk the
// CH partials vectorized uint4 over 4 nodes/thread). One less launch + off re-read.
// Tier B passes nullptr partials (guarded). Everything else = round 20.

#define H_FEATS 128
#define TPAD 136

typedef __attribute__((ext_vector_type(8))) short short8;
typedef __attribute__((ext_vector_type(4))) float float4v;
typedef unsigned short u16;

__device__ __forceinline__ float dload(const void* p, size_t i, int isbf) {
    return isbf ? __bfloat162float(((const __hip_bfloat16*)p)[i])
                : ((const float*)p)[i];
}

__device__ __forceinline__ float4 load4bf(const u16* p) {
    uint2 u = *(const uint2*)p;
    float4 f;
    f.x = __uint_as_float((u.x & 0xFFFFu) << 16);
    f.y = __uint_as_float(u.x & 0xFFFF0000u);
    f.z = __uint_as_float((u.y & 0xFFFFu) << 16);
    f.w = __uint_as_float(u.y & 0xFFFF0000u);
    return f;
}

__device__ __forceinline__ float bf2f(u16 h) {
    return __uint_as_float((unsigned)h << 16);
}

__device__ __forceinline__ u16 f2bf(float v) {
    return __bfloat16_as_ushort(__float2bfloat16(v));
}

__device__ __forceinline__ void add8(float* a, uint4 u) {
    a[0] += __uint_as_float((u.x & 0xFFFFu) << 16);
    a[1] += __uint_as_float(u.x & 0xFFFF0000u);
    a[2] += __uint_as_float((u.y & 0xFFFFu) << 16);
    a[3] += __uint_as_float(u.y & 0xFFFF0000u);
    a[4] += __uint_as_float((u.z & 0xFFFFu) << 16);
    a[5] += __uint_as_float(u.z & 0xFFFF0000u);
    a[6] += __uint_as_float((u.w & 0xFFFFu) << 16);
    a[7] += __uint_as_float(u.w & 0xFFFF0000u);
}

__device__ __forceinline__ void set8(float* a, uint4 u) {
    a[0] = __uint_as_float((u.x & 0xFFFFu) << 16);
    a[1] = __uint_as_float(u.x & 0xFFFF0000u);
    a[2] = __uint_as_float((u.y & 0xFFFFu) << 16);
    a[3] = __uint_as_float(u.y & 0xFFFF0000u);
    a[4] = __uint_as_float((u.z & 0xFFFFu) << 16);
    a[5] = __uint_as_float(u.z & 0xFFFF0000u);
    a[6] = __uint_as_float((u.w & 0xFFFFu) << 16);
    a[7] = __uint_as_float(u.w & 0xFFFF0000u);
}

__device__ __forceinline__ uint4 pack8(const float* f) {
    uint4 r;
    r.x = (unsigned)f2bf(f[0]) | ((unsigned)f2bf(f[1]) << 16);
    r.y = (unsigned)f2bf(f[2]) | ((unsigned)f2bf(f[3]) << 16);
    r.z = (unsigned)f2bf(f[4]) | ((unsigned)f2bf(f[5]) << 16);
    r.w = (unsigned)f2bf(f[6]) | ((unsigned)f2bf(f[7]) << 16);
    return r;
}

// ---------------- dtype sniff + jk softmax ----------------
__device__ __forceinline__ void sniff_body(const unsigned int* __restrict__ x,
                                           const void* __restrict__ jkwb,
                                           float* __restrict__ meta) {
    __shared__ int cnt[256];
    int t = threadIdx.x;
    int c = 0;
    for (int i = 0; i < 16; i++) {
        unsigned int w = x[t * 16 + i];
        unsigned int e = (w >> 7) & 0xFFu;
        c += (e >= 0x60u && e <= 0x8Fu) ? 1 : 0;
    }
    cnt[t] = c;
    __syncthreads();
    for (int s = 128; s > 0; s >>= 1) {
        if (t < s) cnt[t] += cnt[t + s];
        __syncthreads();
    }
    if (t == 0) {
        int isbf = (cnt[0] > 3000) ? 1 : 0;
        ((int*)meta)[0] = isbf;
        float w0 = dload(jkwb, 0, isbf);
        float w1 = dload(jkwb, 1, isbf);
        float w2 = dload(jkwb, 2, isbf);
        float m = fmaxf(w0, fmaxf(w1, w2));
        float e0 = expf(w0 - m), e1 = expf(w1 - m), e2 = expf(w2 - m);
        float s = e0 + e1 + e2;
        meta[8] = e0 / s; meta[9] = e1 / s; meta[10] = e2 / s;
    }
}

__global__ __launch_bounds__(256) void sniff_jkw(const unsigned int* __restrict__ x,
                                                 const void* __restrict__ jkwb,
                                                 float* __restrict__ meta) {
    sniff_body(x, jkwb, meta);
}

// ---------------- atomic-free CSR build (tier 0) ----------------
#define CSR_CH 64
#define CSR_SL 8
#define CSR_NSC (CSR_CH * CSR_SL * 2)

__global__ __launch_bounds__(256) void count_partial(const int* __restrict__ row,
                                                     const int* __restrict__ col,
                                                     unsigned* __restrict__ partC,
                                                     unsigned* __restrict__ partR,
                                                     int E, int N,
                                                     const unsigned int* __restrict__ x,
                                                     const void* __restrict__ jkwb,
                                                     float* __restrict__ meta) {
    if (blockIdx.x == gridDim.x - 1) {  // piggyback the dtype sniff
        sniff_body(x, jkwb, meta);
        return;
    }
    int b = blockIdx.x;
    int dir = b >> 9;
    int r = b & 511;
    int sl = r >> 6;
    int k  = r & 63;
    const int* arr = dir ? row : col;
    unsigned* part = (dir ? partR : partC) + (size_t)k * N;
    int lo = (int)(((long long)N * sl) >> 3);
    int hi = (int)(((long long)N * (sl + 1)) >> 3);
    int wid = hi - lo;

    __shared__ unsigned cnt[8192];
    for (int i = threadIdx.x; i < wid; i += 256) cnt[i] = 0;
    __syncthreads();

    int e0 = (int)(((long long)E * k) >> 6);
    int e1 = (int)(((long long)E * (k + 1)) >> 6);
    for (int e = e0 + threadIdx.x; e < e1; e += 256) {
        int d = arr[e] - lo;
        if ((unsigned)d < (unsigned)wid) atomicAdd(&cnt[d], 1u);
    }
    __syncthreads();
    for (int i = threadIdx.x; i < wid; i += 256) part[lo + i] = cnt[i];
}

// Fused: cnt[i] = sum_k part[k][i]  AND  per-1024-block sums for the scan.
__global__ __launch_bounds__(256) void reduce_bsum(const unsigned* __restrict__ partC,
                                                   const unsigned* __restrict__ partR,
                                                   int* __restrict__ cntc,
                                                   int* __restrict__ cntr,
                                                   int* __restrict__ b0,
                                                   int* __restrict__ b1, int N) {
    const unsigned* p = blockIdx.y ? partR : partC;
    int* cnt = blockIdx.y ? cntr : cntc;
    int* bs = blockIdx.y ? b1 : b0;
    int base = blockIdx.x * 1024 + threadIdx.x * 4;
    unsigned v0 = 0, v1 = 0, v2 = 0, v3 = 0;
    if (base + 3 < N) {
        for (int k = 0; k < CSR_CH; k++) {
            uint4 u = *(const uint4*)(p + (size_t)k * N + base);
            v0 += u.x; v1 += u.y; v2 += u.z; v3 += u.w;
        }
        int4 w = {(int)v0, (int)v1, (int)v2, (int)v3};
        *(int4*)&cnt[base] = w;
    } else {
        unsigned vv[4] = {0, 0, 0, 0};
        for (int k = 0; k < CSR_CH; k++)
            for (int i = 0; i < 4; i++)
                if (base + i < N) vv[i] += p[(size_t)k * N + base + i];
        for (int i = 0; i < 4; i++) if (base + i < N) cnt[base + i] = (int)vv[i];
        v0 = vv[0]; v1 = vv[1]; v2 = vv[2]; v3 = vv[3];
    }
    int s = (int)(v0 + v1 + v2 + v3);
    __shared__ int red[256];
    red[threadIdx.x] = s;
    __syncthreads();
    for (int d = 128; d > 0; d >>= 1) {
        if (threadIdx.x < d) red[threadIdx.x] += red[threadIdx.x + d];
        __syncthreads();
    }
    if (threadIdx.x == 0) bs[blockIdx.x] = red[0];
}

// single-pass scatter body: LDS cursors seeded from bases; 0 global atomics.
__device__ __forceinline__ void scatter_body(int b,
                                             const int* __restrict__ row,
                                             const int* __restrict__ col,
                                             const unsigned* __restrict__ partC,
                                             const unsigned* __restrict__ partR,
                                             u16* __restrict__ ecol,
                                             u16* __restrict__ erow,
                                             int E, int N,
                                             unsigned* __restrict__ cur) {
    int dir = b >> 9;
    int r = b & 511;
    int sl = r >> 6;
    int k  = r & 63;
    const int* darr = dir ? row : col;
    const int* sarr = dir ? col : row;
    u16* out = dir ? erow : ecol;
    const unsigned* base = (dir ? partR : partC) + (size_t)k * N;
    int lo = (int)(((long long)N * sl) >> 3);
    int hi = (int)(((long long)N * (sl + 1)) >> 3);
    int wid = hi - lo;

    for (int i = threadIdx.x; i < wid; i += 256) cur[i] = base[lo + i];
    __syncthreads();

    int e0 = (int)(((long long)E * k) >> 6);
    int e1 = (int)(((long long)E * (k + 1)) >> 6);
    for (int e = e0 + threadIdx.x; e < e1; e += 256) {
        int d = darr[e] - lo;
        if ((unsigned)d < (unsigned)wid) {
            unsigned p = atomicAdd(&cur[d], 1u);
            out[p] = (u16)sarr[e];
        }
    }
}

// ---------------- legacy CSR build (tier B fallback) ----------------
__global__ __launch_bounds__(256) void histo_sniff(const int* __restrict__ row, const int* __restrict__ col,
                                                   int* __restrict__ cntc, int* __restrict__ cntr, int E,
                                                   const unsigned int* __restrict__ x,
                                                   const void* __restrict__ jkwb,
                                                   float* __restrict__ meta) {
    if (blockIdx.x == gridDim.x - 1) {
        sniff_body(x, jkwb, meta);
        return;
    }
    int e = blockIdx.x * 256 + threadIdx.x;
    if (e < E) {
        atomicAdd(&cntc[col[e]], 1);
        atomicAdd(&cntr[row[e]], 1);
    }
}

__global__ __launch_bounds__(256) void scan_bsum(const int* __restrict__ c0, const int* __restrict__ c1,
                                                 int* __restrict__ b0, int* __restrict__ b1, int N) {
    const int* cnt = blockIdx.y ? c1 : c0;
    int* bs = blockIdx.y ? b1 : b0;
    int base = blockIdx.x * 1024 + threadIdx.x * 4;
    int s = 0;
    if (base + 3 < N) {
        int4 v = *(const int4*)&cnt[base];
        s = v.x + v.y + v.z + v.w;
    } else {
        for (int i = 0; i < 4; i++) if (base + i < N) s += cnt[base + i];
    }
    __shared__ int red[256];
    red[threadIdx.x] = s;
    __syncthreads();
    for (int d = 128; d > 0; d >>= 1) {
        if (threadIdx.x < d) red[threadIdx.x] += red[threadIdx.x + d];
        __syncthreads();
    }
    if (threadIdx.x == 0) bs[blockIdx.x] = red[0];
}

__global__ __launch_bounds__(256) void scan_bsum_scan(int* __restrict__ b0, int* __restrict__ b1,
                                                      int* __restrict__ offN0, int* __restrict__ offN1,
                                                      int nb) {
    int* bs = blockIdx.x ? b1 : b0;
    int* offN = blockIdx.x ? offN1 : offN0;
    __shared__ int sh[256];
    int t = threadIdx.x;
    int v = (t < nb) ? bs[t] : 0;
    sh[t] = v;
    __syncthreads();
    for (int d = 1; d < 256; d <<= 1) {
        int u = (t >= d) ? sh[t - d] : 0;
        __syncthreads();
        sh[t] += u;
        __syncthreads();
    }
    if (t < nb) bs[t] = (t == 0) ? 0 : sh[t - 1];
    if (t == 255) *offN = sh[255];
}

// scan_final: offsets + dinv (y==0) + fused prefix over partials (when given).
__global__ __launch_bounds__(256) void scan_final(const int* __restrict__ c0, const int* __restrict__ c1,
                                                  const int* __restrict__ b0, const int* __restrict__ b1,
                                                  int* __restrict__ o0, int* __restrict__ u0,
                                                  int* __restrict__ o1, int* __restrict__ u1,
                                                  unsigned* __restrict__ pc,
                                                  unsigned* __restrict__ pr,
                                                  float* __restrict__ dinvp, int N) {
    const int* cnt = blockIdx.y ? c1 : c0;
    const int* bs  = blockIdx.y ? b1 : b0;
    int* off = blockIdx.y ? o1 : o0;
    int* cur = blockIdx.y ? u1 : u0;
    unsigned* part = blockIdx.y ? pr : pc;
    int t = threadIdx.x;
    int base = blockIdx.x * 1024 + t * 4;
    int4 v = {0, 0, 0, 0};
    if (base + 3 < N) {
        v = *(const int4*)&cnt[base];
    } else {
        int tmp[4] = {0, 0, 0, 0};
        for (int i = 0; i < 4; i++) if (base + i < N) tmp[i] = cnt[base + i];
        v.x = tmp[0]; v.y = tmp[1]; v.z = tmp[2]; v.w = tmp[3];
    }
    if (blockIdx.y == 0) {
        if (base + 3 < N) {
            float4 dv;
            dv.x = rsqrtf(1.0f + (float)v.x);
            dv.y = rsqrtf(1.0f + (float)v.y);
            dv.z = rsqrtf(1.0f + (float)v.z);
            dv.w = rsqrtf(1.0f + (float)v.w);
            *(float4*)&dinvp[base] = dv;
        } else {
            int vv[4] = {v.x, v.y, v.z, v.w};
            for (int i = 0; i < 4; i++)
                if (base + i < N) dinvp[base + i] = rsqrtf(1.0f + (float)vv[i]);
        }
    }
    int s = v.x + v.y + v.z + v.w;
    __shared__ int sh[256];
    sh[t] = s;
    __syncthreads();
    for (int d = 1; d < 256; d <<= 1) {
        int u = (t >= d) ? sh[t - d] : 0;
        __syncthreads();
        sh[t] += u;
        __syncthreads();
    }
    int ex = bs[blockIdx.x] + ((t == 0) ? 0 : sh[t - 1]);
    int4 o;
    o.x = ex; o.y = ex + v.x; o.z = o.y + v.y; o.w = o.z + v.z;
    if (base + 3 < N) {
        *(int4*)&off[base] = o;
        *(int4*)&cur[base] = o;
        if (part) {  // fused prefix: part[k][i] <- running base per chunk
            unsigned a0 = (unsigned)o.x, a1 = (unsigned)o.y,
                     a2 = (unsigned)o.z, a3 = (unsigned)o.w;
            for (int k = 0; k < CSR_CH; k++) {
                unsigned* pp = part + (size_t)k * N + base;
                uint4 u = *(const uint4*)pp;
                uint4 w = {a0, a1, a2, a3};
                *(uint4*)pp = w;
                a0 += u.x; a1 += u.y; a2 += u.z; a3 += u.w;
            }
        }
    } else {
        int arr[4] = {o.x, o.y, o.z, o.w};
        for (int i = 0; i < 4; i++) if (base + i < N) { off[base + i] = arr[i]; cur[base + i] = arr[i]; }
        if (part) {
            for (int i = 0; i < 4; i++) {
                if (base + i >= N) continue;
                unsigned acc = (unsigned)arr[i];
                for (int k = 0; k < CSR_CH; k++) {
                    unsigned* pp = part + (size_t)k * N + base + i;
                    unsigned tv = *pp;
                    *pp = acc;
                    acc += tv;
                }
            }
        }
    }
}

__global__ __launch_bounds__(256) void scatter_tile(const int* __restrict__ row, const int* __restrict__ col,
                                                    int* __restrict__ curc, int* __restrict__ curr,
                                                    u16* __restrict__ ecol, u16* __restrict__ erow,
                                                    int E, int lo, int hi, int doRow) {
    int e = blockIdx.x * 256 + threadIdx.x;
    if (e >= E) return;
    int s = row[e], d = col[e];
    if (d >= lo && d < hi) {
        int p = atomicAdd(&curc[d], 1);
        ecol[p] = (u16)s;
    }
    if (doRow && s >= lo && s < hi) {
        int q = atomicAdd(&curr[s], 1);
        erow[q] = (u16)d;
    }
}

// ---------------- W prepack (W1/W2/W3/Wfc in one launch: 16+8+8+4 blocks) ----------------
__global__ __launch_bounds__(256) void pack_all(const void* __restrict__ W1,
                                                const void* __restrict__ W2,
                                                const void* __restrict__ W3,
                                                const void* __restrict__ Wf,
                                                u16* __restrict__ Wp1,
                                                u16* __restrict__ Wp2,
                                                u16* __restrict__ Wp3,
                                                u16* __restrict__ Wfp,
                                                const int* __restrict__ flagp) {
    int bid = blockIdx.x;
    const void* W; u16* Wp; int K, C, gid;
    if (bid < 16)      { W = W1; Wp = Wp1; K = 256; C = 128; gid = bid * 256 + threadIdx.x; }
    else if (bid < 24) { W = W2; Wp = Wp2; K = 128; C = 128; gid = (bid - 16) * 256 + threadIdx.x; }
    else if (bid < 32) { W = W3; Wp = Wp3; K = 128; C = 128; gid = (bid - 24) * 256 + threadIdx.x; }
    else               { W = Wf; Wp = Wfp; K = 128; C = 64;  gid = (bid - 32) * 256 + threadIdx.x; }
    int tiles = C >> 4;
    int steps = K >> 5;
    if (gid >= steps * tiles * 64) return;
    int isbf = *flagp;
    int lane = gid & 63;
    int tt = (gid >> 6) % tiles;
    int s = (gid >> 6) / tiles;
    int krow = s * 32 + ((lane >> 4) << 3);
    int ncol = tt * 16 + (lane & 15);
#pragma unroll
    for (int j = 0; j < 8; j++) {
        float v = dload(W, (size_t)(krow + j) * C + ncol, isbf);
        Wp[(size_t)gid * 8 + j] = f2bf(v);
    }
}

// ---------------- MFMA GEMM body (global A) ----------------
template <int K, bool RTBF, bool BFIN, bool SCALE>
__device__ __forceinline__ void gemm_mfma_body(int bid, const void* __restrict__ Xv,
                                               const u16* __restrict__ Wp,
                                               u16* __restrict__ Cb,
                                               const float* __restrict__ dinv,
                                               const int* __restrict__ flagp, int M) {
    const int isbf = RTBF ? *flagp : (BFIN ? 1 : 0);
    const int tid = threadIdx.x;
    const int wave = tid >> 6, lane = tid & 63;
    const int m16 = lane & 15, quad = lane >> 4;
    const int row = bid * 64 + wave * 16 + m16;
    constexpr int STEPS = K / 32;

    float4v acc[8];
#pragma unroll
    for (int t = 0; t < 8; t++) acc[t] = (float4v){0.f, 0.f, 0.f, 0.f};

    const bool rowOK = row < M;
#pragma unroll
    for (int s = 0; s < STEPS; s++) {
        int k0 = s * 32 + quad * 8;
        short8 a = (short8)(short)0;
        if (rowOK) {
            if (isbf) {
                a = *(const short8*)((const u16*)Xv + (size_t)row * K + k0);
            } else {
                const float* p = (const float*)Xv + (size_t)row * K + k0;
                float4 f0 = *(const float4*)p;
                float4 f1 = *(const float4*)(p + 4);
                a[0] = (short)f2bf(f0.x); a[1] = (short)f2bf(f0.y);
                a[2] = (short)f2bf(f0.z); a[3] = (short)f2bf(f0.w);
                a[4] = (short)f2bf(f1.x); a[5] = (short)f2bf(f1.y);
                a[6] = (short)f2bf(f1.z); a[7] = (short)f2bf(f1.w);
            }
        }
#pragma unroll
        for (int t = 0; t < 8; t++) {
            short8 b = *(const short8*)(Wp + ((size_t)(s * 8 + t) * 64 + lane) * 8);
            acc[t] = __builtin_amdgcn_mfma_f32_16x16x32_bf16(a, b, acc[t], 0, 0, 0);
        }
    }
#pragma unroll
    for (int r = 0; r < 4; r++) {
        int gr = bid * 64 + wave * 16 + quad * 4 + r;
        if (gr < M) {
            float sc = SCALE ? dinv[gr] : 1.0f;
#pragma unroll
            for (int t = 0; t < 8; t++) {
                size_t o = (size_t)gr * H_FEATS + t * 16 + m16;
                Cb[o] = f2bf(sc * acc[t][r]);
            }
        }
    }
}

template <int K, bool RTBF, bool BFIN, bool SCALE>
__global__ __launch_bounds__(256) void gemm_mfma(const void* __restrict__ Xv,
                                                 const u16* __restrict__ Wp,
                                                 u16* __restrict__ Cb,
                                                 const float* __restrict__ dinv,
                                                 const int* __restrict__ flagp, int M) {
    gemm_mfma_body<K, RTBF, BFIN, SCALE>(blockIdx.x, Xv, Wp, Cb, dinv, flagp, M);
}

// ---------------- fused: scatter (blocks [0,NSC)) + gemm L0 (rest) ----------------
__global__ __launch_bounds__(256) void scatter_gemm0(const int* __restrict__ row,
                                                     const int* __restrict__ col,
                                                     const unsigned* __restrict__ partC,
                                                     const unsigned* __restrict__ partR,
                                                     u16* __restrict__ ecol,
                                                     u16* __restrict__ erow,
                                                     int E, int N,
                                                     const void* __restrict__ Xv,
                                                     const u16* __restrict__ Wp,
                                                     u16* __restrict__ Pb,
                                                     const float* __restrict__ dinv,
                                                     const int* __restrict__ flagp) {
    __shared__ unsigned cur[8192];
    if (blockIdx.x < CSR_NSC) {
        scatter_body(blockIdx.x, row, col, partC, partR, ecol, erow, E, N, cur);
    } else {
        gemm_mfma_body<256, true, false, true>(blockIdx.x - CSR_NSC, Xv, Wp, Pb, dinv, flagp, N);
    }
}

// ---------------- standalone tier-0 gather (L0): 32-lane/8B, depth-4 (proven) ----------------
__global__ __launch_bounds__(256) void agg_sum(const int* __restrict__ off,
                                               const u16* __restrict__ idx,
                                               const float* __restrict__ dinv,
                                               const u16* __restrict__ Pb,
                                               const void* __restrict__ bv,
                                               u16* __restrict__ hout,
                                               const int* __restrict__ flagp, int N) {
    int node = blockIdx.x * 8 + (threadIdx.x >> 5);
    if (node >= N) return;
    int l = threadIdx.x & 31;
    int isbf = *flagp;
    int beg = off[node], end = off[node + 1];
    size_t ro = (size_t)l * 4;

    float4 acc = load4bf(&Pb[(size_t)node * H_FEATS + ro]);

    const float4 z = {0.f, 0.f, 0.f, 0.f};
    int i = beg;
    int s0 = (i     < end) ? (int)idx[i]     : 0;
    int s1 = (i + 1 < end) ? (int)idx[i + 1] : 0;
    int s2 = (i + 2 < end) ? (int)idx[i + 2] : 0;
    int s3 = (i + 3 < end) ? (int)idx[i + 3] : 0;
    float4 h0 = (i     < end) ? load4bf(&Pb[(size_t)s0 * H_FEATS + ro]) : z;
    float4 h1 = (i + 1 < end) ? load4bf(&Pb[(size_t)s1 * H_FEATS + ro]) : z;
    float4 h2 = (i + 2 < end) ? load4bf(&Pb[(size_t)s2 * H_FEATS + ro]) : z;
    float4 h3 = (i + 3 < end) ? load4bf(&Pb[(size_t)s3 * H_FEATS + ro]) : z;
    for (; i + 4 < end; i += 4) {
        int t0 = (int)idx[i + 4];
        int t1 = (i + 5 < end) ? (int)idx[i + 5] : 0;
        int t2 = (i + 6 < end) ? (int)idx[i + 6] : 0;
        int t3 = (i + 7 < end) ? (int)idx[i + 7] : 0;
        float4 n0 = load4bf(&Pb[(size_t)t0 * H_FEATS + ro]);
        float4 n1 = (i + 5 < end) ? load4bf(&Pb[(size_t)t1 * H_FEATS + ro]) : z;
        float4 n2 = (i + 6 < end) ? load4bf(&Pb[(size_t)t2 * H_FEATS + ro]) : z;
        float4 n3 = (i + 7 < end) ? load4bf(&Pb[(size_t)t3 * H_FEATS + ro]) : z;
        acc.x += (h0.x + h1.x) + (h2.x + h3.x);
        acc.y += (h0.y + h1.y) + (h2.y + h3.y);
        acc.z += (h0.z + h1.z) + (h2.z + h3.z);
        acc.w += (h0.w + h1.w) + (h2.w + h3.w);
        h0 = n0; h1 = n1; h2 = n2; h3 = n3;
    }
    acc.x += (h0.x + h1.x) + (h2.x + h3.x);
    acc.y += (h0.y + h1.y) + (h2.y + h3.y);
    acc.z += (h0.z + h1.z) + (h2.z + h3.z);
    acc.w += (h0.w + h1.w) + (h2.w + h3.w);

    float dd = dinv[node];
    acc.x = fmaxf(fmaf(dd, acc.x, dload(bv, l * 4 + 0, isbf)), 0.0f);
    acc.y = fmaxf(fmaf(dd, acc.y, dload(bv, l * 4 + 1, isbf)), 0.0f);
    acc.z = fmaxf(fmaf(dd, acc.z, dload(bv, l * 4 + 2, isbf)), 0.0f);
    acc.w = fmaxf(fmaf(dd, acc.w, dload(bv, l * 4 + 3, isbf)), 0.0f);
    uint2 pk;
    pk.x = (unsigned)f2bf(acc.x) | ((unsigned)f2bf(acc.y) << 16);
    pk.y = (unsigned)f2bf(acc.z) | ((unsigned)f2bf(acc.w) << 16);
    *(uint2*)&hout[(size_t)node * H_FEATS + ro] = pk;
}

// ---------------- fused gather-tile helper: 16 lanes/row, uint4, depth-4 ----------------
// MODE 0 = AGG (self + sum, dinv scale, bias, relu); MODE 1 = MEAN (out-nbr mean, self fallback)
template <int MODE, bool WRITEG>
__device__ __forceinline__ void gather_tile(int bid,
                                            const int* __restrict__ off,
                                            const u16* __restrict__ idx,
                                            const float* __restrict__ dinv,
                                            const u16* __restrict__ Src,
                                            const void* __restrict__ bv, int isbf,
                                            u16* __restrict__ Hg,
                                            u16* __restrict__ tile, int N) {
    int lane16 = threadIdx.x & 15;
    int rloc = threadIdx.x >> 4;
    int co = lane16 * 8;
    const uint4 zz = {0u, 0u, 0u, 0u};
#pragma unroll
    for (int pass = 0; pass < 4; ++pass) {
        int r = pass * 16 + rloc;
        int gr = bid * 64 + r;
        uint4* ldst = (uint4*)(tile + (size_t)r * TPAD + co);
        if (gr >= N) { *ldst = zz; continue; }
        int beg = off[gr], end = off[gr + 1];
        float acc[8];
        if (MODE == 0) {
            uint4 u = *(const uint4*)(Src + (size_t)gr * H_FEATS + co);
            set8(acc, u);
        } else {
#pragma unroll
            for (int j = 0; j < 8; j++) acc[j] = 0.0f;
        }
        int i = beg;
        int s0 = (i     < end) ? (int)idx[i]     : 0;
        int s1 = (i + 1 < end) ? (int)idx[i + 1] : 0;
        int s2 = (i + 2 < end) ? (int)idx[i + 2] : 0;
        int s3 = (i + 3 < end) ? (int)idx[i + 3] : 0;
        uint4 h0 = (i     < end) ? *(const uint4*)(Src + (size_t)s0 * H_FEATS + co) : zz;
        uint4 h1 = (i + 1 < end) ? *(const uint4*)(Src + (size_t)s1 * H_FEATS + co) : zz;
        uint4 h2 = (i + 2 < end) ? *(const uint4*)(Src + (size_t)s2 * H_FEATS + co) : zz;
        uint4 h3 = (i + 3 < end) ? *(const uint4*)(Src + (size_t)s3 * H_FEATS + co) : zz;
        for (; i + 4 < end; i += 4) {
            int t0 = (int)idx[i + 4];
            int t1 = (i + 5 < end) ? (int)idx[i + 5] : 0;
            int t2 = (i + 6 < end) ? (int)idx[i + 6] : 0;
            int t3 = (i + 7 < end) ? (int)idx[i + 7] : 0;
            uint4 n0 = *(const uint4*)(Src + (size_t)t0 * H_FEATS + co);
            uint4 n1 = (i + 5 < end) ? *(const uint4*)(Src + (size_t)t1 * H_FEATS + co) : zz;
            uint4 n2 = (i + 6 < end) ? *(const uint4*)(Src + (size_t)t2 * H_FEATS + co) : zz;
            uint4 n3 = (i + 7 < end) ? *(const uint4*)(Src + (size_t)t3 * H_FEATS + co) : zz;
            add8(acc, h0); add8(acc, h1); add8(acc, h2); add8(acc, h3);
            h0 = n0; h1 = n1; h2 = n2; h3 = n3;
        }
        add8(acc, h0); add8(acc, h1); add8(acc, h2); add8(acc, h3);

        if (MODE == 0) {
            float dd = dinv[gr];
#pragma unroll
            for (int j = 0; j < 8; j++)
                acc[j] = fmaxf(fmaf(dd, acc[j], dload(bv, co + j, isbf)), 0.0f);
        } else {
            int cnt = end - beg;
            if (cnt > 0) {
                float inv = 1.0f / (float)cnt;
#pragma unroll
                for (int j = 0; j < 8; j++) acc[j] *= inv;
            } else {
                uint4 u = *(const uint4*)(Src + (size_t)gr * H_FEATS + co);
                set8(acc, u);
            }
        }
        uint4 pk = pack8(acc);
        *ldst = pk;
        if (WRITEG) *(uint4*)(Hg + (size_t)gr * H_FEATS + co) = pk;
    }
}

// ---------------- MFMA GEMM phase with A from LDS tile (K=128) ----------------
__device__ __forceinline__ void gemm_lds_body(int bid, const u16* __restrict__ tile,
                                              const u16* __restrict__ Wp,
                                              u16* __restrict__ Cb,
                                              const float* __restrict__ dinv, int M) {
    const int tid = threadIdx.x;
    const int wave = tid >> 6, lane = tid & 63;
    const int m16 = lane & 15, quad = lane >> 4;
    const int lrow = wave * 16 + m16;

    float4v acc[8];
#pragma unroll
    for (int t = 0; t < 8; t++) acc[t] = (float4v){0.f, 0.f, 0.f, 0.f};

#pragma unroll
    for (int s = 0; s < 4; s++) {
        int k0 = s * 32 + quad * 8;
        short8 a = *(const short8*)(tile + (size_t)lrow * TPAD + k0);
#pragma unroll
        for (int t = 0; t < 8; t++) {
            short8 b = *(const short8*)(Wp + ((size_t)(s * 8 + t) * 64 + lane) * 8);
            acc[t] = __builtin_amdgcn_mfma_f32_16x16x32_bf16(a, b, acc[t], 0, 0, 0);
        }
    }
#pragma unroll
    for (int r = 0; r < 4; r++) {
        int gr = bid * 64 + wave * 16 + quad * 4 + r;
        if (gr < M) {
            float sc = dinv[gr];
#pragma unroll
            for (int t = 0; t < 8; t++) {
                size_t o = (size_t)gr * H_FEATS + t * 16 + m16;
                Cb[o] = f2bf(sc * acc[t][r]);
            }
        }
    }
}

// ---------------- fused gather + gemm (tier 0, layers 1/2) ----------------
template <int MODE>
__global__ __launch_bounds__(256) void agg_gemm(const int* __restrict__ off,
                                                const u16* __restrict__ idx,
                                                const float* __restrict__ dinv,
                                                const u16* __restrict__ Src,
                                                const void* __restrict__ bv,
                                                const u16* __restrict__ Wp,
                                                u16* __restrict__ Hg,
                                                u16* __restrict__ Pnext,
                                                const int* __restrict__ flagp, int N) {
    __shared__ u16 tile[64 * TPAD];
    gather_tile<MODE, true>(blockIdx.x, off, idx, dinv, Src, bv, *flagp, Hg, tile, N);
    __syncthreads();
    gemm_lds_body(blockIdx.x, tile, Wp, Pnext, dinv, N);
}

// ---------------- fused gather + jk + MFMA fc (tier 0, last layer) ----------------
__global__ __launch_bounds__(256) void agg_fc3(const int* __restrict__ off,
                                               const u16* __restrict__ idx,
                                               const float* __restrict__ dinv,
                                               const u16* __restrict__ Src,
                                               const void* __restrict__ bv3,
                                               const u16* __restrict__ H0,
                                               const u16* __restrict__ H1,
                                               const u16* __restrict__ Wfp,
                                               const void* __restrict__ bv,
                                               void* __restrict__ Outv,
                                               const float* __restrict__ meta, int N) {
    __shared__ u16 tile[64 * TPAD];
    const int isbf = ((const int*)meta)[0];
    gather_tile<0, false>(blockIdx.x, off, idx, dinv, Src, bv3, isbf, (u16*)0, tile, N);
    __syncthreads();

    const float w0 = meta[8], w1 = meta[9], w2 = meta[10];
    const int tid = threadIdx.x;
    const int wave = tid >> 6, lane = tid & 63;
    const int m16 = lane & 15, quad = lane >> 4;
    const int lrow = wave * 16 + m16;
    const int gr0 = blockIdx.x * 64 + lrow;

    float4v acc[4];
#pragma unroll
    for (int t = 0; t < 4; t++) acc[t] = (float4v){0.f, 0.f, 0.f, 0.f};

#pragma unroll
    for (int s = 0; s < 4; s++) {
        int k0 = s * 32 + quad * 8;
        short8 a = (short8)(short)0;
        if (gr0 < N) {
            float f0[8], f1[8], f2[8];
            uint4 u0 = *(const uint4*)(H0 + (size_t)gr0 * H_FEATS + k0);
            uint4 u1 = *(const uint4*)(H1 + (size_t)gr0 * H_FEATS + k0);
            uint4 tv = *(const uint4*)(tile + (size_t)lrow * TPAD + k0);
            set8(f0, u0); set8(f1, u1); set8(f2, tv);
#pragma unroll
            for (int j = 0; j < 8; j++)
                a[j] = (short)f2bf(w0 * f0[j] + w1 * f1[j] + w2 * f2[j]);
        }
#pragma unroll
        for (int t = 0; t < 4; t++) {
            short8 b = *(const short8*)(Wfp + ((size_t)(s * 4 + t) * 64 + lane) * 8);
            acc[t] = __builtin_amdgcn_mfma_f32_16x16x32_bf16(a, b, acc[t], 0, 0, 0);
        }
    }

    __hip_bfloat16* ob = (__hip_bfloat16*)Outv;
    float* of = (float*)Outv;
#pragma unroll
    for (int r = 0; r < 4; r++) {
        int gr = blockIdx.x * 64 + wave * 16 + quad * 4 + r;
        if (gr < N) {
#pragma unroll
            for (int t = 0; t < 4; t++) {
                int c = t * 16 + m16;
                size_t o = (size_t)gr * 64 + c;
                float v = acc[t][r] + dload(bv, c, isbf);
                if (isbf) ob[o] = __float2bfloat16(v); else of[o] = v;
            }
        }
    }
}

// ---------------- weighted gather (tier B only) ----------------
template <bool BF16OUT>
__global__ __launch_bounds__(256) void agg_gather3b(const int* __restrict__ off,
                                                    const u16* __restrict__ idx,
                                                    const float* __restrict__ dinv,
                                                    const u16* __restrict__ Hb,
                                                    const void* __restrict__ bv,
                                                    void* __restrict__ houtv,
                                                    const int* __restrict__ flagp, int N) {
    int node = blockIdx.x * 8 + (threadIdx.x >> 5);
    if (node >= N) return;
    int l = threadIdx.x & 31;
    int isbf = *flagp;
    int beg = off[node], end = off[node + 1];
    float dd = dinv[node];
    size_t ro = (size_t)l * 4;

    float4 self = load4bf(&Hb[(size_t)node * H_FEATS + ro]);
    float w0s = dd * dd;
    float4 acc = {w0s * self.x, w0s * self.y, w0s * self.z, w0s * self.w};

    int i = beg;
    int s0 = (i < end) ? (int)idx[i] : 0;
    float4 h0 = (i < end) ? load4bf(&Hb[(size_t)s0 * H_FEATS + ro])
                          : (float4){0.f, 0.f, 0.f, 0.f};
    for (; i < end; i++) {
        int s1 = (i + 1 < end) ? (int)idx[i + 1] : 0;
        float4 h1 = (i + 1 < end) ? load4bf(&Hb[(size_t)s1 * H_FEATS + ro]) : h0;
        float w = dinv[s0] * dd;
        acc.x = fmaf(w, h0.x, acc.x);
        acc.y = fmaf(w, h0.y, acc.y);
        acc.z = fmaf(w, h0.z, acc.z);
        acc.w = fmaf(w, h0.w, acc.w);
        s0 = s1; h0 = h1;
    }
    acc.x = fmaxf(acc.x + dload(bv, l * 4 + 0, isbf), 0.0f);
    acc.y = fmaxf(acc.y + dload(bv, l * 4 + 1, isbf), 0.0f);
    acc.z = fmaxf(acc.z + dload(bv, l * 4 + 2, isbf), 0.0f);
    acc.w = fmaxf(acc.w + dload(bv, l * 4 + 3, isbf), 0.0f);
    if (BF16OUT) {
        u16* hb = (u16*)houtv;
        uint2 pk;
        pk.x = (unsigned)f2bf(acc.x) | ((unsigned)f2bf(acc.y) << 16);
        pk.y = (unsigned)f2bf(acc.z) | ((unsigned)f2bf(acc.w) << 16);
        *(uint2*)&hb[(size_t)node * H_FEATS + ro] = pk;
    } else {
        *(float4*)&((float*)houtv)[(size_t)node * H_FEATS + ro] = acc;
    }
}

// ---------------- fp32 GEMM (tier C) ----------------
template <int K, bool XIN, bool GATEBF, bool BF16OUT>
__global__ __launch_bounds__(256) void gemm128(const void* __restrict__ Xv,
                                               const void* __restrict__ Wv,
                                               void* __restrict__ Cv,
                                               const int* __restrict__ flagp, int N) {
    constexpr int BM = 64, BK = 16, BN = 128, TN = 8, TX = BN / TN;
    __shared__ float Xs[BK][BM + 4];
    __shared__ float Ws[BK][BN];
    const int isbf = *flagp;
    if (GATEBF && isbf != 1) return;
    const float* Xf = (const float*)Xv;

    const int tid = threadIdx.x;
    const int tx = tid % TX;
    const int ty = tid / TX;
    const int rowBase = blockIdx.x * BM;

    float acc[4][TN] = {};
    const int lk = tid % BK;
    const int lr0 = tid / BK;

    for (int kb = 0; kb < K; kb += BK) {
#pragma unroll
        for (int i = 0; i < 4; i++) {
            int r = lr0 + i * 16;
            int gr = rowBase + r;
            float v = 0.0f;
            if (gr < N) {
                size_t idx = (size_t)gr * K + kb + lk;
                v = XIN ? dload(Xv, idx, isbf) : Xf[idx];
            }
            Xs[lk][r] = v;
        }
#pragma unroll
        for (int i = 0; i < 8; i++) {
            int idx = i * 256 + tid;
            int k = idx >> 7, c = idx & 127;
            Ws[k][c] = dload(Wv, (size_t)(kb + k) * BN + c, isbf);
        }
        __syncthreads();
#pragma unroll
        for (int k = 0; k < BK; k++) {
            float4 a = *(const float4*)&Xs[k][ty * 4];
            float av[4] = {a.x, a.y, a.z, a.w};
            float4 b0 = *(const float4*)&Ws[k][tx * TN];
            float4 b1 = *(const float4*)&Ws[k][tx * TN + 4];
            float bv[8] = {b0.x, b0.y, b0.z, b0.w, b1.x, b1.y, b1.z, b1.w};
#pragma unroll
            for (int i = 0; i < 4; i++)
#pragma unroll
                for (int j = 0; j < TN; j++) acc[i][j] = fmaf(av[i], bv[j], acc[i][j]);
        }
        __syncthreads();
    }
#pragma unroll
    for (int i = 0; i < 4; i++) {
        int gr = rowBase + ty * 4 + i;
        if (gr < N) {
#pragma unroll
            for (int j = 0; j < TN; j++) {
                size_t o = (size_t)gr * BN + tx * TN + j;
                if (BF16OUT) ((u16*)Cv)[o] = f2bf(acc[i][j]);
                else         ((float*)Cv)[o] = acc[i][j];
            }
        }
    }
}

template <bool FIRST, bool LAST, bool BFIN>
__global__ __launch_bounds__(256) void fc_accum(const void* __restrict__ Hmv,
                                                const void* __restrict__ Wv,
                                                const void* __restrict__ bv,
                                                void* __restrict__ Outv,
                                                const float* __restrict__ meta,
                                                int widx, int N) {
    constexpr int BM = 64, BK = 16, BN = 64, TN = 4, TX = BN / TN, K = 128;
    __shared__ float Xs[BK][BM + 4];
    __shared__ float Ws[BK][BN];
    const int isbf = ((const int*)meta)[0];
    const float scale = meta[8 + widx];

    const int tid = threadIdx.x;
    const int tx = tid % TX;
    const int ty = tid / TX;
    const int rowBase = blockIdx.x * BM;

    float acc[4][TN] = {};
    const int lk = tid % BK;
    const int lr0 = tid / BK;

    for (int kb = 0; kb < K; kb += BK) {
#pragma unroll
        for (int i = 0; i < 4; i++) {
            int r = lr0 + i * 16;
            int gr = rowBase + r;
            float v = 0.0f;
            if (gr < N) {
                size_t idx = (size_t)gr * K + kb + lk;
                if (BFIN) v = bf2f(((const u16*)Hmv)[idx]);
                else      v = ((const float*)Hmv)[idx];
            }
            Xs[lk][r] = v;
        }
#pragma unroll
        for (int i = 0; i < 4; i++) {
            int idx = i * 256 + tid;
            int k = idx >> 6, c = idx & 63;
            Ws[k][c] = dload(Wv, (size_t)(kb + k) * BN + c, isbf);
        }
        __syncthreads();
#pragma unroll
        for (int k = 0; k < BK; k++) {
            float4 a = *(const float4*)&Xs[k][ty * 4];
            float av[4] = {a.x, a.y, a.z, a.w};
            float4 bb = *(const float4*)&Ws[k][tx * TN];
            float bvv[4] = {bb.x, bb.y, bb.z, bb.w};
#pragma unroll
            for (int i = 0; i < 4; i++)
#pragma unroll
                for (int j = 0; j < TN; j++) acc[i][j] = fmaf(av[i], bvv[j], acc[i][j]);
        }
        __syncthreads();
    }
    __hip_bfloat16* ob = (__hip_bfloat16*)Outv;
    float* of = (float*)Outv;
#pragma unroll
    for (int i = 0; i < 4; i++) {
        int gr = rowBase + ty * 4 + i;
        if (gr < N) {
#pragma unroll
            for (int j = 0; j < TN; j++) {
                int c = tx * TN + j;
                size_t o = (size_t)gr * BN + c;
                float v = scale * acc[i][j];
                if (!FIRST) v += isbf ? __bfloat162float(ob[o]) : of[o];
                if (LAST) v += dload(bv, c, isbf);
                if (isbf) ob[o] = __float2bfloat16(v); else of[o] = v;
            }
        }
    }
}

// ---------------- atomic fallbacks (tier B / C) ----------------
__global__ __launch_bounds__(256) void init_deg(float* deg, float* odeg, int N) {
    int i = blockIdx.x * 256 + threadIdx.x;
    if (i < N) { deg[i] = 1.0f; odeg[i] = 0.0f; }
}
__global__ __launch_bounds__(256) void count_deg(const int* __restrict__ row, const int* __restrict__ col,
                                                 float* deg, float* odeg, int E) {
    int e = blockIdx.x * 256 + threadIdx.x;
    if (e < E) {
        atomicAdd(&deg[col[e]], 1.0f);
        atomicAdd(&odeg[row[e]], 1.0f);
    }
}
__global__ __launch_bounds__(256) void deg_to_dinv(float* deg, int N) {
    int i = blockIdx.x * 256 + threadIdx.x;
    if (i < N) deg[i] = rsqrtf(deg[i]);
}
__global__ __launch_bounds__(256) void agg_edges(const int* __restrict__ row, const int* __restrict__ col,
                                                 const float* __restrict__ dinv,
                                                 const float* __restrict__ H,
                                                 float* __restrict__ agg, int E) {
    int e = blockIdx.x * 2 + (threadIdx.x >> 7);
    if (e >= E) return;
    int j = threadIdx.x & 127;
    int s = row[e], d = col[e];
    float w = dinv[s] * dinv[d];
    atomicAdd(&agg[(size_t)d * H_FEATS + j], w * H[(size_t)s * H_FEATS + j]);
}
__global__ __launch_bounds__(256) void mean_edges(const int* __restrict__ row, const int* __restrict__ col,
                                                  const float* __restrict__ h0pre,
                                                  float* __restrict__ nsum, int E) {
    int e = blockIdx.x * 2 + (threadIdx.x >> 7);
    if (e >= E) return;
    int j = threadIdx.x & 127;
    int r = row[e], c = col[e];
    atomicAdd(&nsum[(size_t)r * H_FEATS + j], h0pre[(size_t)c * H_FEATS + j]);
}
__global__ __launch_bounds__(256) void finalize_layer(const float* __restrict__ agg,
                                                      const float* __restrict__ H,
                                                      const float* __restrict__ dinv,
                                                      const void* __restrict__ bv,
                                                      float* __restrict__ hout,
                                                      const int* __restrict__ flagp, int NH) {
    int idx = blockIdx.x * 256 + threadIdx.x;
    if (idx >= NH) return;
    int isbf = *flagp;
    int v = idx >> 7, j = idx & 127;
    float di = dinv[v];
    float h = fmaf(di * di, H[idx], agg[idx]) + dload(bv, j, isbf);
    hout[idx] = fmaxf(h, 0.0f);
}
__global__ __launch_bounds__(256) void finalize_mean(const float* __restrict__ nsum,
                                                     const float* __restrict__ h0pre,
                                                     const float* __restrict__ odeg,
                                                     float* __restrict__ h0, int NH) {
    int idx = blockIdx.x * 256 + threadIdx.x;
    if (idx >= NH) return;
    int v = idx >> 7;
    float od = odeg[v];
    h0[idx] = (od > 0.0f) ? (nsum[idx] / od) : h0pre[idx];
}
__global__ __launch_bounds__(256) void finalize_mean_cnt(const float* __restrict__ nsum,
                                                         const float* __restrict__ h0pre,
                                                         const int* __restrict__ cntr,
                                                         float* __restrict__ h0, int NH) {
    int idx = blockIdx.x * 256 + threadIdx.x;
    if (idx >= NH) return;
    int v = idx >> 7;
    int od = cntr[v];
    h0[idx] = (od > 0) ? (nsum[idx] / (float)od) : h0pre[idx];
}

extern "C" void kernel_launch(void* const* d_in, const int* in_sizes, int n_in,
                              void* d_out, int out_size, void* d_ws, size_t ws_size,
                              hipStream_t stream) {
    const void* x   = d_in[0];
    const int*  ei  = (const int*)d_in[1];
    const void* W1  = d_in[2];
    const void* b1  = d_in[3];
    const void* W2  = d_in[4];
    const void* b2  = d_in[5];
    const void* W3  = d_in[6];
    const void* b3  = d_in[7];
    const void* jkb = d_in[8];
    const void* Wfc = d_in[9];
    const void* bfc = d_in[10];

    const int IN = 256;
    const int N = in_sizes[0] / IN;          // 50000
    const int E = in_sizes[1] / 2;           // 800000
    const int NH = N * H_FEATS;

    const int* row = ei;
    const int* col = ei + E;

    // ---- workspace layout (fp32 words); arrays 16B-aligned ----
    auto a4 = [](size_t v) { return (v + 3) & ~(size_t)3; };
    float* ws = (float*)d_ws;
    size_t o = 0;
    float* meta  = ws + o;           o += 256;
    float* dinv  = ws + o;           o += N;          o = a4(o);
    int*   cntc  = (int*)(ws + o);   o += N;          o = a4(o);
    int*   cntr  = (int*)(ws + o);   o += N;          o = a4(o);
    int*   bsumc = (int*)(ws + o);   o += 256;
    int*   bsumr = (int*)(ws + o);   o += 256;
    int*   coff  = (int*)(ws + o);   o += N + 1;      o = a4(o);
    int*   curc  = (int*)(ws + o);   o += N;          o = a4(o);
    u16*   ecol  = (u16*)(ws + o);   o += E;          o = a4(o);
    size_t oB_small = o;
    int*   roff  = (int*)(ws + o);   o += N + 1;      o = a4(o);
    int*   curr  = (int*)(ws + o);   o += N;          o = a4(o);
    u16*   erow  = (u16*)(ws + o);   o += E;          o = a4(o);
    size_t oA_full = o;

    auto alignup = [](size_t v) { return (v + 63) & ~(size_t)63; };
    const size_t WPW = 16384 + 8192 + 8192 + 4096;   // Wp1 + Wp2 + Wp3 + Wfcp (fp32 words)
    size_t needA = alignup(oA_full) + 2 * (size_t)NH + 64 + WPW;
    size_t needB = alignup(oB_small) + 2 * (size_t)NH + 64 + WPW;

    int tier;
    size_t hoff;
    if (N >= 65536)                { tier = 2; hoff = alignup(256 + 2 * (size_t)N); }
    else if (ws_size >= needA * 4) { tier = 0; hoff = alignup(oA_full); }
    else if (ws_size >= needB * 4) { tier = 1; hoff = alignup(oB_small); }
    else                           { tier = 2; hoff = alignup(256 + 2 * (size_t)N); }
    float* A = ws + hoff;
    float* B = A + NH;
    u16* HbA = (u16*)A;
    u16* HbB = (u16*)B;
    // tier-0 carves four bf16 NH buffers out of the same 2*NH-float region:
    u16* Pb  = (u16*)A;              // P rows (rotating)
    u16* Qb  = Pb + (size_t)NH;      // h0pre, later P2
    u16* H0b = Pb + 2 * (size_t)NH;
    u16* H1b = Pb + 3 * (size_t)NH;
    // CSR-build partials overlay the H0/H1 half (dead until meangemm1):
    unsigned* partC = (unsigned*)H0b;
    unsigned* partR = partC + (size_t)CSR_CH * N;
    size_t wpoff = alignup(hoff + 2 * (size_t)NH);
    u16* Wp1 = (u16*)(ws + wpoff);
    u16* Wp2 = Wp1 + 32768;
    u16* Wp3 = Wp2 + 16384;
    u16* Wfcp = Wp3 + 16384;
    float* odegf = ws + 256 + N;
    const int* flag = (const int*)meta;

    dim3 blk(256);
    int gN = (N + 255) / 256;
    int gE = (E + 255) / 256;
    int gE2 = (E + 1) / 2;
    int gNH = (NH + 255) / 256;
    int gGemm = (N + 63) / 64;
    int gNode8 = (N + 7) / 8;
    int nb = (N + 1023) / 1024;

    if (tier == 0) {
        // ---- atomic-free CSR build (XCD-local block order) ----
        count_partial<<<CSR_NSC + 1, blk, 0, stream>>>(row, col, partC, partR, E, N,
                                                       (const unsigned int*)x, jkb, meta);
        pack_all<<<36, blk, 0, stream>>>(W1, W2, W3, Wfc, Wp1, Wp2, Wp3, Wfcp, flag);
        reduce_bsum<<<dim3(nb, 2), blk, 0, stream>>>(partC, partR, cntc, cntr, bsumc, bsumr, N);
        scan_bsum_scan<<<2, blk, 0, stream>>>(bsumc, bsumr, &coff[N], &roff[N], nb);
        scan_final<<<dim3(nb, 2), blk, 0, stream>>>(cntc, cntr, bsumc, bsumr,
                                                    coff, curc, roff, curr,
                                                    partC, partR, dinv, N);

        // ---- fused: scatter + layer-0 GEMM (P0 = dinv .* (x@W1)) ----
        scatter_gemm0<<<CSR_NSC + gGemm, blk, 0, stream>>>(row, col, partC, partR, ecol, erow,
                                                           E, N, x, Wp1, Pb, dinv, flag);

        // ---- h0pre = relu(dd*(P0[d]+sum P0[s]) + b1) ----
        agg_sum<<<gNode8, blk, 0, stream>>>(coff, ecol, dinv, Pb, b1, Qb, flag, N);

        // ---- fused mean + gemm1: h0 -> H0b, P1 = dinv.(h0@W2) -> Pb ----
        agg_gemm<1><<<gGemm, blk, 0, stream>>>(roff, erow, dinv, Qb, b1, Wp2, H0b, Pb, flag, N);

        // ---- fused agg + gemm2: h1 -> H1b, P2 = dinv.(h1@W3) -> Qb ----
        agg_gemm<0><<<gGemm, blk, 0, stream>>>(coff, ecol, dinv, Pb, b2, Wp3, H1b, Qb, flag, N);

        // ---- fused agg + jk + MFMA fc: h2 (LDS only) + out ----
        agg_fc3<<<gGemm, blk, 0, stream>>>(coff, ecol, dinv, Qb, b3, H0b, H1b,
                                           Wfcp, bfc, d_out, meta, N);
    } else if (tier == 1) {
        // ---- tier B: legacy atomic CSR build (col only) + fp32 mean path ----
        hipMemsetAsync(cntc, 0, 2 * (size_t)N * 4, stream);
        histo_sniff<<<gE + 1, blk, 0, stream>>>(row, col, cntc, cntr, E,
                                                (const unsigned int*)x, jkb, meta);
        const int T = 4;
        int step = (N + T - 1) / T;
        scan_bsum<<<dim3(nb, 1), blk, 0, stream>>>(cntc, cntc, bsumc, bsumc, N);
        scan_bsum_scan<<<1, blk, 0, stream>>>(bsumc, bsumc, &coff[N], &coff[N], nb);
        scan_final<<<dim3(nb, 1), blk, 0, stream>>>(cntc, cntc, bsumc, bsumc,
                                                    coff, curc, coff, curc,
                                                    (unsigned*)0, (unsigned*)0, dinv, N);
        for (int t = 0; t < T; t++) {
            int lo = t * step, hi = lo + step; if (hi > N) hi = N;
            scatter_tile<<<gE, blk, 0, stream>>>(row, col, curc, curc, ecol, ecol, E, lo, hi, 0);
        }

        pack_all<<<36, blk, 0, stream>>>(W1, W2, W3, Wfc, Wp1, Wp2, Wp3, Wfcp, flag);

        gemm_mfma<256, true, false, false><<<gGemm, blk, 0, stream>>>(x, Wp1, HbA, dinv, flag, N);
        agg_gather3b<false><<<gNode8, blk, 0, stream>>>(coff, ecol, dinv, HbA, b1, B, flag, N);
        hipMemsetAsync(A, 0, (size_t)NH * 4, stream);
        mean_edges<<<gE2, blk, 0, stream>>>(row, col, B, A, E);
        finalize_mean_cnt<<<gNH, blk, 0, stream>>>(A, B, cntr, A, NH);
        fc_accum<true, false, false><<<gGemm, blk, 0, stream>>>(A, Wfc, bfc, d_out, meta, 0, N);

        gemm_mfma<128, false, false, false><<<gGemm, blk, 0, stream>>>(A, Wp2, HbB, dinv, flag, N);
        agg_gather3b<true><<<gNode8, blk, 0, stream>>>(coff, ecol, dinv, HbB, b2, HbA, flag, N);
        fc_accum<false, false, true><<<gGemm, blk, 0, stream>>>(HbA, Wfc, bfc, d_out, meta, 1, N);

        gemm_mfma<128, false, true, false><<<gGemm, blk, 0, stream>>>(HbA, Wp3, HbB, dinv, flag, N);
        agg_gather3b<true><<<gNode8, blk, 0, stream>>>(coff, ecol, dinv, HbB, b3, HbA, flag, N);
        fc_accum<false, true, true><<<gGemm, blk, 0, stream>>>(HbA, Wfc, bfc, d_out, meta, 2, N);
    } else {
        // ---- tier C: fp32 atomic path ----
        sniff_jkw<<<1, blk, 0, stream>>>((const unsigned int*)x, jkb, meta);
        init_deg<<<gN, blk, 0, stream>>>(dinv, odegf, N);
        count_deg<<<gE, blk, 0, stream>>>(row, col, dinv, odegf, E);
        deg_to_dinv<<<gN, blk, 0, stream>>>(dinv, N);

        gemm128<256, true, false, false><<<gGemm, blk, 0, stream>>>(x, W1, A, flag, N);
        hipMemsetAsync(B, 0, (size_t)NH * 4, stream);
        agg_edges<<<gE2, blk, 0, stream>>>(row, col, dinv, A, B, E);
        finalize_layer<<<gNH, blk, 0, stream>>>(B, A, dinv, b1, B, flag, NH);
        hipMemsetAsync(A, 0, (size_t)NH * 4, stream);
        mean_edges<<<gE2, blk, 0, stream>>>(row, col, B, A, E);
        finalize_mean<<<gNH, blk, 0, stream>>>(A, B, odegf, A, NH);
        fc_accum<true, false, false><<<gGemm, blk, 0, stream>>>(A, Wfc, bfc, d_out, meta, 0, N);

        gemm128<128, false, false, false><<<gGemm, blk, 0, stream>>>(A, W2, B, flag, N);
        hipMemsetAsync(A, 0, (size_t)NH * 4, stream);
        agg_edges<<<gE2, blk, 0, stream>>>(row, col, dinv, B, A, E);
        finalize_layer<<<gNH, blk, 0, stream>>>(A, B, dinv, b2, A, flag, NH);
        fc_accum<false, false, false><<<gGemm, blk, 0, stream>>>(A, Wfc, bfc, d_out, meta, 1, N);

        gemm128<128, false, false, false><<<gGemm, blk, 0, stream>>>(A, W3, B, flag, N);
        hipMemsetAsync(A, 0, (size_t)NH * 4, stream);
        agg_edges<<<gE2, blk, 0, stream>>>(row, col, dinv, B, A, E);
        finalize_layer<<<gNH, blk, 0, stream>>>(A, B, dinv, b3, A, flag, NH);
        fc_accum<false, true, false><<<gGemm, blk, 0, stream>>>(A, Wfc, bfc, d_out, meta, 2, N);
    }
}

// Round 11
// 396.832 us; speedup vs baseline: 1.0646x; 1.0226x over previous
//
#include <hip/hip_runtime.h>
#include <hip/hip_bf16.h>

// DynamicJKGCN on MI355X — round 23: 32-row fused tiles + dynamic LDS.
// Round-22 (405.8us = best): scatter_gemm0 traffic-bound (FETCH41+WRITE71MB at
// 1.8TB/s ~= its 62us). Remaining lever: fused agg_gemm/agg_fc3 run at only
// 782 blocks = 3 blk/CU = 12 waves/CU for a latency-bound gather phase.
// This round:
//  1) 32-row tiles for agg_gemm/agg_fc3 (grid 2x -> 6 blk/CU, LDS 17.4->8.7KB);
//     gemm phase re-split: wave w = rows (w&1)*16, col-tiles (w>>1)*4 (fc: *2).
//  2) count_partial/scatter_gemm0: dynamic LDS = ceil(N/8)*4 (25KB for N=50K,
//     was static 32KB) -> occupancy cap 5->6 blk/CU.
// Everything else identical to round 22. Tier B/C unchanged.

#define H_FEATS 128
#define TPAD 136

typedef __attribute__((ext_vector_type(8))) short short8;
typedef __attribute__((ext_vector_type(4))) float float4v;
typedef unsigned short u16;

__device__ __forceinline__ float dload(const void* p, size_t i, int isbf) {
    return isbf ? __bfloat162float(((const __hip_bfloat16*)p)[i])
                : ((const float*)p)[i];
}

__device__ __forceinline__ float4 load4bf(const u16* p) {
    uint2 u = *(const uint2*)p;
    float4 f;
    f.x = __uint_as_float((u.x & 0xFFFFu) << 16);
    f.y = __uint_as_float(u.x & 0xFFFF0000u);
    f.z = __uint_as_float((u.y & 0xFFFFu) << 16);
    f.w = __uint_as_float(u.y & 0xFFFF0000u);
    return f;
}

__device__ __forceinline__ float bf2f(u16 h) {
    return __uint_as_float((unsigned)h << 16);
}

__device__ __forceinline__ u16 f2bf(float v) {
    return __bfloat16_as_ushort(__float2bfloat16(v));
}

__device__ __forceinline__ void add8(float* a, uint4 u) {
    a[0] += __uint_as_float((u.x & 0xFFFFu) << 16);
    a[1] += __uint_as_float(u.x & 0xFFFF0000u);
    a[2] += __uint_as_float((u.y & 0xFFFFu) << 16);
    a[3] += __uint_as_float(u.y & 0xFFFF0000u);
    a[4] += __uint_as_float((u.z & 0xFFFFu) << 16);
    a[5] += __uint_as_float(u.z & 0xFFFF0000u);
    a[6] += __uint_as_float((u.w & 0xFFFFu) << 16);
    a[7] += __uint_as_float(u.w & 0xFFFF0000u);
}

__device__ __forceinline__ void set8(float* a, uint4 u) {
    a[0] = __uint_as_float((u.x & 0xFFFFu) << 16);
    a[1] = __uint_as_float(u.x & 0xFFFF0000u);
    a[2] = __uint_as_float((u.y & 0xFFFFu) << 16);
    a[3] = __uint_as_float(u.y & 0xFFFF0000u);
    a[4] = __uint_as_float((u.z & 0xFFFFu) << 16);
    a[5] = __uint_as_float(u.z & 0xFFFF0000u);
    a[6] = __uint_as_float((u.w & 0xFFFFu) << 16);
    a[7] = __uint_as_float(u.w & 0xFFFF0000u);
}

__device__ __forceinline__ uint4 pack8(const float* f) {
    uint4 r;
    r.x = (unsigned)f2bf(f[0]) | ((unsigned)f2bf(f[1]) << 16);
    r.y = (unsigned)f2bf(f[2]) | ((unsigned)f2bf(f[3]) << 16);
    r.z = (unsigned)f2bf(f[4]) | ((unsigned)f2bf(f[5]) << 16);
    r.w = (unsigned)f2bf(f[6]) | ((unsigned)f2bf(f[7]) << 16);
    return r;
}

// ---------------- dtype sniff + jk softmax ----------------
__device__ __forceinline__ void sniff_body(const unsigned int* __restrict__ x,
                                           const void* __restrict__ jkwb,
                                           float* __restrict__ meta) {
    __shared__ int cnt[256];
    int t = threadIdx.x;
    int c = 0;
    for (int i = 0; i < 16; i++) {
        unsigned int w = x[t * 16 + i];
        unsigned int e = (w >> 7) & 0xFFu;
        c += (e >= 0x60u && e <= 0x8Fu) ? 1 : 0;
    }
    cnt[t] = c;
    __syncthreads();
    for (int s = 128; s > 0; s >>= 1) {
        if (t < s) cnt[t] += cnt[t + s];
        __syncthreads();
    }
    if (t == 0) {
        int isbf = (cnt[0] > 3000) ? 1 : 0;
        ((int*)meta)[0] = isbf;
        float w0 = dload(jkwb, 0, isbf);
        float w1 = dload(jkwb, 1, isbf);
        float w2 = dload(jkwb, 2, isbf);
        float m = fmaxf(w0, fmaxf(w1, w2));
        float e0 = expf(w0 - m), e1 = expf(w1 - m), e2 = expf(w2 - m);
        float s = e0 + e1 + e2;
        meta[8] = e0 / s; meta[9] = e1 / s; meta[10] = e2 / s;
    }
}

__global__ __launch_bounds__(256) void sniff_jkw(const unsigned int* __restrict__ x,
                                                 const void* __restrict__ jkwb,
                                                 float* __restrict__ meta) {
    sniff_body(x, jkwb, meta);
}

// ---------------- atomic-free CSR build (tier 0) ----------------
#define CSR_CH 64
#define CSR_SL 8
#define CSR_NSC (CSR_CH * CSR_SL * 2)

__global__ __launch_bounds__(256) void count_partial(const int* __restrict__ row,
                                                     const int* __restrict__ col,
                                                     unsigned* __restrict__ partC,
                                                     unsigned* __restrict__ partR,
                                                     int E, int N,
                                                     const unsigned int* __restrict__ x,
                                                     const void* __restrict__ jkwb,
                                                     float* __restrict__ meta) {
    if (blockIdx.x == gridDim.x - 1) {  // piggyback the dtype sniff
        sniff_body(x, jkwb, meta);
        return;
    }
    extern __shared__ unsigned cnt[];
    int b = blockIdx.x;
    int dir = b >> 9;
    int r = b & 511;
    int sl = r >> 6;
    int k  = r & 63;
    const int* arr = dir ? row : col;
    unsigned* part = (dir ? partR : partC) + (size_t)k * N;
    int lo = (int)(((long long)N * sl) >> 3);
    int hi = (int)(((long long)N * (sl + 1)) >> 3);
    int wid = hi - lo;

    for (int i = threadIdx.x; i < wid; i += 256) cnt[i] = 0;
    __syncthreads();

    int e0 = (int)(((long long)E * k) >> 6);
    int e1 = (int)(((long long)E * (k + 1)) >> 6);
    for (int e = e0 + threadIdx.x; e < e1; e += 256) {
        int d = arr[e] - lo;
        if ((unsigned)d < (unsigned)wid) atomicAdd(&cnt[d], 1u);
    }
    __syncthreads();
    for (int i = threadIdx.x; i < wid; i += 256) part[lo + i] = cnt[i];
}

// Fused: cnt[i] = sum_k part[k][i]  AND  per-1024-block sums for the scan.
__global__ __launch_bounds__(256) void reduce_bsum(const unsigned* __restrict__ partC,
                                                   const unsigned* __restrict__ partR,
                                                   int* __restrict__ cntc,
                                                   int* __restrict__ cntr,
                                                   int* __restrict__ b0,
                                                   int* __restrict__ b1, int N) {
    const unsigned* p = blockIdx.y ? partR : partC;
    int* cnt = blockIdx.y ? cntr : cntc;
    int* bs = blockIdx.y ? b1 : b0;
    int base = blockIdx.x * 1024 + threadIdx.x * 4;
    unsigned v0 = 0, v1 = 0, v2 = 0, v3 = 0;
    if (base + 3 < N) {
        for (int k = 0; k < CSR_CH; k++) {
            uint4 u = *(const uint4*)(p + (size_t)k * N + base);
            v0 += u.x; v1 += u.y; v2 += u.z; v3 += u.w;
        }
        int4 w = {(int)v0, (int)v1, (int)v2, (int)v3};
        *(int4*)&cnt[base] = w;
    } else {
        unsigned vv[4] = {0, 0, 0, 0};
        for (int k = 0; k < CSR_CH; k++)
            for (int i = 0; i < 4; i++)
                if (base + i < N) vv[i] += p[(size_t)k * N + base + i];
        for (int i = 0; i < 4; i++) if (base + i < N) cnt[base + i] = (int)vv[i];
        v0 = vv[0]; v1 = vv[1]; v2 = vv[2]; v3 = vv[3];
    }
    int s = (int)(v0 + v1 + v2 + v3);
    __shared__ int red[256];
    red[threadIdx.x] = s;
    __syncthreads();
    for (int d = 128; d > 0; d >>= 1) {
        if (threadIdx.x < d) red[threadIdx.x] += red[threadIdx.x + d];
        __syncthreads();
    }
    if (threadIdx.x == 0) bs[blockIdx.x] = red[0];
}

// single-pass scatter body: LDS cursors seeded from bases; 0 global atomics.
__device__ __forceinline__ void scatter_body(int b,
                                             const int* __restrict__ row,
                                             const int* __restrict__ col,
                                             const unsigned* __restrict__ partC,
                                             const unsigned* __restrict__ partR,
                                             u16* __restrict__ ecol,
                                             u16* __restrict__ erow,
                                             int E, int N,
                                             unsigned* __restrict__ cur) {
    int dir = b >> 9;
    int r = b & 511;
    int sl = r >> 6;
    int k  = r & 63;
    const int* darr = dir ? row : col;
    const int* sarr = dir ? col : row;
    u16* out = dir ? erow : ecol;
    const unsigned* base = (dir ? partR : partC) + (size_t)k * N;
    int lo = (int)(((long long)N * sl) >> 3);
    int hi = (int)(((long long)N * (sl + 1)) >> 3);
    int wid = hi - lo;

    for (int i = threadIdx.x; i < wid; i += 256) cur[i] = base[lo + i];
    __syncthreads();

    int e0 = (int)(((long long)E * k) >> 6);
    int e1 = (int)(((long long)E * (k + 1)) >> 6);
    for (int e = e0 + threadIdx.x; e < e1; e += 256) {
        int d = darr[e] - lo;
        if ((unsigned)d < (unsigned)wid) {
            unsigned p = atomicAdd(&cur[d], 1u);
            out[p] = (u16)sarr[e];
        }
    }
}

// ---------------- legacy CSR build (tier B fallback) ----------------
__global__ __launch_bounds__(256) void histo_sniff(const int* __restrict__ row, const int* __restrict__ col,
                                                   int* __restrict__ cntc, int* __restrict__ cntr, int E,
                                                   const unsigned int* __restrict__ x,
                                                   const void* __restrict__ jkwb,
                                                   float* __restrict__ meta) {
    if (blockIdx.x == gridDim.x - 1) {
        sniff_body(x, jkwb, meta);
        return;
    }
    int e = blockIdx.x * 256 + threadIdx.x;
    if (e < E) {
        atomicAdd(&cntc[col[e]], 1);
        atomicAdd(&cntr[row[e]], 1);
    }
}

__global__ __launch_bounds__(256) void scan_bsum(const int* __restrict__ c0, const int* __restrict__ c1,
                                                 int* __restrict__ b0, int* __restrict__ b1, int N) {
    const int* cnt = blockIdx.y ? c1 : c0;
    int* bs = blockIdx.y ? b1 : b0;
    int base = blockIdx.x * 1024 + threadIdx.x * 4;
    int s = 0;
    if (base + 3 < N) {
        int4 v = *(const int4*)&cnt[base];
        s = v.x + v.y + v.z + v.w;
    } else {
        for (int i = 0; i < 4; i++) if (base + i < N) s += cnt[base + i];
    }
    __shared__ int red[256];
    red[threadIdx.x] = s;
    __syncthreads();
    for (int d = 128; d > 0; d >>= 1) {
        if (threadIdx.x < d) red[threadIdx.x] += red[threadIdx.x + d];
        __syncthreads();
    }
    if (threadIdx.x == 0) bs[blockIdx.x] = red[0];
}

__global__ __launch_bounds__(256) void scan_bsum_scan(int* __restrict__ b0, int* __restrict__ b1,
                                                      int* __restrict__ offN0, int* __restrict__ offN1,
                                                      int nb) {
    int* bs = blockIdx.x ? b1 : b0;
    int* offN = blockIdx.x ? offN1 : offN0;
    __shared__ int sh[256];
    int t = threadIdx.x;
    int v = (t < nb) ? bs[t] : 0;
    sh[t] = v;
    __syncthreads();
    for (int d = 1; d < 256; d <<= 1) {
        int u = (t >= d) ? sh[t - d] : 0;
        __syncthreads();
        sh[t] += u;
        __syncthreads();
    }
    if (t < nb) bs[t] = (t == 0) ? 0 : sh[t - 1];
    if (t == 255) *offN = sh[255];
}

// scan_final: offsets + dinv (y==0) + fused prefix over partials (when given).
__global__ __launch_bounds__(256) void scan_final(const int* __restrict__ c0, const int* __restrict__ c1,
                                                  const int* __restrict__ b0, const int* __restrict__ b1,
                                                  int* __restrict__ o0, int* __restrict__ u0,
                                                  int* __restrict__ o1, int* __restrict__ u1,
                                                  unsigned* __restrict__ pc,
                                                  unsigned* __restrict__ pr,
                                                  float* __restrict__ dinvp, int N) {
    const int* cnt = blockIdx.y ? c1 : c0;
    const int* bs  = blockIdx.y ? b1 : b0;
    int* off = blockIdx.y ? o1 : o0;
    int* cur = blockIdx.y ? u1 : u0;
    unsigned* part = blockIdx.y ? pr : pc;
    int t = threadIdx.x;
    int base = blockIdx.x * 1024 + t * 4;
    int4 v = {0, 0, 0, 0};
    if (base + 3 < N) {
        v = *(const int4*)&cnt[base];
    } else {
        int tmp[4] = {0, 0, 0, 0};
        for (int i = 0; i < 4; i++) if (base + i < N) tmp[i] = cnt[base + i];
        v.x = tmp[0]; v.y = tmp[1]; v.z = tmp[2]; v.w = tmp[3];
    }
    if (blockIdx.y == 0) {
        if (base + 3 < N) {
            float4 dv;
            dv.x = rsqrtf(1.0f + (float)v.x);
            dv.y = rsqrtf(1.0f + (float)v.y);
            dv.z = rsqrtf(1.0f + (float)v.z);
            dv.w = rsqrtf(1.0f + (float)v.w);
            *(float4*)&dinvp[base] = dv;
        } else {
            int vv[4] = {v.x, v.y, v.z, v.w};
            for (int i = 0; i < 4; i++)
                if (base + i < N) dinvp[base + i] = rsqrtf(1.0f + (float)vv[i]);
        }
    }
    int s = v.x + v.y + v.z + v.w;
    __shared__ int sh[256];
    sh[t] = s;
    __syncthreads();
    for (int d = 1; d < 256; d <<= 1) {
        int u = (t >= d) ? sh[t - d] : 0;
        __syncthreads();
        sh[t] += u;
        __syncthreads();
    }
    int ex = bs[blockIdx.x] + ((t == 0) ? 0 : sh[t - 1]);
    int4 o;
    o.x = ex; o.y = ex + v.x; o.z = o.y + v.y; o.w = o.z + v.z;
    if (base + 3 < N) {
        *(int4*)&off[base] = o;
        *(int4*)&cur[base] = o;
        if (part) {
            unsigned a0 = (unsigned)o.x, a1 = (unsigned)o.y,
                     a2 = (unsigned)o.z, a3 = (unsigned)o.w;
            for (int k = 0; k < CSR_CH; k++) {
                unsigned* pp = part + (size_t)k * N + base;
                uint4 u = *(const uint4*)pp;
                uint4 w = {a0, a1, a2, a3};
                *(uint4*)pp = w;
                a0 += u.x; a1 += u.y; a2 += u.z; a3 += u.w;
            }
        }
    } else {
        int arr[4] = {o.x, o.y, o.z, o.w};
        for (int i = 0; i < 4; i++) if (base + i < N) { off[base + i] = arr[i]; cur[base + i] = arr[i]; }
        if (part) {
            for (int i = 0; i < 4; i++) {
                if (base + i >= N) continue;
                unsigned acc = (unsigned)arr[i];
                for (int k = 0; k < CSR_CH; k++) {
                    unsigned* pp = part + (size_t)k * N + base + i;
                    unsigned tv = *pp;
                    *pp = acc;
                    acc += tv;
                }
            }
        }
    }
}

__global__ __launch_bounds__(256) void scatter_tile(const int* __restrict__ row, const int* __restrict__ col,
                                                    int* __restrict__ curc, int* __restrict__ curr,
                                                    u16* __restrict__ ecol, u16* __restrict__ erow,
                                                    int E, int lo, int hi, int doRow) {
    int e = blockIdx.x * 256 + threadIdx.x;
    if (e >= E) return;
    int s = row[e], d = col[e];
    if (d >= lo && d < hi) {
        int p = atomicAdd(&curc[d], 1);
        ecol[p] = (u16)s;
    }
    if (doRow && s >= lo && s < hi) {
        int q = atomicAdd(&curr[s], 1);
        erow[q] = (u16)d;
    }
}

// ---------------- W prepack (W1/W2/W3/Wfc in one launch: 16+8+8+4 blocks) ----------------
__global__ __launch_bounds__(256) void pack_all(const void* __restrict__ W1,
                                                const void* __restrict__ W2,
                                                const void* __restrict__ W3,
                                                const void* __restrict__ Wf,
                                                u16* __restrict__ Wp1,
                                                u16* __restrict__ Wp2,
                                                u16* __restrict__ Wp3,
                                                u16* __restrict__ Wfp,
                                                const int* __restrict__ flagp) {
    int bid = blockIdx.x;
    const void* W; u16* Wp; int K, C, gid;
    if (bid < 16)      { W = W1; Wp = Wp1; K = 256; C = 128; gid = bid * 256 + threadIdx.x; }
    else if (bid < 24) { W = W2; Wp = Wp2; K = 128; C = 128; gid = (bid - 16) * 256 + threadIdx.x; }
    else if (bid < 32) { W = W3; Wp = Wp3; K = 128; C = 128; gid = (bid - 24) * 256 + threadIdx.x; }
    else               { W = Wf; Wp = Wfp; K = 128; C = 64;  gid = (bid - 32) * 256 + threadIdx.x; }
    int tiles = C >> 4;
    int steps = K >> 5;
    if (gid >= steps * tiles * 64) return;
    int isbf = *flagp;
    int lane = gid & 63;
    int tt = (gid >> 6) % tiles;
    int s = (gid >> 6) / tiles;
    int krow = s * 32 + ((lane >> 4) << 3);
    int ncol = tt * 16 + (lane & 15);
#pragma unroll
    for (int j = 0; j < 8; j++) {
        float v = dload(W, (size_t)(krow + j) * C + ncol, isbf);
        Wp[(size_t)gid * 8 + j] = f2bf(v);
    }
}

// ---------------- MFMA GEMM body (global A) ----------------
template <int K, bool RTBF, bool BFIN, bool SCALE>
__device__ __forceinline__ void gemm_mfma_body(int bid, const void* __restrict__ Xv,
                                               const u16* __restrict__ Wp,
                                               u16* __restrict__ Cb,
                                               const float* __restrict__ dinv,
                                               const int* __restrict__ flagp, int M) {
    const int isbf = RTBF ? *flagp : (BFIN ? 1 : 0);
    const int tid = threadIdx.x;
    const int wave = tid >> 6, lane = tid & 63;
    const int m16 = lane & 15, quad = lane >> 4;
    const int row = bid * 64 + wave * 16 + m16;
    constexpr int STEPS = K / 32;

    float4v acc[8];
#pragma unroll
    for (int t = 0; t < 8; t++) acc[t] = (float4v){0.f, 0.f, 0.f, 0.f};

    const bool rowOK = row < M;
#pragma unroll
    for (int s = 0; s < STEPS; s++) {
        int k0 = s * 32 + quad * 8;
        short8 a = (short8)(short)0;
        if (rowOK) {
            if (isbf) {
                a = *(const short8*)((const u16*)Xv + (size_t)row * K + k0);
            } else {
                const float* p = (const float*)Xv + (size_t)row * K + k0;
                float4 f0 = *(const float4*)p;
                float4 f1 = *(const float4*)(p + 4);
                a[0] = (short)f2bf(f0.x); a[1] = (short)f2bf(f0.y);
                a[2] = (short)f2bf(f0.z); a[3] = (short)f2bf(f0.w);
                a[4] = (short)f2bf(f1.x); a[5] = (short)f2bf(f1.y);
                a[6] = (short)f2bf(f1.z); a[7] = (short)f2bf(f1.w);
            }
        }
#pragma unroll
        for (int t = 0; t < 8; t++) {
            short8 b = *(const short8*)(Wp + ((size_t)(s * 8 + t) * 64 + lane) * 8);
            acc[t] = __builtin_amdgcn_mfma_f32_16x16x32_bf16(a, b, acc[t], 0, 0, 0);
        }
    }
#pragma unroll
    for (int r = 0; r < 4; r++) {
        int gr = bid * 64 + wave * 16 + quad * 4 + r;
        if (gr < M) {
            float sc = SCALE ? dinv[gr] : 1.0f;
#pragma unroll
            for (int t = 0; t < 8; t++) {
                size_t o = (size_t)gr * H_FEATS + t * 16 + m16;
                Cb[o] = f2bf(sc * acc[t][r]);
            }
        }
    }
}

template <int K, bool RTBF, bool BFIN, bool SCALE>
__global__ __launch_bounds__(256) void gemm_mfma(const void* __restrict__ Xv,
                                                 const u16* __restrict__ Wp,
                                                 u16* __restrict__ Cb,
                                                 const float* __restrict__ dinv,
                                                 const int* __restrict__ flagp, int M) {
    gemm_mfma_body<K, RTBF, BFIN, SCALE>(blockIdx.x, Xv, Wp, Cb, dinv, flagp, M);
}

// ---------------- fused: scatter (blocks [0,NSC)) + gemm L0 (rest) ----------------
__global__ __launch_bounds__(256) void scatter_gemm0(const int* __restrict__ row,
                                                     const int* __restrict__ col,
                                                     const unsigned* __restrict__ partC,
                                                     const unsigned* __restrict__ partR,
                                                     u16* __restrict__ ecol,
                                                     u16* __restrict__ erow,
                                                     int E, int N,
                                                     const void* __restrict__ Xv,
                                                     const u16* __restrict__ Wp,
                                                     u16* __restrict__ Pb,
                                                     const float* __restrict__ dinv,
                                                     const int* __restrict__ flagp) {
    extern __shared__ unsigned cur[];
    if (blockIdx.x < CSR_NSC) {
        scatter_body(blockIdx.x, row, col, partC, partR, ecol, erow, E, N, cur);
    } else {
        gemm_mfma_body<256, true, false, true>(blockIdx.x - CSR_NSC, Xv, Wp, Pb, dinv, flagp, N);
    }
}

// ---------------- standalone tier-0 gather (L0): 32-lane/8B, depth-4 (proven) ----------------
__global__ __launch_bounds__(256) void agg_sum(const int* __restrict__ off,
                                               const u16* __restrict__ idx,
                                               const float* __restrict__ dinv,
                                               const u16* __restrict__ Pb,
                                               const void* __restrict__ bv,
                                               u16* __restrict__ hout,
                                               const int* __restrict__ flagp, int N) {
    int node = blockIdx.x * 8 + (threadIdx.x >> 5);
    if (node >= N) return;
    int l = threadIdx.x & 31;
    int isbf = *flagp;
    int beg = off[node], end = off[node + 1];
    size_t ro = (size_t)l * 4;

    float4 acc = load4bf(&Pb[(size_t)node * H_FEATS + ro]);

    const float4 z = {0.f, 0.f, 0.f, 0.f};
    int i = beg;
    int s0 = (i     < end) ? (int)idx[i]     : 0;
    int s1 = (i + 1 < end) ? (int)idx[i + 1] : 0;
    int s2 = (i + 2 < end) ? (int)idx[i + 2] : 0;
    int s3 = (i + 3 < end) ? (int)idx[i + 3] : 0;
    float4 h0 = (i     < end) ? load4bf(&Pb[(size_t)s0 * H_FEATS + ro]) : z;
    float4 h1 = (i + 1 < end) ? load4bf(&Pb[(size_t)s1 * H_FEATS + ro]) : z;
    float4 h2 = (i + 2 < end) ? load4bf(&Pb[(size_t)s2 * H_FEATS + ro]) : z;
    float4 h3 = (i + 3 < end) ? load4bf(&Pb[(size_t)s3 * H_FEATS + ro]) : z;
    for (; i + 4 < end; i += 4) {
        int t0 = (int)idx[i + 4];
        int t1 = (i + 5 < end) ? (int)idx[i + 5] : 0;
        int t2 = (i + 6 < end) ? (int)idx[i + 6] : 0;
        int t3 = (i + 7 < end) ? (int)idx[i + 7] : 0;
        float4 n0 = load4bf(&Pb[(size_t)t0 * H_FEATS + ro]);
        float4 n1 = (i + 5 < end) ? load4bf(&Pb[(size_t)t1 * H_FEATS + ro]) : z;
        float4 n2 = (i + 6 < end) ? load4bf(&Pb[(size_t)t2 * H_FEATS + ro]) : z;
        float4 n3 = (i + 7 < end) ? load4bf(&Pb[(size_t)t3 * H_FEATS + ro]) : z;
        acc.x += (h0.x + h1.x) + (h2.x + h3.x);
        acc.y += (h0.y + h1.y) + (h2.y + h3.y);
        acc.z += (h0.z + h1.z) + (h2.z + h3.z);
        acc.w += (h0.w + h1.w) + (h2.w + h3.w);
        h0 = n0; h1 = n1; h2 = n2; h3 = n3;
    }
    acc.x += (h0.x + h1.x) + (h2.x + h3.x);
    acc.y += (h0.y + h1.y) + (h2.y + h3.y);
    acc.z += (h0.z + h1.z) + (h2.z + h3.z);
    acc.w += (h0.w + h1.w) + (h2.w + h3.w);

    float dd = dinv[node];
    acc.x = fmaxf(fmaf(dd, acc.x, dload(bv, l * 4 + 0, isbf)), 0.0f);
    acc.y = fmaxf(fmaf(dd, acc.y, dload(bv, l * 4 + 1, isbf)), 0.0f);
    acc.z = fmaxf(fmaf(dd, acc.z, dload(bv, l * 4 + 2, isbf)), 0.0f);
    acc.w = fmaxf(fmaf(dd, acc.w, dload(bv, l * 4 + 3, isbf)), 0.0f);
    uint2 pk;
    pk.x = (unsigned)f2bf(acc.x) | ((unsigned)f2bf(acc.y) << 16);
    pk.y = (unsigned)f2bf(acc.z) | ((unsigned)f2bf(acc.w) << 16);
    *(uint2*)&hout[(size_t)node * H_FEATS + ro] = pk;
}

// ---------------- fused gather-tile helper: 32-row tile, 16 lanes/row, uint4, depth-4 ----------------
// MODE 0 = AGG (self + sum, dinv scale, bias, relu); MODE 1 = MEAN (out-nbr mean, self fallback)
template <int MODE, bool WRITEG>
__device__ __forceinline__ void gather_tile(int bid,
                                            const int* __restrict__ off,
                                            const u16* __restrict__ idx,
                                            const float* __restrict__ dinv,
                                            const u16* __restrict__ Src,
                                            const void* __restrict__ bv, int isbf,
                                            u16* __restrict__ Hg,
                                            u16* __restrict__ tile, int N) {
    int lane16 = threadIdx.x & 15;
    int rloc = threadIdx.x >> 4;
    int co = lane16 * 8;
    const uint4 zz = {0u, 0u, 0u, 0u};
#pragma unroll
    for (int pass = 0; pass < 2; ++pass) {
        int r = pass * 16 + rloc;
        int gr = bid * 32 + r;
        uint4* ldst = (uint4*)(tile + (size_t)r * TPAD + co);
        if (gr >= N) { *ldst = zz; continue; }
        int beg = off[gr], end = off[gr + 1];
        float acc[8];
        if (MODE == 0) {
            uint4 u = *(const uint4*)(Src + (size_t)gr * H_FEATS + co);
            set8(acc, u);
        } else {
#pragma unroll
            for (int j = 0; j < 8; j++) acc[j] = 0.0f;
        }
        int i = beg;
        int s0 = (i     < end) ? (int)idx[i]     : 0;
        int s1 = (i + 1 < end) ? (int)idx[i + 1] : 0;
        int s2 = (i + 2 < end) ? (int)idx[i + 2] : 0;
        int s3 = (i + 3 < end) ? (int)idx[i + 3] : 0;
        uint4 h0 = (i     < end) ? *(const uint4*)(Src + (size_t)s0 * H_FEATS + co) : zz;
        uint4 h1 = (i + 1 < end) ? *(const uint4*)(Src + (size_t)s1 * H_FEATS + co) : zz;
        uint4 h2 = (i + 2 < end) ? *(const uint4*)(Src + (size_t)s2 * H_FEATS + co) : zz;
        uint4 h3 = (i + 3 < end) ? *(const uint4*)(Src + (size_t)s3 * H_FEATS + co) : zz;
        for (; i + 4 < end; i += 4) {
            int t0 = (int)idx[i + 4];
            int t1 = (i + 5 < end) ? (int)idx[i + 5] : 0;
            int t2 = (i + 6 < end) ? (int)idx[i + 6] : 0;
            int t3 = (i + 7 < end) ? (int)idx[i + 7] : 0;
            uint4 n0 = *(const uint4*)(Src + (size_t)t0 * H_FEATS + co);
            uint4 n1 = (i + 5 < end) ? *(const uint4*)(Src + (size_t)t1 * H_FEATS + co) : zz;
            uint4 n2 = (i + 6 < end) ? *(const uint4*)(Src + (size_t)t2 * H_FEATS + co) : zz;
            uint4 n3 = (i + 7 < end) ? *(const uint4*)(Src + (size_t)t3 * H_FEATS + co) : zz;
            add8(acc, h0); add8(acc, h1); add8(acc, h2); add8(acc, h3);
            h0 = n0; h1 = n1; h2 = n2; h3 = n3;
        }
        add8(acc, h0); add8(acc, h1); add8(acc, h2); add8(acc, h3);

        if (MODE == 0) {
            float dd = dinv[gr];
#pragma unroll
            for (int j = 0; j < 8; j++)
                acc[j] = fmaxf(fmaf(dd, acc[j], dload(bv, co + j, isbf)), 0.0f);
        } else {
            int cnt = end - beg;
            if (cnt > 0) {
                float inv = 1.0f / (float)cnt;
#pragma unroll
                for (int j = 0; j < 8; j++) acc[j] *= inv;
            } else {
                uint4 u = *(const uint4*)(Src + (size_t)gr * H_FEATS + co);
                set8(acc, u);
            }
        }
        uint4 pk = pack8(acc);
        *ldst = pk;
        if (WRITEG) *(uint4*)(Hg + (size_t)gr * H_FEATS + co) = pk;
    }
}

// ---------------- MFMA GEMM phase, A from 32-row LDS tile (K=128) ----------------
// wave w: rows (w&1)*16..+16, col-tiles (w>>1)*4..+4
__device__ __forceinline__ void gemm_lds_body32(int bid, const u16* __restrict__ tile,
                                                const u16* __restrict__ Wp,
                                                u16* __restrict__ Cb,
                                                const float* __restrict__ dinv, int M) {
    const int tid = threadIdx.x;
    const int wave = tid >> 6, lane = tid & 63;
    const int m16 = lane & 15, quad = lane >> 4;
    const int rg = wave & 1, cg = wave >> 1;
    const int lrow = rg * 16 + m16;

    float4v acc[4];
#pragma unroll
    for (int t = 0; t < 4; t++) acc[t] = (float4v){0.f, 0.f, 0.f, 0.f};

#pragma unroll
    for (int s = 0; s < 4; s++) {
        int k0 = s * 32 + quad * 8;
        short8 a = *(const short8*)(tile + (size_t)lrow * TPAD + k0);
#pragma unroll
        for (int t = 0; t < 4; t++) {
            int tg = cg * 4 + t;
            short8 b = *(const short8*)(Wp + ((size_t)(s * 8 + tg) * 64 + lane) * 8);
            acc[t] = __builtin_amdgcn_mfma_f32_16x16x32_bf16(a, b, acc[t], 0, 0, 0);
        }
    }
#pragma unroll
    for (int r = 0; r < 4; r++) {
        int gr = bid * 32 + rg * 16 + quad * 4 + r;
        if (gr < M) {
            float sc = dinv[gr];
#pragma unroll
            for (int t = 0; t < 4; t++) {
                size_t o = (size_t)gr * H_FEATS + (cg * 4 + t) * 16 + m16;
                Cb[o] = f2bf(sc * acc[t][r]);
            }
        }
    }
}

// ---------------- fused gather + gemm (tier 0, layers 1/2), 32-row tile ----------------
template <int MODE>
__global__ __launch_bounds__(256) void agg_gemm(const int* __restrict__ off,
                                                const u16* __restrict__ idx,
                                                const float* __restrict__ dinv,
                                                const u16* __restrict__ Src,
                                                const void* __restrict__ bv,
                                                const u16* __restrict__ Wp,
                                                u16* __restrict__ Hg,
                                                u16* __restrict__ Pnext,
                                                const int* __restrict__ flagp, int N) {
    __shared__ u16 tile[32 * TPAD];
    gather_tile<MODE, true>(blockIdx.x, off, idx, dinv, Src, bv, *flagp, Hg, tile, N);
    __syncthreads();
    gemm_lds_body32(blockIdx.x, tile, Wp, Pnext, dinv, N);
}

// ---------------- fused gather + jk + MFMA fc (tier 0, last layer), 32-row tile ----------------
__global__ __launch_bounds__(256) void agg_fc3(const int* __restrict__ off,
                                               const u16* __restrict__ idx,
                                               const float* __restrict__ dinv,
                                               const u16* __restrict__ Src,
                                               const void* __restrict__ bv3,
                                               const u16* __restrict__ H0,
                                               const u16* __restrict__ H1,
                                               const u16* __restrict__ Wfp,
                                               const void* __restrict__ bv,
                                               void* __restrict__ Outv,
                                               const float* __restrict__ meta, int N) {
    __shared__ u16 tile[32 * TPAD];
    const int isbf = ((const int*)meta)[0];
    gather_tile<0, false>(blockIdx.x, off, idx, dinv, Src, bv3, isbf, (u16*)0, tile, N);
    __syncthreads();

    const float w0 = meta[8], w1 = meta[9], w2 = meta[10];
    const int tid = threadIdx.x;
    const int wave = tid >> 6, lane = tid & 63;
    const int m16 = lane & 15, quad = lane >> 4;
    const int rg = wave & 1, cg = wave >> 1;   // cg in [0,2): col-tiles cg*2..+2
    const int lrow = rg * 16 + m16;
    const int gr0 = blockIdx.x * 32 + lrow;

    float4v acc[2];
#pragma unroll
    for (int t = 0; t < 2; t++) acc[t] = (float4v){0.f, 0.f, 0.f, 0.f};

#pragma unroll
    for (int s = 0; s < 4; s++) {
        int k0 = s * 32 + quad * 8;
        short8 a = (short8)(short)0;
        if (gr0 < N) {
            float f0[8], f1[8], f2[8];
            uint4 u0 = *(const uint4*)(H0 + (size_t)gr0 * H_FEATS + k0);
            uint4 u1 = *(const uint4*)(H1 + (size_t)gr0 * H_FEATS + k0);
            uint4 tv = *(const uint4*)(tile + (size_t)lrow * TPAD + k0);
            set8(f0, u0); set8(f1, u1); set8(f2, tv);
#pragma unroll
            for (int j = 0; j < 8; j++)
                a[j] = (short)f2bf(w0 * f0[j] + w1 * f1[j] + w2 * f2[j]);
        }
#pragma unroll
        for (int t = 0; t < 2; t++) {
            int tg = cg * 2 + t;
            short8 b = *(const short8*)(Wfp + ((size_t)(s * 4 + tg) * 64 + lane) * 8);
            acc[t] = __builtin_amdgcn_mfma_f32_16x16x32_bf16(a, b, acc[t], 0, 0, 0);
        }
    }

    __hip_bfloat16* ob = (__hip_bfloat16*)Outv;
    float* of = (float*)Outv;
#pragma unroll
    for (int r = 0; r < 4; r++) {
        int gr = blockIdx.x * 32 + rg * 16 + quad * 4 + r;
        if (gr < N) {
#pragma unroll
            for (int t = 0; t < 2; t++) {
                int c = (cg * 2 + t) * 16 + m16;
                size_t o = (size_t)gr * 64 + c;
                float v = acc[t][r] + dload(bv, c, isbf);
                if (isbf) ob[o] = __float2bfloat16(v); else of[o] = v;
            }
        }
    }
}

// ---------------- weighted gather (tier B only) ----------------
template <bool BF16OUT>
__global__ __launch_bounds__(256) void agg_gather3b(const int* __restrict__ off,
                                                    const u16* __restrict__ idx,
                                                    const float* __restrict__ dinv,
                                                    const u16* __restrict__ Hb,
                                                    const void* __restrict__ bv,
                                                    void* __restrict__ houtv,
                                                    const int* __restrict__ flagp, int N) {
    int node = blockIdx.x * 8 + (threadIdx.x >> 5);
    if (node >= N) return;
    int l = threadIdx.x & 31;
    int isbf = *flagp;
    int beg = off[node], end = off[node + 1];
    float dd = dinv[node];
    size_t ro = (size_t)l * 4;

    float4 self = load4bf(&Hb[(size_t)node * H_FEATS + ro]);
    float w0s = dd * dd;
    float4 acc = {w0s * self.x, w0s * self.y, w0s * self.z, w0s * self.w};

    int i = beg;
    int s0 = (i < end) ? (int)idx[i] : 0;
    float4 h0 = (i < end) ? load4bf(&Hb[(size_t)s0 * H_FEATS + ro])
                          : (float4){0.f, 0.f, 0.f, 0.f};
    for (; i < end; i++) {
        int s1 = (i + 1 < end) ? (int)idx[i + 1] : 0;
        float4 h1 = (i + 1 < end) ? load4bf(&Hb[(size_t)s1 * H_FEATS + ro]) : h0;
        float w = dinv[s0] * dd;
        acc.x = fmaf(w, h0.x, acc.x);
        acc.y = fmaf(w, h0.y, acc.y);
        acc.z = fmaf(w, h0.z, acc.z);
        acc.w = fmaf(w, h0.w, acc.w);
        s0 = s1; h0 = h1;
    }
    acc.x = fmaxf(acc.x + dload(bv, l * 4 + 0, isbf), 0.0f);
    acc.y = fmaxf(acc.y + dload(bv, l * 4 + 1, isbf), 0.0f);
    acc.z = fmaxf(acc.z + dload(bv, l * 4 + 2, isbf), 0.0f);
    acc.w = fmaxf(acc.w + dload(bv, l * 4 + 3, isbf), 0.0f);
    if (BF16OUT) {
        u16* hb = (u16*)houtv;
        uint2 pk;
        pk.x = (unsigned)f2bf(acc.x) | ((unsigned)f2bf(acc.y) << 16);
        pk.y = (unsigned)f2bf(acc.z) | ((unsigned)f2bf(acc.w) << 16);
        *(uint2*)&hb[(size_t)node * H_FEATS + ro] = pk;
    } else {
        *(float4*)&((float*)houtv)[(size_t)node * H_FEATS + ro] = acc;
    }
}

// ---------------- fp32 GEMM (tier C) ----------------
template <int K, bool XIN, bool GATEBF, bool BF16OUT>
__global__ __launch_bounds__(256) void gemm128(const void* __restrict__ Xv,
                                               const void* __restrict__ Wv,
                                               void* __restrict__ Cv,
                                               const int* __restrict__ flagp, int N) {
    constexpr int BM = 64, BK = 16, BN = 128, TN = 8, TX = BN / TN;
    __shared__ float Xs[BK][BM + 4];
    __shared__ float Ws[BK][BN];
    const int isbf = *flagp;
    if (GATEBF && isbf != 1) return;
    const float* Xf = (const float*)Xv;

    const int tid = threadIdx.x;
    const int tx = tid % TX;
    const int ty = tid / TX;
    const int rowBase = blockIdx.x * BM;

    float acc[4][TN] = {};
    const int lk = tid % BK;
    const int lr0 = tid / BK;

    for (int kb = 0; kb < K; kb += BK) {
#pragma unroll
        for (int i = 0; i < 4; i++) {
            int r = lr0 + i * 16;
            int gr = rowBase + r;
            float v = 0.0f;
            if (gr < N) {
                size_t idx = (size_t)gr * K + kb + lk;
                v = XIN ? dload(Xv, idx, isbf) : Xf[idx];
            }
            Xs[lk][r] = v;
        }
#pragma unroll
        for (int i = 0; i < 8; i++) {
            int idx = i * 256 + tid;
            int k = idx >> 7, c = idx & 127;
            Ws[k][c] = dload(Wv, (size_t)(kb + k) * BN + c, isbf);
        }
        __syncthreads();
#pragma unroll
        for (int k = 0; k < BK; k++) {
            float4 a = *(const float4*)&Xs[k][ty * 4];
            float av[4] = {a.x, a.y, a.z, a.w};
            float4 b0 = *(const float4*)&Ws[k][tx * TN];
            float4 b1 = *(const float4*)&Ws[k][tx * TN + 4];
            float bv[8] = {b0.x, b0.y, b0.z, b0.w, b1.x, b1.y, b1.z, b1.w};
#pragma unroll
            for (int i = 0; i < 4; i++)
#pragma unroll
                for (int j = 0; j < TN; j++) acc[i][j] = fmaf(av[i], bv[j], acc[i][j]);
        }
        __syncthreads();
    }
#pragma unroll
    for (int i = 0; i < 4; i++) {
        int gr = rowBase + ty * 4 + i;
        if (gr < N) {
#pragma unroll
            for (int j = 0; j < TN; j++) {
                size_t o = (size_t)gr * BN + tx * TN + j;
                if (BF16OUT) ((u16*)Cv)[o] = f2bf(acc[i][j]);
                else         ((float*)Cv)[o] = acc[i][j];
            }
        }
    }
}

template <bool FIRST, bool LAST, bool BFIN>
__global__ __launch_bounds__(256) void fc_accum(const void* __restrict__ Hmv,
                                                const void* __restrict__ Wv,
                                                const void* __restrict__ bv,
                                                void* __restrict__ Outv,
                                                const float* __restrict__ meta,
                                                int widx, int N) {
    constexpr int BM = 64, BK = 16, BN = 64, TN = 4, TX = BN / TN, K = 128;
    __shared__ float Xs[BK][BM + 4];
    __shared__ float Ws[BK][BN];
    const int isbf = ((const int*)meta)[0];
    const float scale = meta[8 + widx];

    const int tid = threadIdx.x;
    const int tx = tid % TX;
    const int ty = tid / TX;
    const int rowBase = blockIdx.x * BM;

    float acc[4][TN] = {};
    const int lk = tid % BK;
    const int lr0 = tid / BK;

    for (int kb = 0; kb < K; kb += BK) {
#pragma unroll
        for (int i = 0; i < 4; i++) {
            int r = lr0 + i * 16;
            int gr = rowBase + r;
            float v = 0.0f;
            if (gr < N) {
                size_t idx = (size_t)gr * K + kb + lk;
                if (BFIN) v = bf2f(((const u16*)Hmv)[idx]);
                else      v = ((const float*)Hmv)[idx];
            }
            Xs[lk][r] = v;
        }
#pragma unroll
        for (int i = 0; i < 4; i++) {
            int idx = i * 256 + tid;
            int k = idx >> 6, c = idx & 63;
            Ws[k][c] = dload(Wv, (size_t)(kb + k) * BN + c, isbf);
        }
        __syncthreads();
#pragma unroll
        for (int k = 0; k < BK; k++) {
            float4 a = *(const float4*)&Xs[k][ty * 4];
            float av[4] = {a.x, a.y, a.z, a.w};
            float4 bb = *(const float4*)&Ws[k][tx * TN];
            float bvv[4] = {bb.x, bb.y, bb.z, bb.w};
#pragma unroll
            for (int i = 0; i < 4; i++)
#pragma unroll
                for (int j = 0; j < TN; j++) acc[i][j] = fmaf(av[i], bvv[j], acc[i][j]);
        }
        __syncthreads();
    }
    __hip_bfloat16* ob = (__hip_bfloat16*)Outv;
    float* of = (float*)Outv;
#pragma unroll
    for (int i = 0; i < 4; i++) {
        int gr = rowBase + ty * 4 + i;
        if (gr < N) {
#pragma unroll
            for (int j = 0; j < TN; j++) {
                int c = tx * TN + j;
                size_t o = (size_t)gr * BN + c;
                float v = scale * acc[i][j];
                if (!FIRST) v += isbf ? __bfloat162float(ob[o]) : of[o];
                if (LAST) v += dload(bv, c, isbf);
                if (isbf) ob[o] = __float2bfloat16(v); else of[o] = v;
            }
        }
    }
}

// ---------------- atomic fallbacks (tier B / C) ----------------
__global__ __launch_bounds__(256) void init_deg(float* deg, float* odeg, int N) {
    int i = blockIdx.x * 256 + threadIdx.x;
    if (i < N) { deg[i] = 1.0f; odeg[i] = 0.0f; }
}
__global__ __launch_bounds__(256) void count_deg(const int* __restrict__ row, const int* __restrict__ col,
                                                 float* deg, float* odeg, int E) {
    int e = blockIdx.x * 256 + threadIdx.x;
    if (e < E) {
        atomicAdd(&deg[col[e]], 1.0f);
        atomicAdd(&odeg[row[e]], 1.0f);
    }
}
__global__ __launch_bounds__(256) void deg_to_dinv(float* deg, int N) {
    int i = blockIdx.x * 256 + threadIdx.x;
    if (i < N) deg[i] = rsqrtf(deg[i]);
}
__global__ __launch_bounds__(256) void agg_edges(const int* __restrict__ row, const int* __restrict__ col,
                                                 const float* __restrict__ dinv,
                                                 const float* __restrict__ H,
                                                 float* __restrict__ agg, int E) {
    int e = blockIdx.x * 2 + (threadIdx.x >> 7);
    if (e >= E) return;
    int j = threadIdx.x & 127;
    int s = row[e], d = col[e];
    float w = dinv[s] * dinv[d];
    atomicAdd(&agg[(size_t)d * H_FEATS + j], w * H[(size_t)s * H_FEATS + j]);
}
__global__ __launch_bounds__(256) void mean_edges(const int* __restrict__ row, const int* __restrict__ col,
                                                  const float* __restrict__ h0pre,
                                                  float* __restrict__ nsum, int E) {
    int e = blockIdx.x * 2 + (threadIdx.x >> 7);
    if (e >= E) return;
    int j = threadIdx.x & 127;
    int r = row[e], c = col[e];
    atomicAdd(&nsum[(size_t)r * H_FEATS + j], h0pre[(size_t)c * H_FEATS + j]);
}
__global__ __launch_bounds__(256) void finalize_layer(const float* __restrict__ agg,
                                                      const float* __restrict__ H,
                                                      const float* __restrict__ dinv,
                                                      const void* __restrict__ bv,
                                                      float* __restrict__ hout,
                                                      const int* __restrict__ flagp, int NH) {
    int idx = blockIdx.x * 256 + threadIdx.x;
    if (idx >= NH) return;
    int isbf = *flagp;
    int v = idx >> 7, j = idx & 127;
    float di = dinv[v];
    float h = fmaf(di * di, H[idx], agg[idx]) + dload(bv, j, isbf);
    hout[idx] = fmaxf(h, 0.0f);
}
__global__ __launch_bounds__(256) void finalize_mean(const float* __restrict__ nsum,
                                                     const float* __restrict__ h0pre,
                                                     const float* __restrict__ odeg,
                                                     float* __restrict__ h0, int NH) {
    int idx = blockIdx.x * 256 + threadIdx.x;
    if (idx >= NH) return;
    int v = idx >> 7;
    float od = odeg[v];
    h0[idx] = (od > 0.0f) ? (nsum[idx] / od) : h0pre[idx];
}
__global__ __launch_bounds__(256) void finalize_mean_cnt(const float* __restrict__ nsum,
                                                         const float* __restrict__ h0pre,
                                                         const int* __restrict__ cntr,
                                                         float* __restrict__ h0, int NH) {
    int idx = blockIdx.x * 256 + threadIdx.x;
    if (idx >= NH) return;
    int v = idx >> 7;
    int od = cntr[v];
    h0[idx] = (od > 0) ? (nsum[idx] / (float)od) : h0pre[idx];
}

extern "C" void kernel_launch(void* const* d_in, const int* in_sizes, int n_in,
                              void* d_out, int out_size, void* d_ws, size_t ws_size,
                              hipStream_t stream) {
    const void* x   = d_in[0];
    const int*  ei  = (const int*)d_in[1];
    const void* W1  = d_in[2];
    const void* b1  = d_in[3];
    const void* W2  = d_in[4];
    const void* b2  = d_in[5];
    const void* W3  = d_in[6];
    const void* b3  = d_in[7];
    const void* jkb = d_in[8];
    const void* Wfc = d_in[9];
    const void* bfc = d_in[10];

    const int IN = 256;
    const int N = in_sizes[0] / IN;          // 50000
    const int E = in_sizes[1] / 2;           // 800000
    const int NH = N * H_FEATS;

    const int* row = ei;
    const int* col = ei + E;

    // ---- workspace layout (fp32 words); arrays 16B-aligned ----
    auto a4 = [](size_t v) { return (v + 3) & ~(size_t)3; };
    float* ws = (float*)d_ws;
    size_t o = 0;
    float* meta  = ws + o;           o += 256;
    float* dinv  = ws + o;           o += N;          o = a4(o);
    int*   cntc  = (int*)(ws + o);   o += N;          o = a4(o);
    int*   cntr  = (int*)(ws + o);   o += N;          o = a4(o);
    int*   bsumc = (int*)(ws + o);   o += 256;
    int*   bsumr = (int*)(ws + o);   o += 256;
    int*   coff  = (int*)(ws + o);   o += N + 1;      o = a4(o);
    int*   curc  = (int*)(ws + o);   o += N;          o = a4(o);
    u16*   ecol  = (u16*)(ws + o);   o += E;          o = a4(o);
    size_t oB_small = o;
    int*   roff  = (int*)(ws + o);   o += N + 1;      o = a4(o);
    int*   curr  = (int*)(ws + o);   o += N;          o = a4(o);
    u16*   erow  = (u16*)(ws + o);   o += E;          o = a4(o);
    size_t oA_full = o;

    auto alignup = [](size_t v) { return (v + 63) & ~(size_t)63; };
    const size_t WPW = 16384 + 8192 + 8192 + 4096;   // Wp1 + Wp2 + Wp3 + Wfcp (fp32 words)
    size_t needA = alignup(oA_full) + 2 * (size_t)NH + 64 + WPW;
    size_t needB = alignup(oB_small) + 2 * (size_t)NH + 64 + WPW;

    int tier;
    size_t hoff;
    if (N >= 65536)                { tier = 2; hoff = alignup(256 + 2 * (size_t)N); }
    else if (ws_size >= needA * 4) { tier = 0; hoff = alignup(oA_full); }
    else if (ws_size >= needB * 4) { tier = 1; hoff = alignup(oB_small); }
    else                           { tier = 2; hoff = alignup(256 + 2 * (size_t)N); }
    float* A = ws + hoff;
    float* B = A + NH;
    u16* HbA = (u16*)A;
    u16* HbB = (u16*)B;
    // tier-0 carves four bf16 NH buffers out of the same 2*NH-float region:
    u16* Pb  = (u16*)A;              // P rows (rotating)
    u16* Qb  = Pb + (size_t)NH;      // h0pre, later P2
    u16* H0b = Pb + 2 * (size_t)NH;
    u16* H1b = Pb + 3 * (size_t)NH;
    // CSR-build partials overlay the H0/H1 half (dead until meangemm1):
    unsigned* partC = (unsigned*)H0b;
    unsigned* partR = partC + (size_t)CSR_CH * N;
    size_t wpoff = alignup(hoff + 2 * (size_t)NH);
    u16* Wp1 = (u16*)(ws + wpoff);
    u16* Wp2 = Wp1 + 32768;
    u16* Wp3 = Wp2 + 16384;
    u16* Wfcp = Wp3 + 16384;
    float* odegf = ws + 256 + N;
    const int* flag = (const int*)meta;

    dim3 blk(256);
    int gN = (N + 255) / 256;
    int gE = (E + 255) / 256;
    int gE2 = (E + 1) / 2;
    int gNH = (NH + 255) / 256;
    int gGemm = (N + 63) / 64;
    int gG32 = (N + 31) / 32;
    int gNode8 = (N + 7) / 8;
    int nb = (N + 1023) / 1024;
    // dynamic LDS for count/scatter: max slice width * 4B
    size_t shb = (size_t)((N + CSR_SL - 1) / CSR_SL) * 4;

    if (tier == 0) {
        // ---- atomic-free CSR build (XCD-local block order) ----
        count_partial<<<CSR_NSC + 1, blk, shb, stream>>>(row, col, partC, partR, E, N,
                                                         (const unsigned int*)x, jkb, meta);
        pack_all<<<36, blk, 0, stream>>>(W1, W2, W3, Wfc, Wp1, Wp2, Wp3, Wfcp, flag);
        reduce_bsum<<<dim3(nb, 2), blk, 0, stream>>>(partC, partR, cntc, cntr, bsumc, bsumr, N);
        scan_bsum_scan<<<2, blk, 0, stream>>>(bsumc, bsumr, &coff[N], &roff[N], nb);
        scan_final<<<dim3(nb, 2), blk, 0, stream>>>(cntc, cntr, bsumc, bsumr,
                                                    coff, curc, roff, curr,
                                                    partC, partR, dinv, N);

        // ---- fused: scatter + layer-0 GEMM (P0 = dinv .* (x@W1)) ----
        scatter_gemm0<<<CSR_NSC + gGemm, blk, shb, stream>>>(row, col, partC, partR, ecol, erow,
                                                             E, N, x, Wp1, Pb, dinv, flag);

        // ---- h0pre = relu(dd*(P0[d]+sum P0[s]) + b1) ----
        agg_sum<<<gNode8, blk, 0, stream>>>(coff, ecol, dinv, Pb, b1, Qb, flag, N);

        // ---- fused mean + gemm1: h0 -> H0b, P1 = dinv.(h0@W2) -> Pb ----
        agg_gemm<1><<<gG32, blk, 0, stream>>>(roff, erow, dinv, Qb, b1, Wp2, H0b, Pb, flag, N);

        // ---- fused agg + gemm2: h1 -> H1b, P2 = dinv.(h1@W3) -> Qb ----
        agg_gemm<0><<<gG32, blk, 0, stream>>>(coff, ecol, dinv, Pb, b2, Wp3, H1b, Qb, flag, N);

        // ---- fused agg + jk + MFMA fc: h2 (LDS only) + out ----
        agg_fc3<<<gG32, blk, 0, stream>>>(coff, ecol, dinv, Qb, b3, H0b, H1b,
                                          Wfcp, bfc, d_out, meta, N);
    } else if (tier == 1) {
        // ---- tier B: legacy atomic CSR build (col only) + fp32 mean path ----
        hipMemsetAsync(cntc, 0, 2 * (size_t)N * 4, stream);
        histo_sniff<<<gE + 1, blk, 0, stream>>>(row, col, cntc, cntr, E,
                                                (const unsigned int*)x, jkb, meta);
        const int T = 4;
        int step = (N + T - 1) / T;
        scan_bsum<<<dim3(nb, 1), blk, 0, stream>>>(cntc, cntc, bsumc, bsumc, N);
        scan_bsum_scan<<<1, blk, 0, stream>>>(bsumc, bsumc, &coff[N], &coff[N], nb);
        scan_final<<<dim3(nb, 1), blk, 0, stream>>>(cntc, cntc, bsumc, bsumc,
                                                    coff, curc, coff, curc,
                                                    (unsigned*)0, (unsigned*)0, dinv, N);
        for (int t = 0; t < T; t++) {
            int lo = t * step, hi = lo + step; if (hi > N) hi = N;
            scatter_tile<<<gE, blk, 0, stream>>>(row, col, curc, curc, ecol, ecol, E, lo, hi, 0);
        }

        pack_all<<<36, blk, 0, stream>>>(W1, W2, W3, Wfc, Wp1, Wp2, Wp3, Wfcp, flag);

        gemm_mfma<256, true, false, false><<<gGemm, blk, 0, stream>>>(x, Wp1, HbA, dinv, flag, N);
        agg_gather3b<false><<<gNode8, blk, 0, stream>>>(coff, ecol, dinv, HbA, b1, B, flag, N);
        hipMemsetAsync(A, 0, (size_t)NH * 4, stream);
        mean_edges<<<gE2, blk, 0, stream>>>(row, col, B, A, E);
        finalize_mean_cnt<<<gNH, blk, 0, stream>>>(A, B, cntr, A, NH);
        fc_accum<true, false, false><<<gGemm, blk, 0, stream>>>(A, Wfc, bfc, d_out, meta, 0, N);

        gemm_mfma<128, false, false, false><<<gGemm, blk, 0, stream>>>(A, Wp2, HbB, dinv, flag, N);
        agg_gather3b<true><<<gNode8, blk, 0, stream>>>(coff, ecol, dinv, HbB, b2, HbA, flag, N);
        fc_accum<false, false, true><<<gGemm, blk, 0, stream>>>(HbA, Wfc, bfc, d_out, meta, 1, N);

        gemm_mfma<128, false, true, false><<<gGemm, blk, 0, stream>>>(HbA, Wp3, HbB, dinv, flag, N);
        agg_gather3b<true><<<gNode8, blk, 0, stream>>>(coff, ecol, dinv, HbB, b3, HbA, flag, N);
        fc_accum<false, true, true><<<gGemm, blk, 0, stream>>>(HbA, Wfc, bfc, d_out, meta, 2, N);
    } else {
        // ---- tier C: fp32 atomic path ----
        sniff_jkw<<<1, blk, 0, stream>>>((const unsigned int*)x, jkb, meta);
        init_deg<<<gN, blk, 0, stream>>>(dinv, odegf, N);
        count_deg<<<gE, blk, 0, stream>>>(row, col, dinv, odegf, E);
        deg_to_dinv<<<gN, blk, 0, stream>>>(dinv, N);

        gemm128<256, true, false, false><<<gGemm, blk, 0, stream>>>(x, W1, A, flag, N);
        hipMemsetAsync(B, 0, (size_t)NH * 4, stream);
        agg_edges<<<gE2, blk, 0, stream>>>(row, col, dinv, A, B, E);
        finalize_layer<<<gNH, blk, 0, stream>>>(B, A, dinv, b1, B, flag, NH);
        hipMemsetAsync(A, 0, (size_t)NH * 4, stream);
        mean_edges<<<gE2, blk, 0, stream>>>(row, col, B, A, E);
        finalize_mean<<<gNH, blk, 0, stream>>>(A, B, odegf, A, NH);
        fc_accum<true, false, false><<<gGemm, blk, 0, stream>>>(A, Wfc, bfc, d_out, meta, 0, N);

        gemm128<128, false, false, false><<<gGemm, blk, 0, stream>>>(A, W2, B, flag, N);
        hipMemsetAsync(A, 0, (size_t)NH * 4, stream);
        agg_edges<<<gE2, blk, 0, stream>>>(row, col, dinv, B, A, E);
        finalize_layer<<<gNH, blk, 0, stream>>>(A, B, dinv, b2, A, flag, NH);
        fc_accum<false, false, false><<<gGemm, blk, 0, stream>>>(A, Wfc, bfc, d_out, meta, 1, N);

        gemm128<128, false, false, false><<<gGemm, blk, 0, stream>>>(A, W3, B, flag, N);
        hipMemsetAsync(A, 0, (size_t)NH * 4, stream);
        agg_edges<<<gE2, blk, 0, stream>>>(row, col, dinv, B, A, E);
        finalize_layer<<<gNH, blk, 0, stream>>>(A, B, dinv, b3, A, flag, NH);
        fc_accum<false, true, false><<<gGemm, blk, 0, stream>>>(A, Wfc, bfc, d_out, meta, 2, N);
    }
}

// Round 12
// 390.108 us; speedup vs baseline: 1.0829x; 1.0172x over previous
//
#include <hip/hip_runtime.h>
#include <hip/hip_bf16.h>

// DynamicJKGCN on MI355X — round 24: launch diet on the serial CSR chain.
// Round-23 (396.8us = best): 32-row fused tiles + dynamic LDS paid ~9us.
// scatter_gemm0 confirmed traffic-bound (112MB @ 1.87TB/s ~= 61.5us); gathers
// near the random-row fabric floor. Remaining: serial small-kernel overhead.
// This round:
//  1) pack merged into count_partial's grid (blocks NSC+1..NSC+36); pack blocks
//     compute isbf via a local in-block sniff (no meta race).
//  2) scan_bsum_scan eliminated: reduce_bsum writes RAW block sums; scan_final
//     inline-scans the <=64 sums in LDS for its base; block 0 writes off[N].
//     Tier B switched to the same scheme.
// Heavy kernels untouched. Tier C unchanged.

#define H_FEATS 128
#define TPAD 136

typedef __attribute__((ext_vector_type(8))) short short8;
typedef __attribute__((ext_vector_type(4))) float float4v;
typedef unsigned short u16;

__device__ __forceinline__ float dload(const void* p, size_t i, int isbf) {
    return isbf ? __bfloat162float(((const __hip_bfloat16*)p)[i])
                : ((const float*)p)[i];
}

__device__ __forceinline__ float4 load4bf(const u16* p) {
    uint2 u = *(const uint2*)p;
    float4 f;
    f.x = __uint_as_float((u.x & 0xFFFFu) << 16);
    f.y = __uint_as_float(u.x & 0xFFFF0000u);
    f.z = __uint_as_float((u.y & 0xFFFFu) << 16);
    f.w = __uint_as_float(u.y & 0xFFFF0000u);
    return f;
}

__device__ __forceinline__ float bf2f(u16 h) {
    return __uint_as_float((unsigned)h << 16);
}

__device__ __forceinline__ u16 f2bf(float v) {
    return __bfloat16_as_ushort(__float2bfloat16(v));
}

__device__ __forceinline__ void add8(float* a, uint4 u) {
    a[0] += __uint_as_float((u.x & 0xFFFFu) << 16);
    a[1] += __uint_as_float(u.x & 0xFFFF0000u);
    a[2] += __uint_as_float((u.y & 0xFFFFu) << 16);
    a[3] += __uint_as_float(u.y & 0xFFFF0000u);
    a[4] += __uint_as_float((u.z & 0xFFFFu) << 16);
    a[5] += __uint_as_float(u.z & 0xFFFF0000u);
    a[6] += __uint_as_float((u.w & 0xFFFFu) << 16);
    a[7] += __uint_as_float(u.w & 0xFFFF0000u);
}

__device__ __forceinline__ void set8(float* a, uint4 u) {
    a[0] = __uint_as_float((u.x & 0xFFFFu) << 16);
    a[1] = __uint_as_float(u.x & 0xFFFF0000u);
    a[2] = __uint_as_float((u.y & 0xFFFFu) << 16);
    a[3] = __uint_as_float(u.y & 0xFFFF0000u);
    a[4] = __uint_as_float((u.z & 0xFFFFu) << 16);
    a[5] = __uint_as_float(u.z & 0xFFFF0000u);
    a[6] = __uint_as_float((u.w & 0xFFFFu) << 16);
    a[7] = __uint_as_float(u.w & 0xFFFF0000u);
}

__device__ __forceinline__ uint4 pack8(const float* f) {
    uint4 r;
    r.x = (unsigned)f2bf(f[0]) | ((unsigned)f2bf(f[1]) << 16);
    r.y = (unsigned)f2bf(f[2]) | ((unsigned)f2bf(f[3]) << 16);
    r.z = (unsigned)f2bf(f[4]) | ((unsigned)f2bf(f[5]) << 16);
    r.w = (unsigned)f2bf(f[6]) | ((unsigned)f2bf(f[7]) << 16);
    return r;
}

// ---------------- dtype sniff + jk softmax ----------------
__device__ __forceinline__ void sniff_body(const unsigned int* __restrict__ x,
                                           const void* __restrict__ jkwb,
                                           float* __restrict__ meta) {
    __shared__ int cnt[256];
    int t = threadIdx.x;
    int c = 0;
    for (int i = 0; i < 16; i++) {
        unsigned int w = x[t * 16 + i];
        unsigned int e = (w >> 7) & 0xFFu;
        c += (e >= 0x60u && e <= 0x8Fu) ? 1 : 0;
    }
    cnt[t] = c;
    __syncthreads();
    for (int s = 128; s > 0; s >>= 1) {
        if (t < s) cnt[t] += cnt[t + s];
        __syncthreads();
    }
    if (t == 0) {
        int isbf = (cnt[0] > 3000) ? 1 : 0;
        ((int*)meta)[0] = isbf;
        float w0 = dload(jkwb, 0, isbf);
        float w1 = dload(jkwb, 1, isbf);
        float w2 = dload(jkwb, 2, isbf);
        float m = fmaxf(w0, fmaxf(w1, w2));
        float e0 = expf(w0 - m), e1 = expf(w1 - m), e2 = expf(w2 - m);
        float s = e0 + e1 + e2;
        meta[8] = e0 / s; meta[9] = e1 / s; meta[10] = e2 / s;
    }
}

// per-block local sniff (no meta write; all threads get isbf)
__device__ __forceinline__ int sniff_local(const unsigned int* __restrict__ x) {
    __shared__ int cnt2[256];
    int t = threadIdx.x;
    int c = 0;
    for (int i = 0; i < 16; i++) {
        unsigned int w = x[t * 16 + i];
        unsigned int e = (w >> 7) & 0xFFu;
        c += (e >= 0x60u && e <= 0x8Fu) ? 1 : 0;
    }
    cnt2[t] = c;
    __syncthreads();
    for (int s = 128; s > 0; s >>= 1) {
        if (t < s) cnt2[t] += cnt2[t + s];
        __syncthreads();
    }
    int isbf = (cnt2[0] > 3000) ? 1 : 0;
    __syncthreads();
    return isbf;
}

__global__ __launch_bounds__(256) void sniff_jkw(const unsigned int* __restrict__ x,
                                                 const void* __restrict__ jkwb,
                                                 float* __restrict__ meta) {
    sniff_body(x, jkwb, meta);
}

// ---------------- W prepack body (shared by fused + standalone) ----------------
__device__ __forceinline__ void pack_body(int bid,
                                          const void* __restrict__ W1,
                                          const void* __restrict__ W2,
                                          const void* __restrict__ W3,
                                          const void* __restrict__ Wf,
                                          u16* __restrict__ Wp1,
                                          u16* __restrict__ Wp2,
                                          u16* __restrict__ Wp3,
                                          u16* __restrict__ Wfp,
                                          int isbf) {
    const void* W; u16* Wp; int K, C, gid;
    if (bid < 16)      { W = W1; Wp = Wp1; K = 256; C = 128; gid = bid * 256 + threadIdx.x; }
    else if (bid < 24) { W = W2; Wp = Wp2; K = 128; C = 128; gid = (bid - 16) * 256 + threadIdx.x; }
    else if (bid < 32) { W = W3; Wp = Wp3; K = 128; C = 128; gid = (bid - 24) * 256 + threadIdx.x; }
    else               { W = Wf; Wp = Wfp; K = 128; C = 64;  gid = (bid - 32) * 256 + threadIdx.x; }
    int tiles = C >> 4;
    int steps = K >> 5;
    if (gid >= steps * tiles * 64) return;
    int lane = gid & 63;
    int tt = (gid >> 6) % tiles;
    int s = (gid >> 6) / tiles;
    int krow = s * 32 + ((lane >> 4) << 3);
    int ncol = tt * 16 + (lane & 15);
#pragma unroll
    for (int j = 0; j < 8; j++) {
        float v = dload(W, (size_t)(krow + j) * C + ncol, isbf);
        Wp[(size_t)gid * 8 + j] = f2bf(v);
    }
}

__global__ __launch_bounds__(256) void pack_all(const void* __restrict__ W1,
                                                const void* __restrict__ W2,
                                                const void* __restrict__ W3,
                                                const void* __restrict__ Wf,
                                                u16* __restrict__ Wp1,
                                                u16* __restrict__ Wp2,
                                                u16* __restrict__ Wp3,
                                                u16* __restrict__ Wfp,
                                                const int* __restrict__ flagp) {
    pack_body(blockIdx.x, W1, W2, W3, Wf, Wp1, Wp2, Wp3, Wfp, *flagp);
}

// ---------------- atomic-free CSR build (tier 0) ----------------
#define CSR_CH 64
#define CSR_SL 8
#define CSR_NSC (CSR_CH * CSR_SL * 2)

// fused: count (blocks [0,NSC)) + sniff (NSC) + pack (NSC+1 .. NSC+36)
__global__ __launch_bounds__(256) void count_partial(const int* __restrict__ row,
                                                     const int* __restrict__ col,
                                                     unsigned* __restrict__ partC,
                                                     unsigned* __restrict__ partR,
                                                     int E, int N,
                                                     const unsigned int* __restrict__ x,
                                                     const void* __restrict__ jkwb,
                                                     float* __restrict__ meta,
                                                     const void* __restrict__ W1,
                                                     const void* __restrict__ W2,
                                                     const void* __restrict__ W3,
                                                     const void* __restrict__ Wf,
                                                     u16* __restrict__ Wp1,
                                                     u16* __restrict__ Wp2,
                                                     u16* __restrict__ Wp3,
                                                     u16* __restrict__ Wfp) {
    int b = blockIdx.x;
    if (b == CSR_NSC) { sniff_body(x, jkwb, meta); return; }
    if (b > CSR_NSC) {
        int isbf = sniff_local(x);
        pack_body(b - CSR_NSC - 1, W1, W2, W3, Wf, Wp1, Wp2, Wp3, Wfp, isbf);
        return;
    }
    extern __shared__ unsigned cnt[];
    int dir = b >> 9;
    int r = b & 511;
    int sl = r >> 6;
    int k  = r & 63;
    const int* arr = dir ? row : col;
    unsigned* part = (dir ? partR : partC) + (size_t)k * N;
    int lo = (int)(((long long)N * sl) >> 3);
    int hi = (int)(((long long)N * (sl + 1)) >> 3);
    int wid = hi - lo;

    for (int i = threadIdx.x; i < wid; i += 256) cnt[i] = 0;
    __syncthreads();

    int e0 = (int)(((long long)E * k) >> 6);
    int e1 = (int)(((long long)E * (k + 1)) >> 6);
    for (int e = e0 + threadIdx.x; e < e1; e += 256) {
        int d = arr[e] - lo;
        if ((unsigned)d < (unsigned)wid) atomicAdd(&cnt[d], 1u);
    }
    __syncthreads();
    for (int i = threadIdx.x; i < wid; i += 256) part[lo + i] = cnt[i];
}

// Fused: cnt[i] = sum_k part[k][i]  AND  RAW per-1024-block sums.
__global__ __launch_bounds__(256) void reduce_bsum(const unsigned* __restrict__ partC,
                                                   const unsigned* __restrict__ partR,
                                                   int* __restrict__ cntc,
                                                   int* __restrict__ cntr,
                                                   int* __restrict__ b0,
                                                   int* __restrict__ b1, int N) {
    const unsigned* p = blockIdx.y ? partR : partC;
    int* cnt = blockIdx.y ? cntr : cntc;
    int* bs = blockIdx.y ? b1 : b0;
    int base = blockIdx.x * 1024 + threadIdx.x * 4;
    unsigned v0 = 0, v1 = 0, v2 = 0, v3 = 0;
    if (base + 3 < N) {
        for (int k = 0; k < CSR_CH; k++) {
            uint4 u = *(const uint4*)(p + (size_t)k * N + base);
            v0 += u.x; v1 += u.y; v2 += u.z; v3 += u.w;
        }
        int4 w = {(int)v0, (int)v1, (int)v2, (int)v3};
        *(int4*)&cnt[base] = w;
    } else {
        unsigned vv[4] = {0, 0, 0, 0};
        for (int k = 0; k < CSR_CH; k++)
            for (int i = 0; i < 4; i++)
                if (base + i < N) vv[i] += p[(size_t)k * N + base + i];
        for (int i = 0; i < 4; i++) if (base + i < N) cnt[base + i] = (int)vv[i];
        v0 = vv[0]; v1 = vv[1]; v2 = vv[2]; v3 = vv[3];
    }
    int s = (int)(v0 + v1 + v2 + v3);
    __shared__ int red[256];
    red[threadIdx.x] = s;
    __syncthreads();
    for (int d = 128; d > 0; d >>= 1) {
        if (threadIdx.x < d) red[threadIdx.x] += red[threadIdx.x + d];
        __syncthreads();
    }
    if (threadIdx.x == 0) bs[blockIdx.x] = red[0];
}

// single-pass scatter body: LDS cursors seeded from bases; 0 global atomics.
__device__ __forceinline__ void scatter_body(int b,
                                             const int* __restrict__ row,
                                             const int* __restrict__ col,
                                             const unsigned* __restrict__ partC,
                                             const unsigned* __restrict__ partR,
                                             u16* __restrict__ ecol,
                                             u16* __restrict__ erow,
                                             int E, int N,
                                             unsigned* __restrict__ cur) {
    int dir = b >> 9;
    int r = b & 511;
    int sl = r >> 6;
    int k  = r & 63;
    const int* darr = dir ? row : col;
    const int* sarr = dir ? col : row;
    u16* out = dir ? erow : ecol;
    const unsigned* base = (dir ? partR : partC) + (size_t)k * N;
    int lo = (int)(((long long)N * sl) >> 3);
    int hi = (int)(((long long)N * (sl + 1)) >> 3);
    int wid = hi - lo;

    for (int i = threadIdx.x; i < wid; i += 256) cur[i] = base[lo + i];
    __syncthreads();

    int e0 = (int)(((long long)E * k) >> 6);
    int e1 = (int)(((long long)E * (k + 1)) >> 6);
    for (int e = e0 + threadIdx.x; e < e1; e += 256) {
        int d = darr[e] - lo;
        if ((unsigned)d < (unsigned)wid) {
            unsigned p = atomicAdd(&cur[d], 1u);
            out[p] = (u16)sarr[e];
        }
    }
}

// ---------------- legacy CSR build (tier B fallback) ----------------
__global__ __launch_bounds__(256) void histo_sniff(const int* __restrict__ row, const int* __restrict__ col,
                                                   int* __restrict__ cntc, int* __restrict__ cntr, int E,
                                                   const unsigned int* __restrict__ x,
                                                   const void* __restrict__ jkwb,
                                                   float* __restrict__ meta) {
    if (blockIdx.x == gridDim.x - 1) {
        sniff_body(x, jkwb, meta);
        return;
    }
    int e = blockIdx.x * 256 + threadIdx.x;
    if (e < E) {
        atomicAdd(&cntc[col[e]], 1);
        atomicAdd(&cntr[row[e]], 1);
    }
}

__global__ __launch_bounds__(256) void scan_bsum(const int* __restrict__ c0, const int* __restrict__ c1,
                                                 int* __restrict__ b0, int* __restrict__ b1, int N) {
    const int* cnt = blockIdx.y ? c1 : c0;
    int* bs = blockIdx.y ? b1 : b0;
    int base = blockIdx.x * 1024 + threadIdx.x * 4;
    int s = 0;
    if (base + 3 < N) {
        int4 v = *(const int4*)&cnt[base];
        s = v.x + v.y + v.z + v.w;
    } else {
        for (int i = 0; i < 4; i++) if (base + i < N) s += cnt[base + i];
    }
    __shared__ int red[256];
    red[threadIdx.x] = s;
    __syncthreads();
    for (int d = 128; d > 0; d >>= 1) {
        if (threadIdx.x < d) red[threadIdx.x] += red[threadIdx.x + d];
        __syncthreads();
    }
    if (threadIdx.x == 0) bs[blockIdx.x] = red[0];
}

// scan_final: inline-scans RAW block sums; offsets + dinv (y==0) + fused
// prefix over partials (when given); block 0 writes off[N].
__global__ __launch_bounds__(256) void scan_final(const int* __restrict__ c0, const int* __restrict__ c1,
                                                  const int* __restrict__ b0, const int* __restrict__ b1,
                                                  int* __restrict__ o0, int* __restrict__ u0,
                                                  int* __restrict__ o1, int* __restrict__ u1,
                                                  unsigned* __restrict__ pc,
                                                  unsigned* __restrict__ pr,
                                                  float* __restrict__ dinvp, int N) {
    const int* cnt = blockIdx.y ? c1 : c0;
    const int* bs  = blockIdx.y ? b1 : b0;
    int* off = blockIdx.y ? o1 : o0;
    int* cur = blockIdx.y ? u1 : u0;
    unsigned* part = blockIdx.y ? pr : pc;
    int t = threadIdx.x;
    int nb = gridDim.x;
    __shared__ int sh[256];

    // inline scan of raw per-block sums -> myBase, total
    sh[t] = (t < nb) ? bs[t] : 0;
    __syncthreads();
    for (int d = 1; d < 256; d <<= 1) {
        int u = (t >= d) ? sh[t - d] : 0;
        __syncthreads();
        sh[t] += u;
        __syncthreads();
    }
    int myBase = (blockIdx.x == 0) ? 0 : sh[blockIdx.x - 1];
    int total = sh[255];
    __syncthreads();
    if (blockIdx.x == 0 && t == 0) off[N] = total;

    int base = blockIdx.x * 1024 + t * 4;
    int4 v = {0, 0, 0, 0};
    if (base + 3 < N) {
        v = *(const int4*)&cnt[base];
    } else {
        int tmp[4] = {0, 0, 0, 0};
        for (int i = 0; i < 4; i++) if (base + i < N) tmp[i] = cnt[base + i];
        v.x = tmp[0]; v.y = tmp[1]; v.z = tmp[2]; v.w = tmp[3];
    }
    if (blockIdx.y == 0) {
        if (base + 3 < N) {
            float4 dv;
            dv.x = rsqrtf(1.0f + (float)v.x);
            dv.y = rsqrtf(1.0f + (float)v.y);
            dv.z = rsqrtf(1.0f + (float)v.z);
            dv.w = rsqrtf(1.0f + (float)v.w);
            *(float4*)&dinvp[base] = dv;
        } else {
            int vv[4] = {v.x, v.y, v.z, v.w};
            for (int i = 0; i < 4; i++)
                if (base + i < N) dinvp[base + i] = rsqrtf(1.0f + (float)vv[i]);
        }
    }
    int s = v.x + v.y + v.z + v.w;
    sh[t] = s;
    __syncthreads();
    for (int d = 1; d < 256; d <<= 1) {
        int u = (t >= d) ? sh[t - d] : 0;
        __syncthreads();
        sh[t] += u;
        __syncthreads();
    }
    int ex = myBase + ((t == 0) ? 0 : sh[t - 1]);
    int4 o;
    o.x = ex; o.y = ex + v.x; o.z = o.y + v.y; o.w = o.z + v.z;
    if (base + 3 < N) {
        *(int4*)&off[base] = o;
        *(int4*)&cur[base] = o;
        if (part) {
            unsigned a0 = (unsigned)o.x, a1 = (unsigned)o.y,
                     a2 = (unsigned)o.z, a3 = (unsigned)o.w;
            for (int k = 0; k < CSR_CH; k++) {
                unsigned* pp = part + (size_t)k * N + base;
                uint4 u = *(const uint4*)pp;
                uint4 w = {a0, a1, a2, a3};
                *(uint4*)pp = w;
                a0 += u.x; a1 += u.y; a2 += u.z; a3 += u.w;
            }
        }
    } else {
        int arr[4] = {o.x, o.y, o.z, o.w};
        for (int i = 0; i < 4; i++) if (base + i < N) { off[base + i] = arr[i]; cur[base + i] = arr[i]; }
        if (part) {
            for (int i = 0; i < 4; i++) {
                if (base + i >= N) continue;
                unsigned acc = (unsigned)arr[i];
                for (int k = 0; k < CSR_CH; k++) {
                    unsigned* pp = part + (size_t)k * N + base + i;
                    unsigned tv = *pp;
                    *pp = acc;
                    acc += tv;
                }
            }
        }
    }
}

__global__ __launch_bounds__(256) void scatter_tile(const int* __restrict__ row, const int* __restrict__ col,
                                                    int* __restrict__ curc, int* __restrict__ curr,
                                                    u16* __restrict__ ecol, u16* __restrict__ erow,
                                                    int E, int lo, int hi, int doRow) {
    int e = blockIdx.x * 256 + threadIdx.x;
    if (e >= E) return;
    int s = row[e], d = col[e];
    if (d >= lo && d < hi) {
        int p = atomicAdd(&curc[d], 1);
        ecol[p] = (u16)s;
    }
    if (doRow && s >= lo && s < hi) {
        int q = atomicAdd(&curr[s], 1);
        erow[q] = (u16)d;
    }
}

// ---------------- MFMA GEMM body (global A) ----------------
template <int K, bool RTBF, bool BFIN, bool SCALE>
__device__ __forceinline__ void gemm_mfma_body(int bid, const void* __restrict__ Xv,
                                               const u16* __restrict__ Wp,
                                               u16* __restrict__ Cb,
                                               const float* __restrict__ dinv,
                                               const int* __restrict__ flagp, int M) {
    const int isbf = RTBF ? *flagp : (BFIN ? 1 : 0);
    const int tid = threadIdx.x;
    const int wave = tid >> 6, lane = tid & 63;
    const int m16 = lane & 15, quad = lane >> 4;
    const int row = bid * 64 + wave * 16 + m16;
    constexpr int STEPS = K / 32;

    float4v acc[8];
#pragma unroll
    for (int t = 0; t < 8; t++) acc[t] = (float4v){0.f, 0.f, 0.f, 0.f};

    const bool rowOK = row < M;
#pragma unroll
    for (int s = 0; s < STEPS; s++) {
        int k0 = s * 32 + quad * 8;
        short8 a = (short8)(short)0;
        if (rowOK) {
            if (isbf) {
                a = *(const short8*)((const u16*)Xv + (size_t)row * K + k0);
            } else {
                const float* p = (const float*)Xv + (size_t)row * K + k0;
                float4 f0 = *(const float4*)p;
                float4 f1 = *(const float4*)(p + 4);
                a[0] = (short)f2bf(f0.x); a[1] = (short)f2bf(f0.y);
                a[2] = (short)f2bf(f0.z); a[3] = (short)f2bf(f0.w);
                a[4] = (short)f2bf(f1.x); a[5] = (short)f2bf(f1.y);
                a[6] = (short)f2bf(f1.z); a[7] = (short)f2bf(f1.w);
            }
        }
#pragma unroll
        for (int t = 0; t < 8; t++) {
            short8 b = *(const short8*)(Wp + ((size_t)(s * 8 + t) * 64 + lane) * 8);
            acc[t] = __builtin_amdgcn_mfma_f32_16x16x32_bf16(a, b, acc[t], 0, 0, 0);
        }
    }
#pragma unroll
    for (int r = 0; r < 4; r++) {
        int gr = bid * 64 + wave * 16 + quad * 4 + r;
        if (gr < M) {
            float sc = SCALE ? dinv[gr] : 1.0f;
#pragma unroll
            for (int t = 0; t < 8; t++) {
                size_t o = (size_t)gr * H_FEATS + t * 16 + m16;
                Cb[o] = f2bf(sc * acc[t][r]);
            }
        }
    }
}

template <int K, bool RTBF, bool BFIN, bool SCALE>
__global__ __launch_bounds__(256) void gemm_mfma(const void* __restrict__ Xv,
                                                 const u16* __restrict__ Wp,
                                                 u16* __restrict__ Cb,
                                                 const float* __restrict__ dinv,
                                                 const int* __restrict__ flagp, int M) {
    gemm_mfma_body<K, RTBF, BFIN, SCALE>(blockIdx.x, Xv, Wp, Cb, dinv, flagp, M);
}

// ---------------- fused: scatter (blocks [0,NSC)) + gemm L0 (rest) ----------------
__global__ __launch_bounds__(256) void scatter_gemm0(const int* __restrict__ row,
                                                     const int* __restrict__ col,
                                                     const unsigned* __restrict__ partC,
                                                     const unsigned* __restrict__ partR,
                                                     u16* __restrict__ ecol,
                                                     u16* __restrict__ erow,
                                                     int E, int N,
                                                     const void* __restrict__ Xv,
                                                     const u16* __restrict__ Wp,
                                                     u16* __restrict__ Pb,
                                                     const float* __restrict__ dinv,
                                                     const int* __restrict__ flagp) {
    extern __shared__ unsigned cur[];
    if (blockIdx.x < CSR_NSC) {
        scatter_body(blockIdx.x, row, col, partC, partR, ecol, erow, E, N, cur);
    } else {
        gemm_mfma_body<256, true, false, true>(blockIdx.x - CSR_NSC, Xv, Wp, Pb, dinv, flagp, N);
    }
}

// ---------------- standalone tier-0 gather (L0): 32-lane/8B, depth-4 (proven) ----------------
__global__ __launch_bounds__(256) void agg_sum(const int* __restrict__ off,
                                               const u16* __restrict__ idx,
                                               const float* __restrict__ dinv,
                                               const u16* __restrict__ Pb,
                                               const void* __restrict__ bv,
                                               u16* __restrict__ hout,
                                               const int* __restrict__ flagp, int N) {
    int node = blockIdx.x * 8 + (threadIdx.x >> 5);
    if (node >= N) return;
    int l = threadIdx.x & 31;
    int isbf = *flagp;
    int beg = off[node], end = off[node + 1];
    size_t ro = (size_t)l * 4;

    float4 acc = load4bf(&Pb[(size_t)node * H_FEATS + ro]);

    const float4 z = {0.f, 0.f, 0.f, 0.f};
    int i = beg;
    int s0 = (i     < end) ? (int)idx[i]     : 0;
    int s1 = (i + 1 < end) ? (int)idx[i + 1] : 0;
    int s2 = (i + 2 < end) ? (int)idx[i + 2] : 0;
    int s3 = (i + 3 < end) ? (int)idx[i + 3] : 0;
    float4 h0 = (i     < end) ? load4bf(&Pb[(size_t)s0 * H_FEATS + ro]) : z;
    float4 h1 = (i + 1 < end) ? load4bf(&Pb[(size_t)s1 * H_FEATS + ro]) : z;
    float4 h2 = (i + 2 < end) ? load4bf(&Pb[(size_t)s2 * H_FEATS + ro]) : z;
    float4 h3 = (i + 3 < end) ? load4bf(&Pb[(size_t)s3 * H_FEATS + ro]) : z;
    for (; i + 4 < end; i += 4) {
        int t0 = (int)idx[i + 4];
        int t1 = (i + 5 < end) ? (int)idx[i + 5] : 0;
        int t2 = (i + 6 < end) ? (int)idx[i + 6] : 0;
        int t3 = (i + 7 < end) ? (int)idx[i + 7] : 0;
        float4 n0 = load4bf(&Pb[(size_t)t0 * H_FEATS + ro]);
        float4 n1 = (i + 5 < end) ? load4bf(&Pb[(size_t)t1 * H_FEATS + ro]) : z;
        float4 n2 = (i + 6 < end) ? load4bf(&Pb[(size_t)t2 * H_FEATS + ro]) : z;
        float4 n3 = (i + 7 < end) ? load4bf(&Pb[(size_t)t3 * H_FEATS + ro]) : z;
        acc.x += (h0.x + h1.x) + (h2.x + h3.x);
        acc.y += (h0.y + h1.y) + (h2.y + h3.y);
        acc.z += (h0.z + h1.z) + (h2.z + h3.z);
        acc.w += (h0.w + h1.w) + (h2.w + h3.w);
        h0 = n0; h1 = n1; h2 = n2; h3 = n3;
    }
    acc.x += (h0.x + h1.x) + (h2.x + h3.x);
    acc.y += (h0.y + h1.y) + (h2.y + h3.y);
    acc.z += (h0.z + h1.z) + (h2.z + h3.z);
    acc.w += (h0.w + h1.w) + (h2.w + h3.w);

    float dd = dinv[node];
    acc.x = fmaxf(fmaf(dd, acc.x, dload(bv, l * 4 + 0, isbf)), 0.0f);
    acc.y = fmaxf(fmaf(dd, acc.y, dload(bv, l * 4 + 1, isbf)), 0.0f);
    acc.z = fmaxf(fmaf(dd, acc.z, dload(bv, l * 4 + 2, isbf)), 0.0f);
    acc.w = fmaxf(fmaf(dd, acc.w, dload(bv, l * 4 + 3, isbf)), 0.0f);
    uint2 pk;
    pk.x = (unsigned)f2bf(acc.x) | ((unsigned)f2bf(acc.y) << 16);
    pk.y = (unsigned)f2bf(acc.z) | ((unsigned)f2bf(acc.w) << 16);
    *(uint2*)&hout[(size_t)node * H_FEATS + ro] = pk;
}

// ---------------- fused gather-tile helper: 32-row tile, 16 lanes/row, uint4, depth-4 ----------------
template <int MODE, bool WRITEG>
__device__ __forceinline__ void gather_tile(int bid,
                                            const int* __restrict__ off,
                                            const u16* __restrict__ idx,
                                            const float* __restrict__ dinv,
                                            const u16* __restrict__ Src,
                                            const void* __restrict__ bv, int isbf,
                                            u16* __restrict__ Hg,
                                            u16* __restrict__ tile, int N) {
    int lane16 = threadIdx.x & 15;
    int rloc = threadIdx.x >> 4;
    int co = lane16 * 8;
    const uint4 zz = {0u, 0u, 0u, 0u};
#pragma unroll
    for (int pass = 0; pass < 2; ++pass) {
        int r = pass * 16 + rloc;
        int gr = bid * 32 + r;
        uint4* ldst = (uint4*)(tile + (size_t)r * TPAD + co);
        if (gr >= N) { *ldst = zz; continue; }
        int beg = off[gr], end = off[gr + 1];
        float acc[8];
        if (MODE == 0) {
            uint4 u = *(const uint4*)(Src + (size_t)gr * H_FEATS + co);
            set8(acc, u);
        } else {
#pragma unroll
            for (int j = 0; j < 8; j++) acc[j] = 0.0f;
        }
        int i = beg;
        int s0 = (i     < end) ? (int)idx[i]     : 0;
        int s1 = (i + 1 < end) ? (int)idx[i + 1] : 0;
        int s2 = (i + 2 < end) ? (int)idx[i + 2] : 0;
        int s3 = (i + 3 < end) ? (int)idx[i + 3] : 0;
        uint4 h0 = (i     < end) ? *(const uint4*)(Src + (size_t)s0 * H_FEATS + co) : zz;
        uint4 h1 = (i + 1 < end) ? *(const uint4*)(Src + (size_t)s1 * H_FEATS + co) : zz;
        uint4 h2 = (i + 2 < end) ? *(const uint4*)(Src + (size_t)s2 * H_FEATS + co) : zz;
        uint4 h3 = (i + 3 < end) ? *(const uint4*)(Src + (size_t)s3 * H_FEATS + co) : zz;
        for (; i + 4 < end; i += 4) {
            int t0 = (int)idx[i + 4];
            int t1 = (i + 5 < end) ? (int)idx[i + 5] : 0;
            int t2 = (i + 6 < end) ? (int)idx[i + 6] : 0;
            int t3 = (i + 7 < end) ? (int)idx[i + 7] : 0;
            uint4 n0 = *(const uint4*)(Src + (size_t)t0 * H_FEATS + co);
            uint4 n1 = (i + 5 < end) ? *(const uint4*)(Src + (size_t)t1 * H_FEATS + co) : zz;
            uint4 n2 = (i + 6 < end) ? *(const uint4*)(Src + (size_t)t2 * H_FEATS + co) : zz;
            uint4 n3 = (i + 7 < end) ? *(const uint4*)(Src + (size_t)t3 * H_FEATS + co) : zz;
            add8(acc, h0); add8(acc, h1); add8(acc, h2); add8(acc, h3);
            h0 = n0; h1 = n1; h2 = n2; h3 = n3;
        }
        add8(acc, h0); add8(acc, h1); add8(acc, h2); add8(acc, h3);

        if (MODE == 0) {
            float dd = dinv[gr];
#pragma unroll
            for (int j = 0; j < 8; j++)
                acc[j] = fmaxf(fmaf(dd, acc[j], dload(bv, co + j, isbf)), 0.0f);
        } else {
            int cnt = end - beg;
            if (cnt > 0) {
                float inv = 1.0f / (float)cnt;
#pragma unroll
                for (int j = 0; j < 8; j++) acc[j] *= inv;
            } else {
                uint4 u = *(const uint4*)(Src + (size_t)gr * H_FEATS + co);
                set8(acc, u);
            }
        }
        uint4 pk = pack8(acc);
        *ldst = pk;
        if (WRITEG) *(uint4*)(Hg + (size_t)gr * H_FEATS + co) = pk;
    }
}

// ---------------- MFMA GEMM phase, A from 32-row LDS tile (K=128) ----------------
__device__ __forceinline__ void gemm_lds_body32(int bid, const u16* __restrict__ tile,
                                                const u16* __restrict__ Wp,
                                                u16* __restrict__ Cb,
                                                const float* __restrict__ dinv, int M) {
    const int tid = threadIdx.x;
    const int wave = tid >> 6, lane = tid & 63;
    const int m16 = lane & 15, quad = lane >> 4;
    const int rg = wave & 1, cg = wave >> 1;
    const int lrow = rg * 16 + m16;

    float4v acc[4];
#pragma unroll
    for (int t = 0; t < 4; t++) acc[t] = (float4v){0.f, 0.f, 0.f, 0.f};

#pragma unroll
    for (int s = 0; s < 4; s++) {
        int k0 = s * 32 + quad * 8;
        short8 a = *(const short8*)(tile + (size_t)lrow * TPAD + k0);
#pragma unroll
        for (int t = 0; t < 4; t++) {
            int tg = cg * 4 + t;
            short8 b = *(const short8*)(Wp + ((size_t)(s * 8 + tg) * 64 + lane) * 8);
            acc[t] = __builtin_amdgcn_mfma_f32_16x16x32_bf16(a, b, acc[t], 0, 0, 0);
        }
    }
#pragma unroll
    for (int r = 0; r < 4; r++) {
        int gr = bid * 32 + rg * 16 + quad * 4 + r;
        if (gr < M) {
            float sc = dinv[gr];
#pragma unroll
            for (int t = 0; t < 4; t++) {
                size_t o = (size_t)gr * H_FEATS + (cg * 4 + t) * 16 + m16;
                Cb[o] = f2bf(sc * acc[t][r]);
            }
        }
    }
}

// ---------------- fused gather + gemm (tier 0, layers 1/2), 32-row tile ----------------
template <int MODE>
__global__ __launch_bounds__(256) void agg_gemm(const int* __restrict__ off,
                                                const u16* __restrict__ idx,
                                                const float* __restrict__ dinv,
                                                const u16* __restrict__ Src,
                                                const void* __restrict__ bv,
                                                const u16* __restrict__ Wp,
                                                u16* __restrict__ Hg,
                                                u16* __restrict__ Pnext,
                                                const int* __restrict__ flagp, int N) {
    __shared__ u16 tile[32 * TPAD];
    gather_tile<MODE, true>(blockIdx.x, off, idx, dinv, Src, bv, *flagp, Hg, tile, N);
    __syncthreads();
    gemm_lds_body32(blockIdx.x, tile, Wp, Pnext, dinv, N);
}

// ---------------- fused gather + jk + MFMA fc (tier 0, last layer), 32-row tile ----------------
__global__ __launch_bounds__(256) void agg_fc3(const int* __restrict__ off,
                                               const u16* __restrict__ idx,
                                               const float* __restrict__ dinv,
                                               const u16* __restrict__ Src,
                                               const void* __restrict__ bv3,
                                               const u16* __restrict__ H0,
                                               const u16* __restrict__ H1,
                                               const u16* __restrict__ Wfp,
                                               const void* __restrict__ bv,
                                               void* __restrict__ Outv,
                                               const float* __restrict__ meta, int N) {
    __shared__ u16 tile[32 * TPAD];
    const int isbf = ((const int*)meta)[0];
    gather_tile<0, false>(blockIdx.x, off, idx, dinv, Src, bv3, isbf, (u16*)0, tile, N);
    __syncthreads();

    const float w0 = meta[8], w1 = meta[9], w2 = meta[10];
    const int tid = threadIdx.x;
    const int wave = tid >> 6, lane = tid & 63;
    const int m16 = lane & 15, quad = lane >> 4;
    const int rg = wave & 1, cg = wave >> 1;
    const int lrow = rg * 16 + m16;
    const int gr0 = blockIdx.x * 32 + lrow;

    float4v acc[2];
#pragma unroll
    for (int t = 0; t < 2; t++) acc[t] = (float4v){0.f, 0.f, 0.f, 0.f};

#pragma unroll
    for (int s = 0; s < 4; s++) {
        int k0 = s * 32 + quad * 8;
        short8 a = (short8)(short)0;
        if (gr0 < N) {
            float f0[8], f1[8], f2[8];
            uint4 u0 = *(const uint4*)(H0 + (size_t)gr0 * H_FEATS + k0);
            uint4 u1 = *(const uint4*)(H1 + (size_t)gr0 * H_FEATS + k0);
            uint4 tv = *(const uint4*)(tile + (size_t)lrow * TPAD + k0);
            set8(f0, u0); set8(f1, u1); set8(f2, tv);
#pragma unroll
            for (int j = 0; j < 8; j++)
                a[j] = (short)f2bf(w0 * f0[j] + w1 * f1[j] + w2 * f2[j]);
        }
#pragma unroll
        for (int t = 0; t < 2; t++) {
            int tg = cg * 2 + t;
            short8 b = *(const short8*)(Wfp + ((size_t)(s * 4 + tg) * 64 + lane) * 8);
            acc[t] = __builtin_amdgcn_mfma_f32_16x16x32_bf16(a, b, acc[t], 0, 0, 0);
        }
    }

    __hip_bfloat16* ob = (__hip_bfloat16*)Outv;
    float* of = (float*)Outv;
#pragma unroll
    for (int r = 0; r < 4; r++) {
        int gr = blockIdx.x * 32 + rg * 16 + quad * 4 + r;
        if (gr < N) {
#pragma unroll
            for (int t = 0; t < 2; t++) {
                int c = (cg * 2 + t) * 16 + m16;
                size_t o = (size_t)gr * 64 + c;
                float v = acc[t][r] + dload(bv, c, isbf);
                if (isbf) ob[o] = __float2bfloat16(v); else of[o] = v;
            }
        }
    }
}

// ---------------- weighted gather (tier B only) ----------------
template <bool BF16OUT>
__global__ __launch_bounds__(256) void agg_gather3b(const int* __restrict__ off,
                                                    const u16* __restrict__ idx,
                                                    const float* __restrict__ dinv,
                                                    const u16* __restrict__ Hb,
                                                    const void* __restrict__ bv,
                                                    void* __restrict__ houtv,
                                                    const int* __restrict__ flagp, int N) {
    int node = blockIdx.x * 8 + (threadIdx.x >> 5);
    if (node >= N) return;
    int l = threadIdx.x & 31;
    int isbf = *flagp;
    int beg = off[node], end = off[node + 1];
    float dd = dinv[node];
    size_t ro = (size_t)l * 4;

    float4 self = load4bf(&Hb[(size_t)node * H_FEATS + ro]);
    float w0s = dd * dd;
    float4 acc = {w0s * self.x, w0s * self.y, w0s * self.z, w0s * self.w};

    int i = beg;
    int s0 = (i < end) ? (int)idx[i] : 0;
    float4 h0 = (i < end) ? load4bf(&Hb[(size_t)s0 * H_FEATS + ro])
                          : (float4){0.f, 0.f, 0.f, 0.f};
    for (; i < end; i++) {
        int s1 = (i + 1 < end) ? (int)idx[i + 1] : 0;
        float4 h1 = (i + 1 < end) ? load4bf(&Hb[(size_t)s1 * H_FEATS + ro]) : h0;
        float w = dinv[s0] * dd;
        acc.x = fmaf(w, h0.x, acc.x);
        acc.y = fmaf(w, h0.y, acc.y);
        acc.z = fmaf(w, h0.z, acc.z);
        acc.w = fmaf(w, h0.w, acc.w);
        s0 = s1; h0 = h1;
    }
    acc.x = fmaxf(acc.x + dload(bv, l * 4 + 0, isbf), 0.0f);
    acc.y = fmaxf(acc.y + dload(bv, l * 4 + 1, isbf), 0.0f);
    acc.z = fmaxf(acc.z + dload(bv, l * 4 + 2, isbf), 0.0f);
    acc.w = fmaxf(acc.w + dload(bv, l * 4 + 3, isbf), 0.0f);
    if (BF16OUT) {
        u16* hb = (u16*)houtv;
        uint2 pk;
        pk.x = (unsigned)f2bf(acc.x) | ((unsigned)f2bf(acc.y) << 16);
        pk.y = (unsigned)f2bf(acc.z) | ((unsigned)f2bf(acc.w) << 16);
        *(uint2*)&hb[(size_t)node * H_FEATS + ro] = pk;
    } else {
        *(float4*)&((float*)houtv)[(size_t)node * H_FEATS + ro] = acc;
    }
}

// ---------------- fp32 GEMM (tier C) ----------------
template <int K, bool XIN, bool GATEBF, bool BF16OUT>
__global__ __launch_bounds__(256) void gemm128(const void* __restrict__ Xv,
                                               const void* __restrict__ Wv,
                                               void* __restrict__ Cv,
                                               const int* __restrict__ flagp, int N) {
    constexpr int BM = 64, BK = 16, BN = 128, TN = 8, TX = BN / TN;
    __shared__ float Xs[BK][BM + 4];
    __shared__ float Ws[BK][BN];
    const int isbf = *flagp;
    if (GATEBF && isbf != 1) return;
    const float* Xf = (const float*)Xv;

    const int tid = threadIdx.x;
    const int tx = tid % TX;
    const int ty = tid / TX;
    const int rowBase = blockIdx.x * BM;

    float acc[4][TN] = {};
    const int lk = tid % BK;
    const int lr0 = tid / BK;

    for (int kb = 0; kb < K; kb += BK) {
#pragma unroll
        for (int i = 0; i < 4; i++) {
            int r = lr0 + i * 16;
            int gr = rowBase + r;
            float v = 0.0f;
            if (gr < N) {
                size_t idx = (size_t)gr * K + kb + lk;
                v = XIN ? dload(Xv, idx, isbf) : Xf[idx];
            }
            Xs[lk][r] = v;
        }
#pragma unroll
        for (int i = 0; i < 8; i++) {
            int idx = i * 256 + tid;
            int k = idx >> 7, c = idx & 127;
            Ws[k][c] = dload(Wv, (size_t)(kb + k) * BN + c, isbf);
        }
        __syncthreads();
#pragma unroll
        for (int k = 0; k < BK; k++) {
            float4 a = *(const float4*)&Xs[k][ty * 4];
            float av[4] = {a.x, a.y, a.z, a.w};
            float4 b0 = *(const float4*)&Ws[k][tx * TN];
            float4 b1 = *(const float4*)&Ws[k][tx * TN + 4];
            float bv[8] = {b0.x, b0.y, b0.z, b0.w, b1.x, b1.y, b1.z, b1.w};
#pragma unroll
            for (int i = 0; i < 4; i++)
#pragma unroll
                for (int j = 0; j < TN; j++) acc[i][j] = fmaf(av[i], bv[j], acc[i][j]);
        }
        __syncthreads();
    }
#pragma unroll
    for (int i = 0; i < 4; i++) {
        int gr = rowBase + ty * 4 + i;
        if (gr < N) {
#pragma unroll
            for (int j = 0; j < TN; j++) {
                size_t o = (size_t)gr * BN + tx * TN + j;
                if (BF16OUT) ((u16*)Cv)[o] = f2bf(acc[i][j]);
                else         ((float*)Cv)[o] = acc[i][j];
            }
        }
    }
}

template <bool FIRST, bool LAST, bool BFIN>
__global__ __launch_bounds__(256) void fc_accum(const void* __restrict__ Hmv,
                                                const void* __restrict__ Wv,
                                                const void* __restrict__ bv,
                                                void* __restrict__ Outv,
                                                const float* __restrict__ meta,
                                                int widx, int N) {
    constexpr int BM = 64, BK = 16, BN = 64, TN = 4, TX = BN / TN, K = 128;
    __shared__ float Xs[BK][BM + 4];
    __shared__ float Ws[BK][BN];
    const int isbf = ((const int*)meta)[0];
    const float scale = meta[8 + widx];

    const int tid = threadIdx.x;
    const int tx = tid % TX;
    const int ty = tid / TX;
    const int rowBase = blockIdx.x * BM;

    float acc[4][TN] = {};
    const int lk = tid % BK;
    const int lr0 = tid / BK;

    for (int kb = 0; kb < K; kb += BK) {
#pragma unroll
        for (int i = 0; i < 4; i++) {
            int r = lr0 + i * 16;
            int gr = rowBase + r;
            float v = 0.0f;
            if (gr < N) {
                size_t idx = (size_t)gr * K + kb + lk;
                if (BFIN) v = bf2f(((const u16*)Hmv)[idx]);
                else      v = ((const float*)Hmv)[idx];
            }
            Xs[lk][r] = v;
        }
#pragma unroll
        for (int i = 0; i < 4; i++) {
            int idx = i * 256 + tid;
            int k = idx >> 6, c = idx & 63;
            Ws[k][c] = dload(Wv, (size_t)(kb + k) * BN + c, isbf);
        }
        __syncthreads();
#pragma unroll
        for (int k = 0; k < BK; k++) {
            float4 a = *(const float4*)&Xs[k][ty * 4];
            float av[4] = {a.x, a.y, a.z, a.w};
            float4 bb = *(const float4*)&Ws[k][tx * TN];
            float bvv[4] = {bb.x, bb.y, bb.z, bb.w};
#pragma unroll
            for (int i = 0; i < 4; i++)
#pragma unroll
                for (int j = 0; j < TN; j++) acc[i][j] = fmaf(av[i], bvv[j], acc[i][j]);
        }
        __syncthreads();
    }
    __hip_bfloat16* ob = (__hip_bfloat16*)Outv;
    float* of = (float*)Outv;
#pragma unroll
    for (int i = 0; i < 4; i++) {
        int gr = rowBase + ty * 4 + i;
        if (gr < N) {
#pragma unroll
            for (int j = 0; j < TN; j++) {
                int c = tx * TN + j;
                size_t o = (size_t)gr * BN + c;
                float v = scale * acc[i][j];
                if (!FIRST) v += isbf ? __bfloat162float(ob[o]) : of[o];
                if (LAST) v += dload(bv, c, isbf);
                if (isbf) ob[o] = __float2bfloat16(v); else of[o] = v;
            }
        }
    }
}

// ---------------- atomic fallbacks (tier B / C) ----------------
__global__ __launch_bounds__(256) void init_deg(float* deg, float* odeg, int N) {
    int i = blockIdx.x * 256 + threadIdx.x;
    if (i < N) { deg[i] = 1.0f; odeg[i] = 0.0f; }
}
__global__ __launch_bounds__(256) void count_deg(const int* __restrict__ row, const int* __restrict__ col,
                                                 float* deg, float* odeg, int E) {
    int e = blockIdx.x * 256 + threadIdx.x;
    if (e < E) {
        atomicAdd(&deg[col[e]], 1.0f);
        atomicAdd(&odeg[row[e]], 1.0f);
    }
}
__global__ __launch_bounds__(256) void deg_to_dinv(float* deg, int N) {
    int i = blockIdx.x * 256 + threadIdx.x;
    if (i < N) deg[i] = rsqrtf(deg[i]);
}
__global__ __launch_bounds__(256) void agg_edges(const int* __restrict__ row, const int* __restrict__ col,
                                                 const float* __restrict__ dinv,
                                                 const float* __restrict__ H,
                                                 float* __restrict__ agg, int E) {
    int e = blockIdx.x * 2 + (threadIdx.x >> 7);
    if (e >= E) return;
    int j = threadIdx.x & 127;
    int s = row[e], d = col[e];
    float w = dinv[s] * dinv[d];
    atomicAdd(&agg[(size_t)d * H_FEATS + j], w * H[(size_t)s * H_FEATS + j]);
}
__global__ __launch_bounds__(256) void mean_edges(const int* __restrict__ row, const int* __restrict__ col,
                                                  const float* __restrict__ h0pre,
                                                  float* __restrict__ nsum, int E) {
    int e = blockIdx.x * 2 + (threadIdx.x >> 7);
    if (e >= E) return;
    int j = threadIdx.x & 127;
    int r = row[e], c = col[e];
    atomicAdd(&nsum[(size_t)r * H_FEATS + j], h0pre[(size_t)c * H_FEATS + j]);
}
__global__ __launch_bounds__(256) void finalize_layer(const float* __restrict__ agg,
                                                      const float* __restrict__ H,
                                                      const float* __restrict__ dinv,
                                                      const void* __restrict__ bv,
                                                      float* __restrict__ hout,
                                                      const int* __restrict__ flagp, int NH) {
    int idx = blockIdx.x * 256 + threadIdx.x;
    if (idx >= NH) return;
    int isbf = *flagp;
    int v = idx >> 7, j = idx & 127;
    float di = dinv[v];
    float h = fmaf(di * di, H[idx], agg[idx]) + dload(bv, j, isbf);
    hout[idx] = fmaxf(h, 0.0f);
}
__global__ __launch_bounds__(256) void finalize_mean(const float* __restrict__ nsum,
                                                     const float* __restrict__ h0pre,
                                                     const float* __restrict__ odeg,
                                                     float* __restrict__ h0, int NH) {
    int idx = blockIdx.x * 256 + threadIdx.x;
    if (idx >= NH) return;
    int v = idx >> 7;
    float od = odeg[v];
    h0[idx] = (od > 0.0f) ? (nsum[idx] / od) : h0pre[idx];
}
__global__ __launch_bounds__(256) void finalize_mean_cnt(const float* __restrict__ nsum,
                                                         const float* __restrict__ h0pre,
                                                         const int* __restrict__ cntr,
                                                         float* __restrict__ h0, int NH) {
    int idx = blockIdx.x * 256 + threadIdx.x;
    if (idx >= NH) return;
    int v = idx >> 7;
    int od = cntr[v];
    h0[idx] = (od > 0) ? (nsum[idx] / (float)od) : h0pre[idx];
}

extern "C" void kernel_launch(void* const* d_in, const int* in_sizes, int n_in,
                              void* d_out, int out_size, void* d_ws, size_t ws_size,
                              hipStream_t stream) {
    const void* x   = d_in[0];
    const int*  ei  = (const int*)d_in[1];
    const void* W1  = d_in[2];
    const void* b1  = d_in[3];
    const void* W2  = d_in[4];
    const void* b2  = d_in[5];
    const void* W3  = d_in[6];
    const void* b3  = d_in[7];
    const void* jkb = d_in[8];
    const void* Wfc = d_in[9];
    const void* bfc = d_in[10];

    const int IN = 256;
    const int N = in_sizes[0] / IN;          // 50000
    const int E = in_sizes[1] / 2;           // 800000
    const int NH = N * H_FEATS;

    const int* row = ei;
    const int* col = ei + E;

    // ---- workspace layout (fp32 words); arrays 16B-aligned ----
    auto a4 = [](size_t v) { return (v + 3) & ~(size_t)3; };
    float* ws = (float*)d_ws;
    size_t o = 0;
    float* meta  = ws + o;           o += 256;
    float* dinv  = ws + o;           o += N;          o = a4(o);
    int*   cntc  = (int*)(ws + o);   o += N;          o = a4(o);
    int*   cntr  = (int*)(ws + o);   o += N;          o = a4(o);
    int*   bsumc = (int*)(ws + o);   o += 256;
    int*   bsumr = (int*)(ws + o);   o += 256;
    int*   coff  = (int*)(ws + o);   o += N + 1;      o = a4(o);
    int*   curc  = (int*)(ws + o);   o += N;          o = a4(o);
    u16*   ecol  = (u16*)(ws + o);   o += E;          o = a4(o);
    size_t oB_small = o;
    int*   roff  = (int*)(ws + o);   o += N + 1;      o = a4(o);
    int*   curr  = (int*)(ws + o);   o += N;          o = a4(o);
    u16*   erow  = (u16*)(ws + o);   o += E;          o = a4(o);
    size_t oA_full = o;

    auto alignup = [](size_t v) { return (v + 63) & ~(size_t)63; };
    const size_t WPW = 16384 + 8192 + 8192 + 4096;   // Wp1 + Wp2 + Wp3 + Wfcp (fp32 words)
    size_t needA = alignup(oA_full) + 2 * (size_t)NH + 64 + WPW;
    size_t needB = alignup(oB_small) + 2 * (size_t)NH + 64 + WPW;

    int tier;
    size_t hoff;
    if (N >= 65536)                { tier = 2; hoff = alignup(256 + 2 * (size_t)N); }
    else if (ws_size >= needA * 4) { tier = 0; hoff = alignup(oA_full); }
    else if (ws_size >= needB * 4) { tier = 1; hoff = alignup(oB_small); }
    else                           { tier = 2; hoff = alignup(256 + 2 * (size_t)N); }
    float* A = ws + hoff;
    float* B = A + NH;
    u16* HbA = (u16*)A;
    u16* HbB = (u16*)B;
    // tier-0 carves four bf16 NH buffers out of the same 2*NH-float region:
    u16* Pb  = (u16*)A;              // P rows (rotating)
    u16* Qb  = Pb + (size_t)NH;      // h0pre, later P2
    u16* H0b = Pb + 2 * (size_t)NH;
    u16* H1b = Pb + 3 * (size_t)NH;
    // CSR-build partials overlay the H0/H1 half (dead until meangemm1):
    unsigned* partC = (unsigned*)H0b;
    unsigned* partR = partC + (size_t)CSR_CH * N;
    size_t wpoff = alignup(hoff + 2 * (size_t)NH);
    u16* Wp1 = (u16*)(ws + wpoff);
    u16* Wp2 = Wp1 + 32768;
    u16* Wp3 = Wp2 + 16384;
    u16* Wfcp = Wp3 + 16384;
    float* odegf = ws + 256 + N;
    const int* flag = (const int*)meta;

    dim3 blk(256);
    int gN = (N + 255) / 256;
    int gE = (E + 255) / 256;
    int gE2 = (E + 1) / 2;
    int gNH = (NH + 255) / 256;
    int gGemm = (N + 63) / 64;
    int gG32 = (N + 31) / 32;
    int gNode8 = (N + 7) / 8;
    int nb = (N + 1023) / 1024;
    size_t shb = (size_t)((N + CSR_SL - 1) / CSR_SL) * 4;

    if (tier == 0) {
        // ---- atomic-free CSR build; count + sniff + pack in one launch ----
        count_partial<<<CSR_NSC + 1 + 36, blk, shb, stream>>>(row, col, partC, partR, E, N,
                                                              (const unsigned int*)x, jkb, meta,
                                                              W1, W2, W3, Wfc,
                                                              Wp1, Wp2, Wp3, Wfcp);
        reduce_bsum<<<dim3(nb, 2), blk, 0, stream>>>(partC, partR, cntc, cntr, bsumc, bsumr, N);
        scan_final<<<dim3(nb, 2), blk, 0, stream>>>(cntc, cntr, bsumc, bsumr,
                                                    coff, curc, roff, curr,
                                                    partC, partR, dinv, N);

        // ---- fused: scatter + layer-0 GEMM (P0 = dinv .* (x@W1)) ----
        scatter_gemm0<<<CSR_NSC + gGemm, blk, shb, stream>>>(row, col, partC, partR, ecol, erow,
                                                             E, N, x, Wp1, Pb, dinv, flag);

        // ---- h0pre = relu(dd*(P0[d]+sum P0[s]) + b1) ----
        agg_sum<<<gNode8, blk, 0, stream>>>(coff, ecol, dinv, Pb, b1, Qb, flag, N);

        // ---- fused mean + gemm1: h0 -> H0b, P1 = dinv.(h0@W2) -> Pb ----
        agg_gemm<1><<<gG32, blk, 0, stream>>>(roff, erow, dinv, Qb, b1, Wp2, H0b, Pb, flag, N);

        // ---- fused agg + gemm2: h1 -> H1b, P2 = dinv.(h1@W3) -> Qb ----
        agg_gemm<0><<<gG32, blk, 0, stream>>>(coff, ecol, dinv, Pb, b2, Wp3, H1b, Qb, flag, N);

        // ---- fused agg + jk + MFMA fc: h2 (LDS only) + out ----
        agg_fc3<<<gG32, blk, 0, stream>>>(coff, ecol, dinv, Qb, b3, H0b, H1b,
                                          Wfcp, bfc, d_out, meta, N);
    } else if (tier == 1) {
        // ---- tier B: legacy atomic CSR build (col only) + fp32 mean path ----
        hipMemsetAsync(cntc, 0, 2 * (size_t)N * 4, stream);
        histo_sniff<<<gE + 1, blk, 0, stream>>>(row, col, cntc, cntr, E,
                                                (const unsigned int*)x, jkb, meta);
        const int T = 4;
        int step = (N + T - 1) / T;
        scan_bsum<<<dim3(nb, 1), blk, 0, stream>>>(cntc, cntc, bsumc, bsumc, N);
        scan_final<<<dim3(nb, 1), blk, 0, stream>>>(cntc, cntc, bsumc, bsumc,
                                                    coff, curc, coff, curc,
                                                    (unsigned*)0, (unsigned*)0, dinv, N);
        for (int t = 0; t < T; t++) {
            int lo = t * step, hi = lo + step; if (hi > N) hi = N;
            scatter_tile<<<gE, blk, 0, stream>>>(row, col, curc, curc, ecol, ecol, E, lo, hi, 0);
        }

        pack_all<<<36, blk, 0, stream>>>(W1, W2, W3, Wfc, Wp1, Wp2, Wp3, Wfcp, flag);

        gemm_mfma<256, true, false, false><<<gGemm, blk, 0, stream>>>(x, Wp1, HbA, dinv, flag, N);
        agg_gather3b<false><<<gNode8, blk, 0, stream>>>(coff, ecol, dinv, HbA, b1, B, flag, N);
        hipMemsetAsync(A, 0, (size_t)NH * 4, stream);
        mean_edges<<<gE2, blk, 0, stream>>>(row, col, B, A, E);
        finalize_mean_cnt<<<gNH, blk, 0, stream>>>(A, B, cntr, A, NH);
        fc_accum<true, false, false><<<gGemm, blk, 0, stream>>>(A, Wfc, bfc, d_out, meta, 0, N);

        gemm_mfma<128, false, false, false><<<gGemm, blk, 0, stream>>>(A, Wp2, HbB, dinv, flag, N);
        agg_gather3b<true><<<gNode8, blk, 0, stream>>>(coff, ecol, dinv, HbB, b2, HbA, flag, N);
        fc_accum<false, false, true><<<gGemm, blk, 0, stream>>>(HbA, Wfc, bfc, d_out, meta, 1, N);

        gemm_mfma<128, false, true, false><<<gGemm, blk, 0, stream>>>(HbA, Wp3, HbB, dinv, flag, N);
        agg_gather3b<true><<<gNode8, blk, 0, stream>>>(coff, ecol, dinv, HbB, b3, HbA, flag, N);
        fc_accum<false, true, true><<<gGemm, blk, 0, stream>>>(HbA, Wfc, bfc, d_out, meta, 2, N);
    } else {
        // ---- tier C: fp32 atomic path ----
        sniff_jkw<<<1, blk, 0, stream>>>((const unsigned int*)x, jkb, meta);
        init_deg<<<gN, blk, 0, stream>>>(dinv, odegf, N);
        count_deg<<<gE, blk, 0, stream>>>(row, col, dinv, odegf, E);
        deg_to_dinv<<<gN, blk, 0, stream>>>(dinv, N);

        gemm128<256, true, false, false><<<gGemm, blk, 0, stream>>>(x, W1, A, flag, N);
        hipMemsetAsync(B, 0, (size_t)NH * 4, stream);
        agg_edges<<<gE2, blk, 0, stream>>>(row, col, dinv, A, B, E);
        finalize_layer<<<gNH, blk, 0, stream>>>(B, A, dinv, b1, B, flag, NH);
        hipMemsetAsync(A, 0, (size_t)NH * 4, stream);
        mean_edges<<<gE2, blk, 0, stream>>>(row, col, B, A, E);
        finalize_mean<<<gNH, blk, 0, stream>>>(A, B, odegf, A, NH);
        fc_accum<true, false, false><<<gGemm, blk, 0, stream>>>(A, Wfc, bfc, d_out, meta, 0, N);

        gemm128<128, false, false, false><<<gGemm, blk, 0, stream>>>(A, W2, B, flag, N);
        hipMemsetAsync(A, 0, (size_t)NH * 4, stream);
        agg_edges<<<gE2, blk, 0, stream>>>(row, col, dinv, B, A, E);
        finalize_layer<<<gNH, blk, 0, stream>>>(A, B, dinv, b2, A, flag, NH);
        fc_accum<false, false, false><<<gGemm, blk, 0, stream>>>(A, Wfc, bfc, d_out, meta, 1, N);

        gemm128<128, false, false, false><<<gGemm, blk, 0, stream>>>(A, W3, B, flag, N);
        hipMemsetAsync(A, 0, (size_t)NH * 4, stream);
        agg_edges<<<gE2, blk, 0, stream>>>(row, col, dinv, B, A, E);
        finalize_layer<<<gNH, blk, 0, stream>>>(A, B, dinv, b3, A, flag, NH);
        fc_accum<false, true, false><<<gGemm, blk, 0, stream>>>(A, Wfc, bfc, d_out, meta, 2, N);
    }
}

// Round 13
// 380.363 us; speedup vs baseline: 1.1106x; 1.0256x over previous
//
#include <hip/hip_runtime.h>
#include <hip/hip_bf16.h>

// DynamicJKGCN on MI355X — round 25: agg_sum -> 16-lane uint4 gather format.
// Round-24 (390.1us = best): launch diet paid ~7us. agg_sum is the last kernel
// on the old gather format (32 lanes/row x 8B); the fused gather_tile kernels
// use 16 lanes/row x uint4: half the load instructions/edge, 4 row-streams per
// wave x depth-4 = 16 outstanding loads (vs 8). This round converts agg_sum to
// that format (16 nodes/block, grid N/16). Single knob; all else = round 24.

#define H_FEATS 128
#define TPAD 136

typedef __attribute__((ext_vector_type(8))) short short8;
typedef __attribute__((ext_vector_type(4))) float float4v;
typedef unsigned short u16;

__device__ __forceinline__ float dload(const void* p, size_t i, int isbf) {
    return isbf ? __bfloat162float(((const __hip_bfloat16*)p)[i])
                : ((const float*)p)[i];
}

__device__ __forceinline__ float4 load4bf(const u16* p) {
    uint2 u = *(const uint2*)p;
    float4 f;
    f.x = __uint_as_float((u.x & 0xFFFFu) << 16);
    f.y = __uint_as_float(u.x & 0xFFFF0000u);
    f.z = __uint_as_float((u.y & 0xFFFFu) << 16);
    f.w = __uint_as_float(u.y & 0xFFFF0000u);
    return f;
}

__device__ __forceinline__ float bf2f(u16 h) {
    return __uint_as_float((unsigned)h << 16);
}

__device__ __forceinline__ u16 f2bf(float v) {
    return __bfloat16_as_ushort(__float2bfloat16(v));
}

__device__ __forceinline__ void add8(float* a, uint4 u) {
    a[0] += __uint_as_float((u.x & 0xFFFFu) << 16);
    a[1] += __uint_as_float(u.x & 0xFFFF0000u);
    a[2] += __uint_as_float((u.y & 0xFFFFu) << 16);
    a[3] += __uint_as_float(u.y & 0xFFFF0000u);
    a[4] += __uint_as_float((u.z & 0xFFFFu) << 16);
    a[5] += __uint_as_float(u.z & 0xFFFF0000u);
    a[6] += __uint_as_float((u.w & 0xFFFFu) << 16);
    a[7] += __uint_as_float(u.w & 0xFFFF0000u);
}

__device__ __forceinline__ void set8(float* a, uint4 u) {
    a[0] = __uint_as_float((u.x & 0xFFFFu) << 16);
    a[1] = __uint_as_float(u.x & 0xFFFF0000u);
    a[2] = __uint_as_float((u.y & 0xFFFFu) << 16);
    a[3] = __uint_as_float(u.y & 0xFFFF0000u);
    a[4] = __uint_as_float((u.z & 0xFFFFu) << 16);
    a[5] = __uint_as_float(u.z & 0xFFFF0000u);
    a[6] = __uint_as_float((u.w & 0xFFFFu) << 16);
    a[7] = __uint_as_float(u.w & 0xFFFF0000u);
}

__device__ __forceinline__ uint4 pack8(const float* f) {
    uint4 r;
    r.x = (unsigned)f2bf(f[0]) | ((unsigned)f2bf(f[1]) << 16);
    r.y = (unsigned)f2bf(f[2]) | ((unsigned)f2bf(f[3]) << 16);
    r.z = (unsigned)f2bf(f[4]) | ((unsigned)f2bf(f[5]) << 16);
    r.w = (unsigned)f2bf(f[6]) | ((unsigned)f2bf(f[7]) << 16);
    return r;
}

// ---------------- dtype sniff + jk softmax ----------------
__device__ __forceinline__ void sniff_body(const unsigned int* __restrict__ x,
                                           const void* __restrict__ jkwb,
                                           float* __restrict__ meta) {
    __shared__ int cnt[256];
    int t = threadIdx.x;
    int c = 0;
    for (int i = 0; i < 16; i++) {
        unsigned int w = x[t * 16 + i];
        unsigned int e = (w >> 7) & 0xFFu;
        c += (e >= 0x60u && e <= 0x8Fu) ? 1 : 0;
    }
    cnt[t] = c;
    __syncthreads();
    for (int s = 128; s > 0; s >>= 1) {
        if (t < s) cnt[t] += cnt[t + s];
        __syncthreads();
    }
    if (t == 0) {
        int isbf = (cnt[0] > 3000) ? 1 : 0;
        ((int*)meta)[0] = isbf;
        float w0 = dload(jkwb, 0, isbf);
        float w1 = dload(jkwb, 1, isbf);
        float w2 = dload(jkwb, 2, isbf);
        float m = fmaxf(w0, fmaxf(w1, w2));
        float e0 = expf(w0 - m), e1 = expf(w1 - m), e2 = expf(w2 - m);
        float s = e0 + e1 + e2;
        meta[8] = e0 / s; meta[9] = e1 / s; meta[10] = e2 / s;
    }
}

// per-block local sniff (no meta write; all threads get isbf)
__device__ __forceinline__ int sniff_local(const unsigned int* __restrict__ x) {
    __shared__ int cnt2[256];
    int t = threadIdx.x;
    int c = 0;
    for (int i = 0; i < 16; i++) {
        unsigned int w = x[t * 16 + i];
        unsigned int e = (w >> 7) & 0xFFu;
        c += (e >= 0x60u && e <= 0x8Fu) ? 1 : 0;
    }
    cnt2[t] = c;
    __syncthreads();
    for (int s = 128; s > 0; s >>= 1) {
        if (t < s) cnt2[t] += cnt2[t + s];
        __syncthreads();
    }
    int isbf = (cnt2[0] > 3000) ? 1 : 0;
    __syncthreads();
    return isbf;
}

__global__ __launch_bounds__(256) void sniff_jkw(const unsigned int* __restrict__ x,
                                                 const void* __restrict__ jkwb,
                                                 float* __restrict__ meta) {
    sniff_body(x, jkwb, meta);
}

// ---------------- W prepack body (shared by fused + standalone) ----------------
__device__ __forceinline__ void pack_body(int bid,
                                          const void* __restrict__ W1,
                                          const void* __restrict__ W2,
                                          const void* __restrict__ W3,
                                          const void* __restrict__ Wf,
                                          u16* __restrict__ Wp1,
                                          u16* __restrict__ Wp2,
                                          u16* __restrict__ Wp3,
                                          u16* __restrict__ Wfp,
                                          int isbf) {
    const void* W; u16* Wp; int K, C, gid;
    if (bid < 16)      { W = W1; Wp = Wp1; K = 256; C = 128; gid = bid * 256 + threadIdx.x; }
    else if (bid < 24) { W = W2; Wp = Wp2; K = 128; C = 128; gid = (bid - 16) * 256 + threadIdx.x; }
    else if (bid < 32) { W = W3; Wp = Wp3; K = 128; C = 128; gid = (bid - 24) * 256 + threadIdx.x; }
    else               { W = Wf; Wp = Wfp; K = 128; C = 64;  gid = (bid - 32) * 256 + threadIdx.x; }
    int tiles = C >> 4;
    int steps = K >> 5;
    if (gid >= steps * tiles * 64) return;
    int lane = gid & 63;
    int tt = (gid >> 6) % tiles;
    int s = (gid >> 6) / tiles;
    int krow = s * 32 + ((lane >> 4) << 3);
    int ncol = tt * 16 + (lane & 15);
#pragma unroll
    for (int j = 0; j < 8; j++) {
        float v = dload(W, (size_t)(krow + j) * C + ncol, isbf);
        Wp[(size_t)gid * 8 + j] = f2bf(v);
    }
}

__global__ __launch_bounds__(256) void pack_all(const void* __restrict__ W1,
                                                const void* __restrict__ W2,
                                                const void* __restrict__ W3,
                                                const void* __restrict__ Wf,
                                                u16* __restrict__ Wp1,
                                                u16* __restrict__ Wp2,
                                                u16* __restrict__ Wp3,
                                                u16* __restrict__ Wfp,
                                                const int* __restrict__ flagp) {
    pack_body(blockIdx.x, W1, W2, W3, Wf, Wp1, Wp2, Wp3, Wfp, *flagp);
}

// ---------------- atomic-free CSR build (tier 0) ----------------
#define CSR_CH 64
#define CSR_SL 8
#define CSR_NSC (CSR_CH * CSR_SL * 2)

// fused: count (blocks [0,NSC)) + sniff (NSC) + pack (NSC+1 .. NSC+36)
__global__ __launch_bounds__(256) void count_partial(const int* __restrict__ row,
                                                     const int* __restrict__ col,
                                                     unsigned* __restrict__ partC,
                                                     unsigned* __restrict__ partR,
                                                     int E, int N,
                                                     const unsigned int* __restrict__ x,
                                                     const void* __restrict__ jkwb,
                                                     float* __restrict__ meta,
                                                     const void* __restrict__ W1,
                                                     const void* __restrict__ W2,
                                                     const void* __restrict__ W3,
                                                     const void* __restrict__ Wf,
                                                     u16* __restrict__ Wp1,
                                                     u16* __restrict__ Wp2,
                                                     u16* __restrict__ Wp3,
                                                     u16* __restrict__ Wfp) {
    int b = blockIdx.x;
    if (b == CSR_NSC) { sniff_body(x, jkwb, meta); return; }
    if (b > CSR_NSC) {
        int isbf = sniff_local(x);
        pack_body(b - CSR_NSC - 1, W1, W2, W3, Wf, Wp1, Wp2, Wp3, Wfp, isbf);
        return;
    }
    extern __shared__ unsigned cnt[];
    int dir = b >> 9;
    int r = b & 511;
    int sl = r >> 6;
    int k  = r & 63;
    const int* arr = dir ? row : col;
    unsigned* part = (dir ? partR : partC) + (size_t)k * N;
    int lo = (int)(((long long)N * sl) >> 3);
    int hi = (int)(((long long)N * (sl + 1)) >> 3);
    int wid = hi - lo;

    for (int i = threadIdx.x; i < wid; i += 256) cnt[i] = 0;
    __syncthreads();

    int e0 = (int)(((long long)E * k) >> 6);
    int e1 = (int)(((long long)E * (k + 1)) >> 6);
    for (int e = e0 + threadIdx.x; e < e1; e += 256) {
        int d = arr[e] - lo;
        if ((unsigned)d < (unsigned)wid) atomicAdd(&cnt[d], 1u);
    }
    __syncthreads();
    for (int i = threadIdx.x; i < wid; i += 256) part[lo + i] = cnt[i];
}

// Fused: cnt[i] = sum_k part[k][i]  AND  RAW per-1024-block sums.
__global__ __launch_bounds__(256) void reduce_bsum(const unsigned* __restrict__ partC,
                                                   const unsigned* __restrict__ partR,
                                                   int* __restrict__ cntc,
                                                   int* __restrict__ cntr,
                                                   int* __restrict__ b0,
                                                   int* __restrict__ b1, int N) {
    const unsigned* p = blockIdx.y ? partR : partC;
    int* cnt = blockIdx.y ? cntr : cntc;
    int* bs = blockIdx.y ? b1 : b0;
    int base = blockIdx.x * 1024 + threadIdx.x * 4;
    unsigned v0 = 0, v1 = 0, v2 = 0, v3 = 0;
    if (base + 3 < N) {
        for (int k = 0; k < CSR_CH; k++) {
            uint4 u = *(const uint4*)(p + (size_t)k * N + base);
            v0 += u.x; v1 += u.y; v2 += u.z; v3 += u.w;
        }
        int4 w = {(int)v0, (int)v1, (int)v2, (int)v3};
        *(int4*)&cnt[base] = w;
    } else {
        unsigned vv[4] = {0, 0, 0, 0};
        for (int k = 0; k < CSR_CH; k++)
            for (int i = 0; i < 4; i++)
                if (base + i < N) vv[i] += p[(size_t)k * N + base + i];
        for (int i = 0; i < 4; i++) if (base + i < N) cnt[base + i] = (int)vv[i];
        v0 = vv[0]; v1 = vv[1]; v2 = vv[2]; v3 = vv[3];
    }
    int s = (int)(v0 + v1 + v2 + v3);
    __shared__ int red[256];
    red[threadIdx.x] = s;
    __syncthreads();
    for (int d = 128; d > 0; d >>= 1) {
        if (threadIdx.x < d) red[threadIdx.x] += red[threadIdx.x + d];
        __syncthreads();
    }
    if (threadIdx.x == 0) bs[blockIdx.x] = red[0];
}

// single-pass scatter body: LDS cursors seeded from bases; 0 global atomics.
__device__ __forceinline__ void scatter_body(int b,
                                             const int* __restrict__ row,
                                             const int* __restrict__ col,
                                             const unsigned* __restrict__ partC,
                                             const unsigned* __restrict__ partR,
                                             u16* __restrict__ ecol,
                                             u16* __restrict__ erow,
                                             int E, int N,
                                             unsigned* __restrict__ cur) {
    int dir = b >> 9;
    int r = b & 511;
    int sl = r >> 6;
    int k  = r & 63;
    const int* darr = dir ? row : col;
    const int* sarr = dir ? col : row;
    u16* out = dir ? erow : ecol;
    const unsigned* base = (dir ? partR : partC) + (size_t)k * N;
    int lo = (int)(((long long)N * sl) >> 3);
    int hi = (int)(((long long)N * (sl + 1)) >> 3);
    int wid = hi - lo;

    for (int i = threadIdx.x; i < wid; i += 256) cur[i] = base[lo + i];
    __syncthreads();

    int e0 = (int)(((long long)E * k) >> 6);
    int e1 = (int)(((long long)E * (k + 1)) >> 6);
    for (int e = e0 + threadIdx.x; e < e1; e += 256) {
        int d = darr[e] - lo;
        if ((unsigned)d < (unsigned)wid) {
            unsigned p = atomicAdd(&cur[d], 1u);
            out[p] = (u16)sarr[e];
        }
    }
}

// ---------------- legacy CSR build (tier B fallback) ----------------
__global__ __launch_bounds__(256) void histo_sniff(const int* __restrict__ row, const int* __restrict__ col,
                                                   int* __restrict__ cntc, int* __restrict__ cntr, int E,
                                                   const unsigned int* __restrict__ x,
                                                   const void* __restrict__ jkwb,
                                                   float* __restrict__ meta) {
    if (blockIdx.x == gridDim.x - 1) {
        sniff_body(x, jkwb, meta);
        return;
    }
    int e = blockIdx.x * 256 + threadIdx.x;
    if (e < E) {
        atomicAdd(&cntc[col[e]], 1);
        atomicAdd(&cntr[row[e]], 1);
    }
}

__global__ __launch_bounds__(256) void scan_bsum(const int* __restrict__ c0, const int* __restrict__ c1,
                                                 int* __restrict__ b0, int* __restrict__ b1, int N) {
    const int* cnt = blockIdx.y ? c1 : c0;
    int* bs = blockIdx.y ? b1 : b0;
    int base = blockIdx.x * 1024 + threadIdx.x * 4;
    int s = 0;
    if (base + 3 < N) {
        int4 v = *(const int4*)&cnt[base];
        s = v.x + v.y + v.z + v.w;
    } else {
        for (int i = 0; i < 4; i++) if (base + i < N) s += cnt[base + i];
    }
    __shared__ int red[256];
    red[threadIdx.x] = s;
    __syncthreads();
    for (int d = 128; d > 0; d >>= 1) {
        if (threadIdx.x < d) red[threadIdx.x] += red[threadIdx.x + d];
        __syncthreads();
    }
    if (threadIdx.x == 0) bs[blockIdx.x] = red[0];
}

// scan_final: inline-scans RAW block sums; offsets + dinv (y==0) + fused
// prefix over partials (when given); block 0 writes off[N].
__global__ __launch_bounds__(256) void scan_final(const int* __restrict__ c0, const int* __restrict__ c1,
                                                  const int* __restrict__ b0, const int* __restrict__ b1,
                                                  int* __restrict__ o0, int* __restrict__ u0,
                                                  int* __restrict__ o1, int* __restrict__ u1,
                                                  unsigned* __restrict__ pc,
                                                  unsigned* __restrict__ pr,
                                                  float* __restrict__ dinvp, int N) {
    const int* cnt = blockIdx.y ? c1 : c0;
    const int* bs  = blockIdx.y ? b1 : b0;
    int* off = blockIdx.y ? o1 : o0;
    int* cur = blockIdx.y ? u1 : u0;
    unsigned* part = blockIdx.y ? pr : pc;
    int t = threadIdx.x;
    int nb = gridDim.x;
    __shared__ int sh[256];

    sh[t] = (t < nb) ? bs[t] : 0;
    __syncthreads();
    for (int d = 1; d < 256; d <<= 1) {
        int u = (t >= d) ? sh[t - d] : 0;
        __syncthreads();
        sh[t] += u;
        __syncthreads();
    }
    int myBase = (blockIdx.x == 0) ? 0 : sh[blockIdx.x - 1];
    int total = sh[255];
    __syncthreads();
    if (blockIdx.x == 0 && t == 0) off[N] = total;

    int base = blockIdx.x * 1024 + t * 4;
    int4 v = {0, 0, 0, 0};
    if (base + 3 < N) {
        v = *(const int4*)&cnt[base];
    } else {
        int tmp[4] = {0, 0, 0, 0};
        for (int i = 0; i < 4; i++) if (base + i < N) tmp[i] = cnt[base + i];
        v.x = tmp[0]; v.y = tmp[1]; v.z = tmp[2]; v.w = tmp[3];
    }
    if (blockIdx.y == 0) {
        if (base + 3 < N) {
            float4 dv;
            dv.x = rsqrtf(1.0f + (float)v.x);
            dv.y = rsqrtf(1.0f + (float)v.y);
            dv.z = rsqrtf(1.0f + (float)v.z);
            dv.w = rsqrtf(1.0f + (float)v.w);
            *(float4*)&dinvp[base] = dv;
        } else {
            int vv[4] = {v.x, v.y, v.z, v.w};
            for (int i = 0; i < 4; i++)
                if (base + i < N) dinvp[base + i] = rsqrtf(1.0f + (float)vv[i]);
        }
    }
    int s = v.x + v.y + v.z + v.w;
    sh[t] = s;
    __syncthreads();
    for (int d = 1; d < 256; d <<= 1) {
        int u = (t >= d) ? sh[t - d] : 0;
        __syncthreads();
        sh[t] += u;
        __syncthreads();
    }
    int ex = myBase + ((t == 0) ? 0 : sh[t - 1]);
    int4 o;
    o.x = ex; o.y = ex + v.x; o.z = o.y + v.y; o.w = o.z + v.z;
    if (base + 3 < N) {
        *(int4*)&off[base] = o;
        *(int4*)&cur[base] = o;
        if (part) {
            unsigned a0 = (unsigned)o.x, a1 = (unsigned)o.y,
                     a2 = (unsigned)o.z, a3 = (unsigned)o.w;
            for (int k = 0; k < CSR_CH; k++) {
                unsigned* pp = part + (size_t)k * N + base;
                uint4 u = *(const uint4*)pp;
                uint4 w = {a0, a1, a2, a3};
                *(uint4*)pp = w;
                a0 += u.x; a1 += u.y; a2 += u.z; a3 += u.w;
            }
        }
    } else {
        int arr[4] = {o.x, o.y, o.z, o.w};
        for (int i = 0; i < 4; i++) if (base + i < N) { off[base + i] = arr[i]; cur[base + i] = arr[i]; }
        if (part) {
            for (int i = 0; i < 4; i++) {
                if (base + i >= N) continue;
                unsigned acc = (unsigned)arr[i];
                for (int k = 0; k < CSR_CH; k++) {
                    unsigned* pp = part + (size_t)k * N + base + i;
                    unsigned tv = *pp;
                    *pp = acc;
                    acc += tv;
                }
            }
        }
    }
}

__global__ __launch_bounds__(256) void scatter_tile(const int* __restrict__ row, const int* __restrict__ col,
                                                    int* __restrict__ curc, int* __restrict__ curr,
                                                    u16* __restrict__ ecol, u16* __restrict__ erow,
                                                    int E, int lo, int hi, int doRow) {
    int e = blockIdx.x * 256 + threadIdx.x;
    if (e >= E) return;
    int s = row[e], d = col[e];
    if (d >= lo && d < hi) {
        int p = atomicAdd(&curc[d], 1);
        ecol[p] = (u16)s;
    }
    if (doRow && s >= lo && s < hi) {
        int q = atomicAdd(&curr[s], 1);
        erow[q] = (u16)d;
    }
}

// ---------------- MFMA GEMM body (global A) ----------------
template <int K, bool RTBF, bool BFIN, bool SCALE>
__device__ __forceinline__ void gemm_mfma_body(int bid, const void* __restrict__ Xv,
                                               const u16* __restrict__ Wp,
                                               u16* __restrict__ Cb,
                                               const float* __restrict__ dinv,
                                               const int* __restrict__ flagp, int M) {
    const int isbf = RTBF ? *flagp : (BFIN ? 1 : 0);
    const int tid = threadIdx.x;
    const int wave = tid >> 6, lane = tid & 63;
    const int m16 = lane & 15, quad = lane >> 4;
    const int row = bid * 64 + wave * 16 + m16;
    constexpr int STEPS = K / 32;

    float4v acc[8];
#pragma unroll
    for (int t = 0; t < 8; t++) acc[t] = (float4v){0.f, 0.f, 0.f, 0.f};

    const bool rowOK = row < M;
#pragma unroll
    for (int s = 0; s < STEPS; s++) {
        int k0 = s * 32 + quad * 8;
        short8 a = (short8)(short)0;
        if (rowOK) {
            if (isbf) {
                a = *(const short8*)((const u16*)Xv + (size_t)row * K + k0);
            } else {
                const float* p = (const float*)Xv + (size_t)row * K + k0;
                float4 f0 = *(const float4*)p;
                float4 f1 = *(const float4*)(p + 4);
                a[0] = (short)f2bf(f0.x); a[1] = (short)f2bf(f0.y);
                a[2] = (short)f2bf(f0.z); a[3] = (short)f2bf(f0.w);
                a[4] = (short)f2bf(f1.x); a[5] = (short)f2bf(f1.y);
                a[6] = (short)f2bf(f1.z); a[7] = (short)f2bf(f1.w);
            }
        }
#pragma unroll
        for (int t = 0; t < 8; t++) {
            short8 b = *(const short8*)(Wp + ((size_t)(s * 8 + t) * 64 + lane) * 8);
            acc[t] = __builtin_amdgcn_mfma_f32_16x16x32_bf16(a, b, acc[t], 0, 0, 0);
        }
    }
#pragma unroll
    for (int r = 0; r < 4; r++) {
        int gr = bid * 64 + wave * 16 + quad * 4 + r;
        if (gr < M) {
            float sc = SCALE ? dinv[gr] : 1.0f;
#pragma unroll
            for (int t = 0; t < 8; t++) {
                size_t o = (size_t)gr * H_FEATS + t * 16 + m16;
                Cb[o] = f2bf(sc * acc[t][r]);
            }
        }
    }
}

template <int K, bool RTBF, bool BFIN, bool SCALE>
__global__ __launch_bounds__(256) void gemm_mfma(const void* __restrict__ Xv,
                                                 const u16* __restrict__ Wp,
                                                 u16* __restrict__ Cb,
                                                 const float* __restrict__ dinv,
                                                 const int* __restrict__ flagp, int M) {
    gemm_mfma_body<K, RTBF, BFIN, SCALE>(blockIdx.x, Xv, Wp, Cb, dinv, flagp, M);
}

// ---------------- fused: scatter (blocks [0,NSC)) + gemm L0 (rest) ----------------
__global__ __launch_bounds__(256) void scatter_gemm0(const int* __restrict__ row,
                                                     const int* __restrict__ col,
                                                     const unsigned* __restrict__ partC,
                                                     const unsigned* __restrict__ partR,
                                                     u16* __restrict__ ecol,
                                                     u16* __restrict__ erow,
                                                     int E, int N,
                                                     const void* __restrict__ Xv,
                                                     const u16* __restrict__ Wp,
                                                     u16* __restrict__ Pb,
                                                     const float* __restrict__ dinv,
                                                     const int* __restrict__ flagp) {
    extern __shared__ unsigned cur[];
    if (blockIdx.x < CSR_NSC) {
        scatter_body(blockIdx.x, row, col, partC, partR, ecol, erow, E, N, cur);
    } else {
        gemm_mfma_body<256, true, false, true>(blockIdx.x - CSR_NSC, Xv, Wp, Pb, dinv, flagp, N);
    }
}

// ---------------- standalone tier-0 gather (L0): 16-lane uint4, depth-4 ----------------
__global__ __launch_bounds__(256) void agg_sum(const int* __restrict__ off,
                                               const u16* __restrict__ idx,
                                               const float* __restrict__ dinv,
                                               const u16* __restrict__ Pb,
                                               const void* __restrict__ bv,
                                               u16* __restrict__ hout,
                                               const int* __restrict__ flagp, int N) {
    int node = blockIdx.x * 16 + (threadIdx.x >> 4);
    if (node >= N) return;
    int l = threadIdx.x & 15;
    int isbf = *flagp;
    int beg = off[node], end = off[node + 1];
    int co = l * 8;

    float acc[8];
    uint4 su = *(const uint4*)(Pb + (size_t)node * H_FEATS + co);
    set8(acc, su);

    const uint4 zz = {0u, 0u, 0u, 0u};
    int i = beg;
    int s0 = (i     < end) ? (int)idx[i]     : 0;
    int s1 = (i + 1 < end) ? (int)idx[i + 1] : 0;
    int s2 = (i + 2 < end) ? (int)idx[i + 2] : 0;
    int s3 = (i + 3 < end) ? (int)idx[i + 3] : 0;
    uint4 h0 = (i     < end) ? *(const uint4*)(Pb + (size_t)s0 * H_FEATS + co) : zz;
    uint4 h1 = (i + 1 < end) ? *(const uint4*)(Pb + (size_t)s1 * H_FEATS + co) : zz;
    uint4 h2 = (i + 2 < end) ? *(const uint4*)(Pb + (size_t)s2 * H_FEATS + co) : zz;
    uint4 h3 = (i + 3 < end) ? *(const uint4*)(Pb + (size_t)s3 * H_FEATS + co) : zz;
    for (; i + 4 < end; i += 4) {
        int t0 = (int)idx[i + 4];
        int t1 = (i + 5 < end) ? (int)idx[i + 5] : 0;
        int t2 = (i + 6 < end) ? (int)idx[i + 6] : 0;
        int t3 = (i + 7 < end) ? (int)idx[i + 7] : 0;
        uint4 n0 = *(const uint4*)(Pb + (size_t)t0 * H_FEATS + co);
        uint4 n1 = (i + 5 < end) ? *(const uint4*)(Pb + (size_t)t1 * H_FEATS + co) : zz;
        uint4 n2 = (i + 6 < end) ? *(const uint4*)(Pb + (size_t)t2 * H_FEATS + co) : zz;
        uint4 n3 = (i + 7 < end) ? *(const uint4*)(Pb + (size_t)t3 * H_FEATS + co) : zz;
        add8(acc, h0); add8(acc, h1); add8(acc, h2); add8(acc, h3);
        h0 = n0; h1 = n1; h2 = n2; h3 = n3;
    }
    add8(acc, h0); add8(acc, h1); add8(acc, h2); add8(acc, h3);

    float dd = dinv[node];
#pragma unroll
    for (int j = 0; j < 8; j++)
        acc[j] = fmaxf(fmaf(dd, acc[j], dload(bv, co + j, isbf)), 0.0f);
    *(uint4*)&hout[(size_t)node * H_FEATS + co] = pack8(acc);
}

// ---------------- fused gather-tile helper: 32-row tile, 16 lanes/row, uint4, depth-4 ----------------
template <int MODE, bool WRITEG>
__device__ __forceinline__ void gather_tile(int bid,
                                            const int* __restrict__ off,
                                            const u16* __restrict__ idx,
                                            const float* __restrict__ dinv,
                                            const u16* __restrict__ Src,
                                            const void* __restrict__ bv, int isbf,
                                            u16* __restrict__ Hg,
                                            u16* __restrict__ tile, int N) {
    int lane16 = threadIdx.x & 15;
    int rloc = threadIdx.x >> 4;
    int co = lane16 * 8;
    const uint4 zz = {0u, 0u, 0u, 0u};
#pragma unroll
    for (int pass = 0; pass < 2; ++pass) {
        int r = pass * 16 + rloc;
        int gr = bid * 32 + r;
        uint4* ldst = (uint4*)(tile + (size_t)r * TPAD + co);
        if (gr >= N) { *ldst = zz; continue; }
        int beg = off[gr], end = off[gr + 1];
        float acc[8];
        if (MODE == 0) {
            uint4 u = *(const uint4*)(Src + (size_t)gr * H_FEATS + co);
            set8(acc, u);
        } else {
#pragma unroll
            for (int j = 0; j < 8; j++) acc[j] = 0.0f;
        }
        int i = beg;
        int s0 = (i     < end) ? (int)idx[i]     : 0;
        int s1 = (i + 1 < end) ? (int)idx[i + 1] : 0;
        int s2 = (i + 2 < end) ? (int)idx[i + 2] : 0;
        int s3 = (i + 3 < end) ? (int)idx[i + 3] : 0;
        uint4 h0 = (i     < end) ? *(const uint4*)(Src + (size_t)s0 * H_FEATS + co) : zz;
        uint4 h1 = (i + 1 < end) ? *(const uint4*)(Src + (size_t)s1 * H_FEATS + co) : zz;
        uint4 h2 = (i + 2 < end) ? *(const uint4*)(Src + (size_t)s2 * H_FEATS + co) : zz;
        uint4 h3 = (i + 3 < end) ? *(const uint4*)(Src + (size_t)s3 * H_FEATS + co) : zz;
        for (; i + 4 < end; i += 4) {
            int t0 = (int)idx[i + 4];
            int t1 = (i + 5 < end) ? (int)idx[i + 5] : 0;
            int t2 = (i + 6 < end) ? (int)idx[i + 6] : 0;
            int t3 = (i + 7 < end) ? (int)idx[i + 7] : 0;
            uint4 n0 = *(const uint4*)(Src + (size_t)t0 * H_FEATS + co);
            uint4 n1 = (i + 5 < end) ? *(const uint4*)(Src + (size_t)t1 * H_FEATS + co) : zz;
            uint4 n2 = (i + 6 < end) ? *(const uint4*)(Src + (size_t)t2 * H_FEATS + co) : zz;
            uint4 n3 = (i + 7 < end) ? *(const uint4*)(Src + (size_t)t3 * H_FEATS + co) : zz;
            add8(acc, h0); add8(acc, h1); add8(acc, h2); add8(acc, h3);
            h0 = n0; h1 = n1; h2 = n2; h3 = n3;
        }
        add8(acc, h0); add8(acc, h1); add8(acc, h2); add8(acc, h3);

        if (MODE == 0) {
            float dd = dinv[gr];
#pragma unroll
            for (int j = 0; j < 8; j++)
                acc[j] = fmaxf(fmaf(dd, acc[j], dload(bv, co + j, isbf)), 0.0f);
        } else {
            int cnt = end - beg;
            if (cnt > 0) {
                float inv = 1.0f / (float)cnt;
#pragma unroll
                for (int j = 0; j < 8; j++) acc[j] *= inv;
            } else {
                uint4 u = *(const uint4*)(Src + (size_t)gr * H_FEATS + co);
                set8(acc, u);
            }
        }
        uint4 pk = pack8(acc);
        *ldst = pk;
        if (WRITEG) *(uint4*)(Hg + (size_t)gr * H_FEATS + co) = pk;
    }
}

// ---------------- MFMA GEMM phase, A from 32-row LDS tile (K=128) ----------------
__device__ __forceinline__ void gemm_lds_body32(int bid, const u16* __restrict__ tile,
                                                const u16* __restrict__ Wp,
                                                u16* __restrict__ Cb,
                                                const float* __restrict__ dinv, int M) {
    const int tid = threadIdx.x;
    const int wave = tid >> 6, lane = tid & 63;
    const int m16 = lane & 15, quad = lane >> 4;
    const int rg = wave & 1, cg = wave >> 1;
    const int lrow = rg * 16 + m16;

    float4v acc[4];
#pragma unroll
    for (int t = 0; t < 4; t++) acc[t] = (float4v){0.f, 0.f, 0.f, 0.f};

#pragma unroll
    for (int s = 0; s < 4; s++) {
        int k0 = s * 32 + quad * 8;
        short8 a = *(const short8*)(tile + (size_t)lrow * TPAD + k0);
#pragma unroll
        for (int t = 0; t < 4; t++) {
            int tg = cg * 4 + t;
            short8 b = *(const short8*)(Wp + ((size_t)(s * 8 + tg) * 64 + lane) * 8);
            acc[t] = __builtin_amdgcn_mfma_f32_16x16x32_bf16(a, b, acc[t], 0, 0, 0);
        }
    }
#pragma unroll
    for (int r = 0; r < 4; r++) {
        int gr = bid * 32 + rg * 16 + quad * 4 + r;
        if (gr < M) {
            float sc = dinv[gr];
#pragma unroll
            for (int t = 0; t < 4; t++) {
                size_t o = (size_t)gr * H_FEATS + (cg * 4 + t) * 16 + m16;
                Cb[o] = f2bf(sc * acc[t][r]);
            }
        }
    }
}

// ---------------- fused gather + gemm (tier 0, layers 1/2), 32-row tile ----------------
template <int MODE>
__global__ __launch_bounds__(256) void agg_gemm(const int* __restrict__ off,
                                                const u16* __restrict__ idx,
                                                const float* __restrict__ dinv,
                                                const u16* __restrict__ Src,
                                                const void* __restrict__ bv,
                                                const u16* __restrict__ Wp,
                                                u16* __restrict__ Hg,
                                                u16* __restrict__ Pnext,
                                                const int* __restrict__ flagp, int N) {
    __shared__ u16 tile[32 * TPAD];
    gather_tile<MODE, true>(blockIdx.x, off, idx, dinv, Src, bv, *flagp, Hg, tile, N);
    __syncthreads();
    gemm_lds_body32(blockIdx.x, tile, Wp, Pnext, dinv, N);
}

// ---------------- fused gather + jk + MFMA fc (tier 0, last layer), 32-row tile ----------------
__global__ __launch_bounds__(256) void agg_fc3(const int* __restrict__ off,
                                               const u16* __restrict__ idx,
                                               const float* __restrict__ dinv,
                                               const u16* __restrict__ Src,
                                               const void* __restrict__ bv3,
                                               const u16* __restrict__ H0,
                                               const u16* __restrict__ H1,
                                               const u16* __restrict__ Wfp,
                                               const void* __restrict__ bv,
                                               void* __restrict__ Outv,
                                               const float* __restrict__ meta, int N) {
    __shared__ u16 tile[32 * TPAD];
    const int isbf = ((const int*)meta)[0];
    gather_tile<0, false>(blockIdx.x, off, idx, dinv, Src, bv3, isbf, (u16*)0, tile, N);
    __syncthreads();

    const float w0 = meta[8], w1 = meta[9], w2 = meta[10];
    const int tid = threadIdx.x;
    const int wave = tid >> 6, lane = tid & 63;
    const int m16 = lane & 15, quad = lane >> 4;
    const int rg = wave & 1, cg = wave >> 1;
    const int lrow = rg * 16 + m16;
    const int gr0 = blockIdx.x * 32 + lrow;

    float4v acc[2];
#pragma unroll
    for (int t = 0; t < 2; t++) acc[t] = (float4v){0.f, 0.f, 0.f, 0.f};

#pragma unroll
    for (int s = 0; s < 4; s++) {
        int k0 = s * 32 + quad * 8;
        short8 a = (short8)(short)0;
        if (gr0 < N) {
            float f0[8], f1[8], f2[8];
            uint4 u0 = *(const uint4*)(H0 + (size_t)gr0 * H_FEATS + k0);
            uint4 u1 = *(const uint4*)(H1 + (size_t)gr0 * H_FEATS + k0);
            uint4 tv = *(const uint4*)(tile + (size_t)lrow * TPAD + k0);
            set8(f0, u0); set8(f1, u1); set8(f2, tv);
#pragma unroll
            for (int j = 0; j < 8; j++)
                a[j] = (short)f2bf(w0 * f0[j] + w1 * f1[j] + w2 * f2[j]);
        }
#pragma unroll
        for (int t = 0; t < 2; t++) {
            int tg = cg * 2 + t;
            short8 b = *(const short8*)(Wfp + ((size_t)(s * 4 + tg) * 64 + lane) * 8);
            acc[t] = __builtin_amdgcn_mfma_f32_16x16x32_bf16(a, b, acc[t], 0, 0, 0);
        }
    }

    __hip_bfloat16* ob = (__hip_bfloat16*)Outv;
    float* of = (float*)Outv;
#pragma unroll
    for (int r = 0; r < 4; r++) {
        int gr = blockIdx.x * 32 + rg * 16 + quad * 4 + r;
        if (gr < N) {
#pragma unroll
            for (int t = 0; t < 2; t++) {
                int c = (cg * 2 + t) * 16 + m16;
                size_t o = (size_t)gr * 64 + c;
                float v = acc[t][r] + dload(bv, c, isbf);
                if (isbf) ob[o] = __float2bfloat16(v); else of[o] = v;
            }
        }
    }
}

// ---------------- weighted gather (tier B only) ----------------
template <bool BF16OUT>
__global__ __launch_bounds__(256) void agg_gather3b(const int* __restrict__ off,
                                                    const u16* __restrict__ idx,
                                                    const float* __restrict__ dinv,
                                                    const u16* __restrict__ Hb,
                                                    const void* __restrict__ bv,
                                                    void* __restrict__ houtv,
                                                    const int* __restrict__ flagp, int N) {
    int node = blockIdx.x * 8 + (threadIdx.x >> 5);
    if (node >= N) return;
    int l = threadIdx.x & 31;
    int isbf = *flagp;
    int beg = off[node], end = off[node + 1];
    float dd = dinv[node];
    size_t ro = (size_t)l * 4;

    float4 self = load4bf(&Hb[(size_t)node * H_FEATS + ro]);
    float w0s = dd * dd;
    float4 acc = {w0s * self.x, w0s * self.y, w0s * self.z, w0s * self.w};

    int i = beg;
    int s0 = (i < end) ? (int)idx[i] : 0;
    float4 h0 = (i < end) ? load4bf(&Hb[(size_t)s0 * H_FEATS + ro])
                          : (float4){0.f, 0.f, 0.f, 0.f};
    for (; i < end; i++) {
        int s1 = (i + 1 < end) ? (int)idx[i + 1] : 0;
        float4 h1 = (i + 1 < end) ? load4bf(&Hb[(size_t)s1 * H_FEATS + ro]) : h0;
        float w = dinv[s0] * dd;
        acc.x = fmaf(w, h0.x, acc.x);
        acc.y = fmaf(w, h0.y, acc.y);
        acc.z = fmaf(w, h0.z, acc.z);
        acc.w = fmaf(w, h0.w, acc.w);
        s0 = s1; h0 = h1;
    }
    acc.x = fmaxf(acc.x + dload(bv, l * 4 + 0, isbf), 0.0f);
    acc.y = fmaxf(acc.y + dload(bv, l * 4 + 1, isbf), 0.0f);
    acc.z = fmaxf(acc.z + dload(bv, l * 4 + 2, isbf), 0.0f);
    acc.w = fmaxf(acc.w + dload(bv, l * 4 + 3, isbf), 0.0f);
    if (BF16OUT) {
        u16* hb = (u16*)houtv;
        uint2 pk;
        pk.x = (unsigned)f2bf(acc.x) | ((unsigned)f2bf(acc.y) << 16);
        pk.y = (unsigned)f2bf(acc.z) | ((unsigned)f2bf(acc.w) << 16);
        *(uint2*)&hb[(size_t)node * H_FEATS + ro] = pk;
    } else {
        *(float4*)&((float*)houtv)[(size_t)node * H_FEATS + ro] = acc;
    }
}

// ---------------- fp32 GEMM (tier C) ----------------
template <int K, bool XIN, bool GATEBF, bool BF16OUT>
__global__ __launch_bounds__(256) void gemm128(const void* __restrict__ Xv,
                                               const void* __restrict__ Wv,
                                               void* __restrict__ Cv,
                                               const int* __restrict__ flagp, int N) {
    constexpr int BM = 64, BK = 16, BN = 128, TN = 8, TX = BN / TN;
    __shared__ float Xs[BK][BM + 4];
    __shared__ float Ws[BK][BN];
    const int isbf = *flagp;
    if (GATEBF && isbf != 1) return;
    const float* Xf = (const float*)Xv;

    const int tid = threadIdx.x;
    const int tx = tid % TX;
    const int ty = tid / TX;
    const int rowBase = blockIdx.x * BM;

    float acc[4][TN] = {};
    const int lk = tid % BK;
    const int lr0 = tid / BK;

    for (int kb = 0; kb < K; kb += BK) {
#pragma unroll
        for (int i = 0; i < 4; i++) {
            int r = lr0 + i * 16;
            int gr = rowBase + r;
            float v = 0.0f;
            if (gr < N) {
                size_t idx = (size_t)gr * K + kb + lk;
                v = XIN ? dload(Xv, idx, isbf) : Xf[idx];
            }
            Xs[lk][r] = v;
        }
#pragma unroll
        for (int i = 0; i < 8; i++) {
            int idx = i * 256 + tid;
            int k = idx >> 7, c = idx & 127;
            Ws[k][c] = dload(Wv, (size_t)(kb + k) * BN + c, isbf);
        }
        __syncthreads();
#pragma unroll
        for (int k = 0; k < BK; k++) {
            float4 a = *(const float4*)&Xs[k][ty * 4];
            float av[4] = {a.x, a.y, a.z, a.w};
            float4 b0 = *(const float4*)&Ws[k][tx * TN];
            float4 b1 = *(const float4*)&Ws[k][tx * TN + 4];
            float bv[8] = {b0.x, b0.y, b0.z, b0.w, b1.x, b1.y, b1.z, b1.w};
#pragma unroll
            for (int i = 0; i < 4; i++)
#pragma unroll
                for (int j = 0; j < TN; j++) acc[i][j] = fmaf(av[i], bv[j], acc[i][j]);
        }
        __syncthreads();
    }
#pragma unroll
    for (int i = 0; i < 4; i++) {
        int gr = rowBase + ty * 4 + i;
        if (gr < N) {
#pragma unroll
            for (int j = 0; j < TN; j++) {
                size_t o = (size_t)gr * BN + tx * TN + j;
                if (BF16OUT) ((u16*)Cv)[o] = f2bf(acc[i][j]);
                else         ((float*)Cv)[o] = acc[i][j];
            }
        }
    }
}

template <bool FIRST, bool LAST, bool BFIN>
__global__ __launch_bounds__(256) void fc_accum(const void* __restrict__ Hmv,
                                                const void* __restrict__ Wv,
                                                const void* __restrict__ bv,
                                                void* __restrict__ Outv,
                                                const float* __restrict__ meta,
                                                int widx, int N) {
    constexpr int BM = 64, BK = 16, BN = 64, TN = 4, TX = BN / TN, K = 128;
    __shared__ float Xs[BK][BM + 4];
    __shared__ float Ws[BK][BN];
    const int isbf = ((const int*)meta)[0];
    const float scale = meta[8 + widx];

    const int tid = threadIdx.x;
    const int tx = tid % TX;
    const int ty = tid / TX;
    const int rowBase = blockIdx.x * BM;

    float acc[4][TN] = {};
    const int lk = tid % BK;
    const int lr0 = tid / BK;

    for (int kb = 0; kb < K; kb += BK) {
#pragma unroll
        for (int i = 0; i < 4; i++) {
            int r = lr0 + i * 16;
            int gr = rowBase + r;
            float v = 0.0f;
            if (gr < N) {
                size_t idx = (size_t)gr * K + kb + lk;
                if (BFIN) v = bf2f(((const u16*)Hmv)[idx]);
                else      v = ((const float*)Hmv)[idx];
            }
            Xs[lk][r] = v;
        }
#pragma unroll
        for (int i = 0; i < 4; i++) {
            int idx = i * 256 + tid;
            int k = idx >> 6, c = idx & 63;
            Ws[k][c] = dload(Wv, (size_t)(kb + k) * BN + c, isbf);
        }
        __syncthreads();
#pragma unroll
        for (int k = 0; k < BK; k++) {
            float4 a = *(const float4*)&Xs[k][ty * 4];
            float av[4] = {a.x, a.y, a.z, a.w};
            float4 bb = *(const float4*)&Ws[k][tx * TN];
            float bvv[4] = {bb.x, bb.y, bb.z, bb.w};
#pragma unroll
            for (int i = 0; i < 4; i++)
#pragma unroll
                for (int j = 0; j < TN; j++) acc[i][j] = fmaf(av[i], bvv[j], acc[i][j]);
        }
        __syncthreads();
    }
    __hip_bfloat16* ob = (__hip_bfloat16*)Outv;
    float* of = (float*)Outv;
#pragma unroll
    for (int i = 0; i < 4; i++) {
        int gr = rowBase + ty * 4 + i;
        if (gr < N) {
#pragma unroll
            for (int j = 0; j < TN; j++) {
                int c = tx * TN + j;
                size_t o = (size_t)gr * BN + c;
                float v = scale * acc[i][j];
                if (!FIRST) v += isbf ? __bfloat162float(ob[o]) : of[o];
                if (LAST) v += dload(bv, c, isbf);
                if (isbf) ob[o] = __float2bfloat16(v); else of[o] = v;
            }
        }
    }
}

// ---------------- atomic fallbacks (tier B / C) ----------------
__global__ __launch_bounds__(256) void init_deg(float* deg, float* odeg, int N) {
    int i = blockIdx.x * 256 + threadIdx.x;
    if (i < N) { deg[i] = 1.0f; odeg[i] = 0.0f; }
}
__global__ __launch_bounds__(256) void count_deg(const int* __restrict__ row, const int* __restrict__ col,
                                                 float* deg, float* odeg, int E) {
    int e = blockIdx.x * 256 + threadIdx.x;
    if (e < E) {
        atomicAdd(&deg[col[e]], 1.0f);
        atomicAdd(&odeg[row[e]], 1.0f);
    }
}
__global__ __launch_bounds__(256) void deg_to_dinv(float* deg, int N) {
    int i = blockIdx.x * 256 + threadIdx.x;
    if (i < N) deg[i] = rsqrtf(deg[i]);
}
__global__ __launch_bounds__(256) void agg_edges(const int* __restrict__ row, const int* __restrict__ col,
                                                 const float* __restrict__ dinv,
                                                 const float* __restrict__ H,
                                                 float* __restrict__ agg, int E) {
    int e = blockIdx.x * 2 + (threadIdx.x >> 7);
    if (e >= E) return;
    int j = threadIdx.x & 127;
    int s = row[e], d = col[e];
    float w = dinv[s] * dinv[d];
    atomicAdd(&agg[(size_t)d * H_FEATS + j], w * H[(size_t)s * H_FEATS + j]);
}
__global__ __launch_bounds__(256) void mean_edges(const int* __restrict__ row, const int* __restrict__ col,
                                                  const float* __restrict__ h0pre,
                                                  float* __restrict__ nsum, int E) {
    int e = blockIdx.x * 2 + (threadIdx.x >> 7);
    if (e >= E) return;
    int j = threadIdx.x & 127;
    int r = row[e], c = col[e];
    atomicAdd(&nsum[(size_t)r * H_FEATS + j], h0pre[(size_t)c * H_FEATS + j]);
}
__global__ __launch_bounds__(256) void finalize_layer(const float* __restrict__ agg,
                                                      const float* __restrict__ H,
                                                      const float* __restrict__ dinv,
                                                      const void* __restrict__ bv,
                                                      float* __restrict__ hout,
                                                      const int* __restrict__ flagp, int NH) {
    int idx = blockIdx.x * 256 + threadIdx.x;
    if (idx >= NH) return;
    int isbf = *flagp;
    int v = idx >> 7, j = idx & 127;
    float di = dinv[v];
    float h = fmaf(di * di, H[idx], agg[idx]) + dload(bv, j, isbf);
    hout[idx] = fmaxf(h, 0.0f);
}
__global__ __launch_bounds__(256) void finalize_mean(const float* __restrict__ nsum,
                                                     const float* __restrict__ h0pre,
                                                     const float* __restrict__ odeg,
                                                     float* __restrict__ h0, int NH) {
    int idx = blockIdx.x * 256 + threadIdx.x;
    if (idx >= NH) return;
    int v = idx >> 7;
    float od = odeg[v];
    h0[idx] = (od > 0.0f) ? (nsum[idx] / od) : h0pre[idx];
}
__global__ __launch_bounds__(256) void finalize_mean_cnt(const float* __restrict__ nsum,
                                                         const float* __restrict__ h0pre,
                                                         const int* __restrict__ cntr,
                                                         float* __restrict__ h0, int NH) {
    int idx = blockIdx.x * 256 + threadIdx.x;
    if (idx >= NH) return;
    int v = idx >> 7;
    int od = cntr[v];
    h0[idx] = (od > 0) ? (nsum[idx] / (float)od) : h0pre[idx];
}

extern "C" void kernel_launch(void* const* d_in, const int* in_sizes, int n_in,
                              void* d_out, int out_size, void* d_ws, size_t ws_size,
                              hipStream_t stream) {
    const void* x   = d_in[0];
    const int*  ei  = (const int*)d_in[1];
    const void* W1  = d_in[2];
    const void* b1  = d_in[3];
    const void* W2  = d_in[4];
    const void* b2  = d_in[5];
    const void* W3  = d_in[6];
    const void* b3  = d_in[7];
    const void* jkb = d_in[8];
    const void* Wfc = d_in[9];
    const void* bfc = d_in[10];

    const int IN = 256;
    const int N = in_sizes[0] / IN;          // 50000
    const int E = in_sizes[1] / 2;           // 800000
    const int NH = N * H_FEATS;

    const int* row = ei;
    const int* col = ei + E;

    // ---- workspace layout (fp32 words); arrays 16B-aligned ----
    auto a4 = [](size_t v) { return (v + 3) & ~(size_t)3; };
    float* ws = (float*)d_ws;
    size_t o = 0;
    float* meta  = ws + o;           o += 256;
    float* dinv  = ws + o;           o += N;          o = a4(o);
    int*   cntc  = (int*)(ws + o);   o += N;          o = a4(o);
    int*   cntr  = (int*)(ws + o);   o += N;          o = a4(o);
    int*   bsumc = (int*)(ws + o);   o += 256;
    int*   bsumr = (int*)(ws + o);   o += 256;
    int*   coff  = (int*)(ws + o);   o += N + 1;      o = a4(o);
    int*   curc  = (int*)(ws + o);   o += N;          o = a4(o);
    u16*   ecol  = (u16*)(ws + o);   o += E;          o = a4(o);
    size_t oB_small = o;
    int*   roff  = (int*)(ws + o);   o += N + 1;      o = a4(o);
    int*   curr  = (int*)(ws + o);   o += N;          o = a4(o);
    u16*   erow  = (u16*)(ws + o);   o += E;          o = a4(o);
    size_t oA_full = o;

    auto alignup = [](size_t v) { return (v + 63) & ~(size_t)63; };
    const size_t WPW = 16384 + 8192 + 8192 + 4096;   // Wp1 + Wp2 + Wp3 + Wfcp (fp32 words)
    size_t needA = alignup(oA_full) + 2 * (size_t)NH + 64 + WPW;
    size_t needB = alignup(oB_small) + 2 * (size_t)NH + 64 + WPW;

    int tier;
    size_t hoff;
    if (N >= 65536)                { tier = 2; hoff = alignup(256 + 2 * (size_t)N); }
    else if (ws_size >= needA * 4) { tier = 0; hoff = alignup(oA_full); }
    else if (ws_size >= needB * 4) { tier = 1; hoff = alignup(oB_small); }
    else                           { tier = 2; hoff = alignup(256 + 2 * (size_t)N); }
    float* A = ws + hoff;
    float* B = A + NH;
    u16* HbA = (u16*)A;
    u16* HbB = (u16*)B;
    // tier-0 carves four bf16 NH buffers out of the same 2*NH-float region:
    u16* Pb  = (u16*)A;              // P rows (rotating)
    u16* Qb  = Pb + (size_t)NH;      // h0pre, later P2
    u16* H0b = Pb + 2 * (size_t)NH;
    u16* H1b = Pb + 3 * (size_t)NH;
    // CSR-build partials overlay the H0/H1 half (dead until meangemm1):
    unsigned* partC = (unsigned*)H0b;
    unsigned* partR = partC + (size_t)CSR_CH * N;
    size_t wpoff = alignup(hoff + 2 * (size_t)NH);
    u16* Wp1 = (u16*)(ws + wpoff);
    u16* Wp2 = Wp1 + 32768;
    u16* Wp3 = Wp2 + 16384;
    u16* Wfcp = Wp3 + 16384;
    float* odegf = ws + 256 + N;
    const int* flag = (const int*)meta;

    dim3 blk(256);
    int gN = (N + 255) / 256;
    int gE = (E + 255) / 256;
    int gE2 = (E + 1) / 2;
    int gNH = (NH + 255) / 256;
    int gGemm = (N + 63) / 64;
    int gG32 = (N + 31) / 32;
    int gNode16 = (N + 15) / 16;
    int gNode8 = (N + 7) / 8;
    int nb = (N + 1023) / 1024;
    size_t shb = (size_t)((N + CSR_SL - 1) / CSR_SL) * 4;

    if (tier == 0) {
        // ---- atomic-free CSR build; count + sniff + pack in one launch ----
        count_partial<<<CSR_NSC + 1 + 36, blk, shb, stream>>>(row, col, partC, partR, E, N,
                                                              (const unsigned int*)x, jkb, meta,
                                                              W1, W2, W3, Wfc,
                                                              Wp1, Wp2, Wp3, Wfcp);
        reduce_bsum<<<dim3(nb, 2), blk, 0, stream>>>(partC, partR, cntc, cntr, bsumc, bsumr, N);
        scan_final<<<dim3(nb, 2), blk, 0, stream>>>(cntc, cntr, bsumc, bsumr,
                                                    coff, curc, roff, curr,
                                                    partC, partR, dinv, N);

        // ---- fused: scatter + layer-0 GEMM (P0 = dinv .* (x@W1)) ----
        scatter_gemm0<<<CSR_NSC + gGemm, blk, shb, stream>>>(row, col, partC, partR, ecol, erow,
                                                             E, N, x, Wp1, Pb, dinv, flag);

        // ---- h0pre = relu(dd*(P0[d]+sum P0[s]) + b1) ----
        agg_sum<<<gNode16, blk, 0, stream>>>(coff, ecol, dinv, Pb, b1, Qb, flag, N);

        // ---- fused mean + gemm1: h0 -> H0b, P1 = dinv.(h0@W2) -> Pb ----
        agg_gemm<1><<<gG32, blk, 0, stream>>>(roff, erow, dinv, Qb, b1, Wp2, H0b, Pb, flag, N);

        // ---- fused agg + gemm2: h1 -> H1b, P2 = dinv.(h1@W3) -> Qb ----
        agg_gemm<0><<<gG32, blk, 0, stream>>>(coff, ecol, dinv, Pb, b2, Wp3, H1b, Qb, flag, N);

        // ---- fused agg + jk + MFMA fc: h2 (LDS only) + out ----
        agg_fc3<<<gG32, blk, 0, stream>>>(coff, ecol, dinv, Qb, b3, H0b, H1b,
                                          Wfcp, bfc, d_out, meta, N);
    } else if (tier == 1) {
        // ---- tier B: legacy atomic CSR build (col only) + fp32 mean path ----
        hipMemsetAsync(cntc, 0, 2 * (size_t)N * 4, stream);
        histo_sniff<<<gE + 1, blk, 0, stream>>>(row, col, cntc, cntr, E,
                                                (const unsigned int*)x, jkb, meta);
        const int T = 4;
        int step = (N + T - 1) / T;
        scan_bsum<<<dim3(nb, 1), blk, 0, stream>>>(cntc, cntc, bsumc, bsumc, N);
        scan_final<<<dim3(nb, 1), blk, 0, stream>>>(cntc, cntc, bsumc, bsumc,
                                                    coff, curc, coff, curc,
                                                    (unsigned*)0, (unsigned*)0, dinv, N);
        for (int t = 0; t < T; t++) {
            int lo = t * step, hi = lo + step; if (hi > N) hi = N;
            scatter_tile<<<gE, blk, 0, stream>>>(row, col, curc, curc, ecol, ecol, E, lo, hi, 0);
        }

        pack_all<<<36, blk, 0, stream>>>(W1, W2, W3, Wfc, Wp1, Wp2, Wp3, Wfcp, flag);

        gemm_mfma<256, true, false, false><<<gGemm, blk, 0, stream>>>(x, Wp1, HbA, dinv, flag, N);
        agg_gather3b<false><<<gNode8, blk, 0, stream>>>(coff, ecol, dinv, HbA, b1, B, flag, N);
        hipMemsetAsync(A, 0, (size_t)NH * 4, stream);
        mean_edges<<<gE2, blk, 0, stream>>>(row, col, B, A, E);
        finalize_mean_cnt<<<gNH, blk, 0, stream>>>(A, B, cntr, A, NH);
        fc_accum<true, false, false><<<gGemm, blk, 0, stream>>>(A, Wfc, bfc, d_out, meta, 0, N);

        gemm_mfma<128, false, false, false><<<gGemm, blk, 0, stream>>>(A, Wp2, HbB, dinv, flag, N);
        agg_gather3b<true><<<gNode8, blk, 0, stream>>>(coff, ecol, dinv, HbB, b2, HbA, flag, N);
        fc_accum<false, false, true><<<gGemm, blk, 0, stream>>>(HbA, Wfc, bfc, d_out, meta, 1, N);

        gemm_mfma<128, false, true, false><<<gGemm, blk, 0, stream>>>(HbA, Wp3, HbB, dinv, flag, N);
        agg_gather3b<true><<<gNode8, blk, 0, stream>>>(coff, ecol, dinv, HbB, b3, HbA, flag, N);
        fc_accum<false, true, true><<<gGemm, blk, 0, stream>>>(HbA, Wfc, bfc, d_out, meta, 2, N);
    } else {
        // ---- tier C: fp32 atomic path ----
        sniff_jkw<<<1, blk, 0, stream>>>((const unsigned int*)x, jkb, meta);
        init_deg<<<gN, blk, 0, stream>>>(dinv, odegf, N);
        count_deg<<<gE, blk, 0, stream>>>(row, col, dinv, odegf, E);
        deg_to_dinv<<<gN, blk, 0, stream>>>(dinv, N);

        gemm128<256, true, false, false><<<gGemm, blk, 0, stream>>>(x, W1, A, flag, N);
        hipMemsetAsync(B, 0, (size_t)NH * 4, stream);
        agg_edges<<<gE2, blk, 0, stream>>>(row, col, dinv, A, B, E);
        finalize_layer<<<gNH, blk, 0, stream>>>(B, A, dinv, b1, B, flag, NH);
        hipMemsetAsync(A, 0, (size_t)NH * 4, stream);
        mean_edges<<<gE2, blk, 0, stream>>>(row, col, B, A, E);
        finalize_mean<<<gNH, blk, 0, stream>>>(A, B, odegf, A, NH);
        fc_accum<true, false, false><<<gGemm, blk, 0, stream>>>(A, Wfc, bfc, d_out, meta, 0, N);

        gemm128<128, false, false, false><<<gGemm, blk, 0, stream>>>(A, W2, B, flag, N);
        hipMemsetAsync(A, 0, (size_t)NH * 4, stream);
        agg_edges<<<gE2, blk, 0, stream>>>(row, col, dinv, B, A, E);
        finalize_layer<<<gNH, blk, 0, stream>>>(A, B, dinv, b2, A, flag, NH);
        fc_accum<false, false, false><<<gGemm, blk, 0, stream>>>(A, Wfc, bfc, d_out, meta, 1, N);

        gemm128<128, false, false, false><<<gGemm, blk, 0, stream>>>(A, W3, B, flag, N);
        hipMemsetAsync(A, 0, (size_t)NH * 4, stream);
        agg_edges<<<gE2, blk, 0, stream>>>(row, col, dinv, B, A, E);
        finalize_layer<<<gNH, blk, 0, stream>>>(A, B, dinv, b3, A, flag, NH);
        fc_accum<false, true, false><<<gGemm, blk, 0, stream>>>(A, Wfc, bfc, d_out, meta, 2, N);
    }
}